// Round 6
// baseline (1091.612 us; speedup 1.0000x reference)
//
#include <hip/hip_runtime.h>
#include <hip/hip_bf16.h>

#define BSZ 16
#define SEQ 512
#define DIM 512
#define NH 8
#define DK 64
#define NROWS (BSZ*SEQ)   // 8192
#define DFF2 2048

typedef unsigned short u16;
typedef u16   u16x8 __attribute__((ext_vector_type(8)));
typedef short s16x8 __attribute__((ext_vector_type(8)));
typedef float f32x4 __attribute__((ext_vector_type(4)));

__device__ __forceinline__ u16 f2b(float x) {
    union { float f; unsigned int u; } c; c.f = x;
    unsigned int r = c.u + 0x7fff + ((c.u >> 16) & 1);   // RNE
    return (u16)(r >> 16);
}
__device__ __forceinline__ float b2f(u16 u) {
    union { unsigned int i; float f; } c; c.i = ((unsigned int)u) << 16; return c.f;
}

// async global->LDS, 16B per lane. LDS dest = wave-uniform base + lane*16.
__device__ __forceinline__ void gld16(const u16* g, u16* l) {
    __builtin_amdgcn_global_load_lds(
        (const __attribute__((address_space(1))) unsigned int*)(unsigned long long)g,
        (__attribute__((address_space(3))) unsigned int*)(unsigned int)(unsigned long long)l,
        16, 0, 0);
}

// ---- cast fp32 -> bf16 ----
__global__ __launch_bounds__(256) void cast_f2b4(const float* __restrict__ in,
                                                 u16* __restrict__ out, int n4) {
    int i = blockIdx.x * 256 + threadIdx.x;
    if (i >= n4) return;
    float4 v = ((const float4*)in)[i];
    ushort4 o; o.x = f2b(v.x); o.y = f2b(v.y); o.z = f2b(v.z); o.w = f2b(v.w);
    ((ushort4*)out)[i] = o;
}

// ---- transpose + cast weights: dest[z][N][K](bf16) from W[layer0+z*lstride][K][N](fp32) ----
__global__ __launch_bounds__(256) void transpose_cast(
    const float* __restrict__ W, u16* __restrict__ WT,
    int K, int N, int layer0, int lstride, size_t dstride)
{
    __shared__ float t[32][33];
    int z = blockIdx.z;
    const float* Wz = W + (size_t)(layer0 + z * lstride) * K * N;
    u16* WTz = WT + (size_t)z * dstride;
    int k0 = blockIdx.x * 32, n0 = blockIdx.y * 32;
    int tx = threadIdx.x & 31, ty = threadIdx.x >> 5;
    for (int i = ty; i < 32; i += 8) t[i][tx] = Wz[(size_t)(k0 + i) * N + n0 + tx];
    __syncthreads();
    for (int i = ty; i < 32; i += 8) WTz[(size_t)(n0 + i) * K + k0 + tx] = f2b(t[tx][i]);
}

// ---- MFMA GEMM. C[M,N] = A[M,K] @ WT[N,K]^T (+bias). Tile 128 x (NI*32), BK=32,
// double-buffered LDS, XCD-chunked 1-D grid swizzle.
// SPLIT : col-tiles with n0 >= nsplit use Av/bias2/C2 (fused q|v).
// SPLITK: grid doubled; second half computes k-slice 1 (A/WT + K) into C2
//         (fp32 partials; bias added later in add_ln2). K param = per-slice K.
// NI    : 2 -> 64-col tiles (more blocks/CU), 4 -> 128-col tiles.
template<int WRITE_BF16, int RELU, int SPLIT, int SPLITK, int NI>
__global__ __launch_bounds__(256) void gemm2(
    const u16* __restrict__ Aq, const u16* __restrict__ Av,
    const u16* __restrict__ WT,
    const float* __restrict__ bias1, const float* __restrict__ bias2,
    void* __restrict__ C1, void* __restrict__ C2,
    int K, int lda, int ldw, int ldc, int nsplit, int nx)
{
    __shared__ __attribute__((aligned(16))) u16 As[2][128 * 32];
    __shared__ __attribute__((aligned(16))) u16 Bs[2][NI * 32 * 32];
    int tid = threadIdx.x;
    int wave = tid >> 6, lane = tid & 63;
    int quad = lane >> 4, l16 = lane & 15;

    // XCD-chunked swizzle over the whole 1-D grid
    int bid = blockIdx.x;
    int per = gridDim.x >> 3;
    int swz = (bid & 7) * per + (bid >> 3);
    int nxy = SPLITK ? ((int)gridDim.x >> 1) : (int)gridDim.x;
    int kslice = 0;
    if (SPLITK && swz >= nxy) { kslice = 1; swz -= nxy; }
    int bx = swz % nx, by = swz / nx;
    int n0 = bx * (NI * 32), m0 = by * 128;

    int wrow = (wave & 1) * 64;
    int wcol = (wave >> 1) * (NI * 16);
    bool isv = SPLIT && (n0 >= nsplit);
    const u16* A = isv ? Av : Aq;

    // A staging: wave w covers rows [w*32, w*32+32); 2 gld16 of 16 rows each
    int sr = wave * 32 + (lane >> 2);
    int sc = (lane & 3) * 8;
    int ko = kslice * K;                     // k-slice base (elements)
    const u16* gA0 = A  + (size_t)(m0 + sr) * lda + sc + ko;
    const u16* gA1 = gA0 + (size_t)16 * lda;
    int lo0 = (wave * 32) * 32;
    int lo1 = (wave * 32 + 16) * 32;

    // B staging
    const u16* gB0;
    const u16* gB1 = nullptr;
    int bo0, bo1 = 0;
    if (NI == 4) {                           // 128-row B tile: like A
        gB0 = WT + (size_t)(n0 + sr) * ldw + sc + ko;
        gB1 = gB0 + (size_t)16 * ldw;
        bo0 = lo0; bo1 = lo1;
    } else {                                 // 64-row B tile: 1 gld16/wave (16 rows)
        gB0 = WT + (size_t)(n0 + wave * 16 + (lane >> 2)) * ldw + sc + ko;
        bo0 = (wave * 16) * 32;
    }

    f32x4 acc[4][NI];
    #pragma unroll
    for (int i = 0; i < 4; i++)
        #pragma unroll
        for (int j = 0; j < NI; j++) acc[i][j] = (f32x4){0.f, 0.f, 0.f, 0.f};

    // prologue: stage k-tile 0 into buf 0
    gld16(gA0, &As[0][lo0]);
    gld16(gA1, &As[0][lo1]);
    gld16(gB0, &Bs[0][bo0]);
    if (NI == 4) gld16(gB1, &Bs[0][bo1]);
    __syncthreads();

    int NT = K >> 5;
    int cur = 0;
    for (int t = 0; t < NT; ++t) {
        if (t + 1 < NT) {                    // prefetch next tile into other buffer
            int k0 = (t + 1) << 5;
            gld16(gA0 + k0, &As[cur ^ 1][lo0]);
            gld16(gA1 + k0, &As[cur ^ 1][lo1]);
            gld16(gB0 + k0, &Bs[cur ^ 1][bo0]);
            if (NI == 4) gld16(gB1 + k0, &Bs[cur ^ 1][bo1]);
        }
        s16x8 af[4], bf[NI];
        #pragma unroll
        for (int i = 0; i < 4; i++)
            af[i] = *(s16x8*)&As[cur][(wrow + i * 16 + l16) * 32 + quad * 8];
        #pragma unroll
        for (int i = 0; i < NI; i++)
            bf[i] = *(s16x8*)&Bs[cur][(wcol + i * 16 + l16) * 32 + quad * 8];
        #pragma unroll
        for (int mi = 0; mi < 4; mi++)
            #pragma unroll
            for (int ni = 0; ni < NI; ni++)
                acc[mi][ni] = __builtin_amdgcn_mfma_f32_16x16x32_bf16(
                    af[mi], bf[ni], acc[mi][ni], 0, 0, 0);
        __syncthreads();                     // drains prefetch loads + frag reads
        cur ^= 1;
    }

    const float* bias = isv ? bias2 : bias1;
    void* C = (isv || (SPLITK && kslice)) ? C2 : C1;
    int nb = n0 - (isv ? nsplit : 0);
    #pragma unroll
    for (int ni = 0; ni < NI; ni++) {
        int cn = nb + wcol + ni * 16 + l16;
        float bb = bias ? bias[cn] : 0.f;
        #pragma unroll
        for (int mi = 0; mi < 4; mi++) {
            int cm = m0 + wrow + mi * 16 + quad * 4;
            #pragma unroll
            for (int r = 0; r < 4; r++) {
                size_t off = (size_t)(cm + r) * ldc + cn;
                float v = acc[mi][ni][r] + bb;
                if (RELU) v = fmaxf(v, 0.f);
                if (WRITE_BF16) ((u16*)C)[off] = f2b(v);
                else            ((float*)C)[off] = v;
            }
        }
    }
}

// ---- rmask init for all 6 layers: [l][b][h], shared heads = 1, routed = 0 ----
__global__ void init_rmask6(float* __restrict__ r) {
    int t = blockIdx.x * 256 + threadIdx.x;
    if (t < 6 * 128) r[t] = ((t & 7) < 2) ? 1.0f : 0.0f;
}

// ---- router: 32 lanes per row, 8 rows/block. wg staged in LDS, chunk-skewed. ----
__global__ __launch_bounds__(256) void router_kernel(
    const u16* __restrict__ qlin, const float* __restrict__ wg,
    float* __restrict__ rmask)
{
    __shared__ float s_wg[6 * 544];     // 13056 B
    __shared__ float sacc[8];
    int tid = threadIdx.x;
    #pragma unroll
    for (int k = 0; k < 12; k++) {
        int n = tid + k * 256;          // 0..3071
        int d = n / 6, r = n - d * 6;
        s_wg[r * 544 + (d >> 4) * 17 + (d & 15)] = wg[n];
    }
    if (tid < 8) sacc[tid] = 0.f;
    __syncthreads();

    int c = tid & 31;                   // chunk within row
    int row = blockIdx.x * 8 + (tid >> 5);
    int cb = c * 17;
    const u16* xr = qlin + (size_t)row * DIM + c * 16;
    u16x8 q0 = *(const u16x8*)xr;
    u16x8 q1 = *(const u16x8*)(xr + 8);

    float lg[6] = {0.f, 0.f, 0.f, 0.f, 0.f, 0.f};
    #pragma unroll
    for (int j = 0; j < 8; j++) {
        float x = b2f(q0[j]);
        #pragma unroll
        for (int r = 0; r < 6; r++) lg[r] += x * s_wg[r * 544 + cb + j];
    }
    #pragma unroll
    for (int j = 0; j < 8; j++) {
        float x = b2f(q1[j]);
        #pragma unroll
        for (int r = 0; r < 6; r++) lg[r] += x * s_wg[r * 544 + cb + 8 + j];
    }
    #pragma unroll
    for (int r = 0; r < 6; r++) {
        #pragma unroll
        for (int o = 1; o < 32; o <<= 1) lg[r] += __shfl_xor(lg[r], o);
    }
    float m = lg[0];
    #pragma unroll
    for (int r = 1; r < 6; r++) m = fmaxf(m, lg[r]);
    float s = 0.f;
    #pragma unroll
    for (int r = 0; r < 6; r++) { lg[r] = __expf(lg[r] - m); s += lg[r]; }
    float inv = 1.0f / s;
    #pragma unroll
    for (int r = 0; r < 6; r++) lg[r] *= inv;
    int i1 = 0; float g1 = lg[0];
    #pragma unroll
    for (int r = 1; r < 6; r++) if (lg[r] > g1) { g1 = lg[r]; i1 = r; }
    int i2 = -1; float g2 = -1.f;
    #pragma unroll
    for (int r = 0; r < 6; r++) if (r != i1 && lg[r] > g2) { g2 = lg[r]; i2 = r; }
    if (c == 0) {
        atomicAdd(&sacc[i1], g1);
        atomicAdd(&sacc[i2], g2);
    }
    __syncthreads();
    if (tid < 6) {
        int b = blockIdx.x >> 6;        // 64 blocks per batch
        atomicAdd(&rmask[b * 8 + 2 + tid], sacc[tid] * (1.0f / (float)SEQ));
    }
}

// ---- per-layer V transpose: vT[b][h][d][j] from v[(b,j)][h*64+d] ----
__global__ __launch_bounds__(256) void transpose_v(
    const u16* __restrict__ v, u16* __restrict__ vT)
{
    __shared__ u16 t[64][72];
    int jt = blockIdx.x, bh = blockIdx.y;
    int b = bh >> 3, h = bh & 7;
    int tid = threadIdx.x;
    int lr = tid >> 2, lc = (tid & 3) * 16;
    const u16* src = v + (size_t)(b * SEQ + jt * 64 + lr) * DIM + h * DK + lc;
    *(u16x8*)&t[lr][lc]     = *(const u16x8*)src;
    *(u16x8*)&t[lr][lc + 8] = *(const u16x8*)(src + 8);
    __syncthreads();
    u16x8 o0, o1;
    #pragma unroll
    for (int i = 0; i < 8; i++) o0[i] = t[lc + i][lr];
    #pragma unroll
    for (int i = 0; i < 8; i++) o1[i] = t[lc + 8 + i][lr];
    u16* dst = vT + ((size_t)bh * DK + lr) * SEQ + jt * 64 + lc;
    *(u16x8*)dst       = o0;
    *(u16x8*)(dst + 8) = o1;
}

// ---- MFMA flash attention v2: NO __syncthreads, NO K/V LDS staging.
// K/V per (b,h) is 64KB each -> L2-resident; fragments loaded direct from
// global (16B/lane gathers). Q fragments hoisted to registers. Only LDS use
// is the per-wave P transpose tile (each wave reads only rows it wrote).
// 1-D grid, XCD-chunked: all 8 qt-blocks of one (b,h) land on one XCD.
__global__ __launch_bounds__(256) void attn_flash(
    const u16* __restrict__ qlin, const u16* __restrict__ vT,
    const float* __restrict__ rmask, u16* __restrict__ ctx, int mask_flag)
{
    __shared__ u16 s_p[64][72];
    int gi = (blockIdx.x & 7) * ((int)gridDim.x >> 3) + (blockIdx.x >> 3);
    int qt = gi & 7, h = (gi >> 3) & 7, b = gi >> 6;
    int tid = threadIdx.x;
    int wave = tid >> 6, lane = tid & 63;
    int quad = lane >> 4, l16 = lane & 15;

    const u16* qbase = qlin + (size_t)(b * SEQ) * DIM + h * DK;   // [s][d], stride DIM
    const u16* vbase = vT + (size_t)(b * NH + h) * DK * SEQ;      // [d][j], stride SEQ

    // Q fragments (jt-invariant): rows wave*16+l16, cols ks*32+quad*8
    s16x8 aq[2];
    #pragma unroll
    for (int ks = 0; ks < 2; ks++)
        aq[ks] = *(const s16x8*)(qbase + (size_t)(qt * 64 + wave * 16 + l16) * DIM
                                 + ks * 32 + quad * 8);

    f32x4 acc_o[4];
    #pragma unroll
    for (int i = 0; i < 4; i++) acc_o[i] = (f32x4){0.f, 0.f, 0.f, 0.f};
    float m_i[4] = {-1e30f, -1e30f, -1e30f, -1e30f};
    float l_i[4] = {0.f, 0.f, 0.f, 0.f};

    for (int jt = 0; jt <= qt; jt++) {
        // K fragments direct from global (L2-hit)
        s16x8 kf[2][4];
        #pragma unroll
        for (int ks = 0; ks < 2; ks++)
            #pragma unroll
            for (int nf = 0; nf < 4; nf++)
                kf[ks][nf] = *(const s16x8*)(qbase
                    + (size_t)(jt * 64 + nf * 16 + l16) * DIM + ks * 32 + quad * 8);

        f32x4 acc_s[4];
        #pragma unroll
        for (int i = 0; i < 4; i++) acc_s[i] = (f32x4){0.f, 0.f, 0.f, 0.f};
        #pragma unroll
        for (int ks = 0; ks < 2; ks++)
            #pragma unroll
            for (int nf = 0; nf < 4; nf++)
                acc_s[nf] = __builtin_amdgcn_mfma_f32_16x16x32_bf16(
                    aq[ks], kf[ks][nf], acc_s[nf], 0, 0, 0);

        int qg0 = qt * 64 + wave * 16 + quad * 4;
        float sc[4][4];
        #pragma unroll
        for (int nf = 0; nf < 4; nf++) {
            int jg = jt * 64 + nf * 16 + l16;
            #pragma unroll
            for (int r = 0; r < 4; r++) {
                float v = acc_s[nf][r] * 0.125f;
                if (jt == qt) {
                    int bound = mask_flag ? (qg0 + r) : (qg0 + r - 1);
                    if (jg > bound) v = -1e30f;
                }
                sc[nf][r] = v;
            }
        }
        float tmax[4];
        #pragma unroll
        for (int r = 0; r < 4; r++) {
            float t = fmaxf(fmaxf(sc[0][r], sc[1][r]), fmaxf(sc[2][r], sc[3][r]));
            #pragma unroll
            for (int o = 1; o < 16; o <<= 1) t = fmaxf(t, __shfl_xor(t, o));
            tmax[r] = t;
        }
        float p[4][4];
        #pragma unroll
        for (int r = 0; r < 4; r++) {
            float mnew = fmaxf(m_i[r], tmax[r]);
            float alpha = __expf(m_i[r] - mnew);
            float su = 0.f;
            #pragma unroll
            for (int nf = 0; nf < 4; nf++) { p[nf][r] = __expf(sc[nf][r] - mnew); su += p[nf][r]; }
            #pragma unroll
            for (int o = 1; o < 16; o <<= 1) su += __shfl_xor(su, o);
            l_i[r] = l_i[r] * alpha + su;
            m_i[r] = mnew;
            #pragma unroll
            for (int nf = 0; nf < 4; nf++) acc_o[nf][r] *= alpha;
        }
        // P transpose through per-wave LDS rows [wave*16, wave*16+16) — no
        // cross-wave sharing; in-order DS pipe per wave makes this safe
        // without a block barrier. wave_barrier stops compiler reordering.
        #pragma unroll
        for (int nf = 0; nf < 4; nf++)
            #pragma unroll
            for (int r = 0; r < 4; r++)
                s_p[wave * 16 + quad * 4 + r][nf * 16 + l16] = f2b(p[nf][r]);
        __builtin_amdgcn_wave_barrier();
        s16x8 pa[2];
        pa[0] = *(s16x8*)&s_p[wave * 16 + l16][quad * 8];
        pa[1] = *(s16x8*)&s_p[wave * 16 + l16][32 + quad * 8];

        // V fragments direct from global (L2-hit)
        s16x8 vf[2][4];
        #pragma unroll
        for (int ks = 0; ks < 2; ks++)
            #pragma unroll
            for (int nf = 0; nf < 4; nf++)
                vf[ks][nf] = *(const s16x8*)(vbase
                    + (size_t)(nf * 16 + l16) * SEQ + jt * 64 + ks * 32 + quad * 8);
        #pragma unroll
        for (int ks = 0; ks < 2; ks++)
            #pragma unroll
            for (int nf = 0; nf < 4; nf++)
                acc_o[nf] = __builtin_amdgcn_mfma_f32_16x16x32_bf16(
                    pa[ks], vf[ks][nf], acc_o[nf], 0, 0, 0);
        __builtin_amdgcn_wave_barrier();   // next iter's P writes stay after pa reads
    }

    float rm = rmask[b * 8 + h];
    int qrow = qt * 64 + wave * 16 + quad * 4;
    #pragma unroll
    for (int r = 0; r < 4; r++) {
        float scale = rm / l_i[r];
        u16* dst = ctx + (size_t)(b * SEQ + qrow + r) * DIM + h * DK;
        #pragma unroll
        for (int nf = 0; nf < 4; nf++)
            dst[nf * 16 + l16] = f2b(acc_o[nf][r] * scale);
    }
}

// ---- row q==0: uniform 1/SEQ over ALL keys; coalesced reads from vT ----
__global__ __launch_bounds__(256) void attn_row0(
    const u16* __restrict__ vT, const float* __restrict__ rmask, u16* __restrict__ ctx)
{
    int bh = blockIdx.x;
    int b = bh >> 3, h = bh & 7;
    int d = threadIdx.x >> 2, seg = threadIdx.x & 3;
    const u16* src = vT + ((size_t)bh * DK + d) * SEQ + seg * 128;
    float s = 0.f;
    for (int i = 0; i < 16; i++) {
        u16x8 v = *(const u16x8*)(src + i * 8);
        #pragma unroll
        for (int j = 0; j < 8; j++) s += b2f(v[j]);
    }
    s += __shfl_down(s, 1);
    s += __shfl_down(s, 2);
    if (seg == 0)
        ctx[(size_t)(b * SEQ) * DIM + h * DK + d] =
            f2b(s * (1.0f / (float)SEQ) * rmask[b * 8 + h]);
}

// ---- x = LN(x + p0 + p1 + bias_col), also emit bf16 copy ----
__global__ __launch_bounds__(256) void add_ln2(
    float* __restrict__ x, const float* __restrict__ p0, const float* __restrict__ p1,
    const float* __restrict__ bcol,
    const float* __restrict__ g, const float* __restrict__ bta,
    u16* __restrict__ out16)
{
    __shared__ float redA[4], redB[4];
    int row = blockIdx.x, tid = threadIdx.x;
    size_t base = (size_t)row * DIM;
    float t0 = x[base + tid]       + p0[base + tid]       + p1[base + tid]       + bcol[tid];
    float t1 = x[base + tid + 256] + p0[base + tid + 256] + p1[base + tid + 256] + bcol[tid + 256];
    float s = t0 + t1, sq = t0 * t0 + t1 * t1;
    for (int o = 32; o > 0; o >>= 1) { s += __shfl_down(s, o, 64); sq += __shfl_down(sq, o, 64); }
    int lane = tid & 63, wid = tid >> 6;
    if (lane == 0) { redA[wid] = s; redB[wid] = sq; }
    __syncthreads();
    float S1 = redA[0] + redA[1] + redA[2] + redA[3];
    float S2 = redB[0] + redB[1] + redB[2] + redB[3];
    float mu = S1 * (1.0f / (float)DIM);
    float var = S2 * (1.0f / (float)DIM) - mu * mu;
    float rstd = rsqrtf(var + 1e-5f);
    float o0 = g[tid]       * (t0 - mu) * rstd + bta[tid];
    float o1 = g[tid + 256] * (t1 - mu) * rstd + bta[tid + 256];
    x[base + tid]       = o0;
    x[base + tid + 256] = o1;
    out16[base + tid]       = f2b(o0);
    out16[base + tid + 256] = f2b(o1);
}

// ---------------- host side ----------------
extern "C" void kernel_launch(void* const* d_in, const int* in_sizes, int n_in,
                              void* d_out, int out_size, void* d_ws, size_t ws_size,
                              hipStream_t stream) {
    const float* qe   = (const float*)d_in[0];
    const float* ie   = (const float*)d_in[1];
    const float* wq   = (const float*)d_in[2];
    const float* bq   = (const float*)d_in[3];
    const float* wv   = (const float*)d_in[4];
    const float* bv   = (const float*)d_in[5];
    const float* wo   = (const float*)d_in[6];
    const float* bo   = (const float*)d_in[7];
    const float* wg   = (const float*)d_in[8];
    const float* ln1g = (const float*)d_in[9];
    const float* ln1b = (const float*)d_in[10];
    const float* fw1  = (const float*)d_in[11];
    const float* fb1  = (const float*)d_in[12];
    const float* fw2  = (const float*)d_in[13];
    const float* fb2  = (const float*)d_in[14];
    const float* ln2g = (const float*)d_in[15];
    const float* ln2b = (const float*)d_in[16];

    const size_t RD = (size_t)NROWS * DIM;     // 4,194,304
    float* ws   = (float*)d_ws;
    float* xbuf = ws;                          // question residual (fp32)
    float* ybuf = ws + RD;                     // knowledge residual (fp32)

    u16* b16    = (u16*)(ws + 2 * RD);
    u16* x16    = b16;                 b16 += RD;
    u16* y16    = b16;                 b16 += RD;
    u16* ctx16  = b16;                 b16 += RD;
    u16* qlin16 = b16;                 b16 += RD;
    u16* vbuf16 = b16;                 b16 += RD;
    u16* vT     = b16;                 b16 += RD;
    float* proj0 = (float*)vbuf16;              // 16.8 MiB overlay: vbuf16+vT (dead after attn)
    u16* hid    = b16;                 b16 += 4 * RD;   // 8192x2048 bf16, dedicated
    float* proj1 = (float*)b16;        b16 += 2 * RD;   // 8192x512 fp32 split-K partial
    u16* wqvT   = b16;                 b16 += 6 * (size_t)1024 * 512;
    u16* woT    = b16;                 b16 += 6 * (size_t)512 * 512;
    u16* fw1T   = b16;                 b16 += 2 * (size_t)DFF2 * 512;
    u16* fw2T   = b16;                 b16 += 2 * (size_t)512 * DFF2;
    float* rmask6 = (float*)b16;                // 6*128 floats

    const size_t nBytes = RD * sizeof(float);
    hipMemcpyAsync(xbuf, qe, nBytes, hipMemcpyDeviceToDevice, stream);
    hipMemcpyAsync(ybuf, ie, nBytes, hipMemcpyDeviceToDevice, stream);
    cast_f2b4<<<(int)(RD / 4 / 256), 256, 0, stream>>>(qe, x16, (int)(RD / 4));
    cast_f2b4<<<(int)(RD / 4 / 256), 256, 0, stream>>>(ie, y16, (int)(RD / 4));

    transpose_cast<<<dim3(16, 16, 6), 256, 0, stream>>>(wq, wqvT,             512, 512, 0, 1, (size_t)1024 * 512);
    transpose_cast<<<dim3(16, 16, 6), 256, 0, stream>>>(wv, wqvT + 512 * 512, 512, 512, 0, 1, (size_t)1024 * 512);
    transpose_cast<<<dim3(16, 16, 6), 256, 0, stream>>>(wo, woT,              512, 512, 0, 1, (size_t)512 * 512);
    transpose_cast<<<dim3(16, 64, 2), 256, 0, stream>>>(fw1, fw1T, 512, DFF2, 3, 2, (size_t)DFF2 * 512);
    transpose_cast<<<dim3(64, 16, 2), 256, 0, stream>>>(fw2, fw2T, DFF2, 512, 3, 2, (size_t)512 * DFF2);
    init_rmask6<<<3, 256, 0, stream>>>(rmask6);

    const int BIG = 1 << 30;
    auto run_block = [&](float* xr, u16* xq16, const u16* xv16, int l, int maskf, int pos) {
        size_t lD = (size_t)l * DIM;
        float* rm = rmask6 + l * 128;
        // q|v fused: N=1024, 64-col tiles -> nx=16, 1024 blocks (4/CU)
        gemm2<1, 0, 1, 0, 2><<<1024, 256, 0, stream>>>(
            xq16, xv16, wqvT + (size_t)l * 1024 * 512, bq + lD, bv + lD,
            qlin16, vbuf16, 512, 512, 512, 512, 512, 16);
        transpose_v<<<dim3(8, 128), 256, 0, stream>>>(vbuf16, vT);
        router_kernel<<<NROWS / 8, 256, 0, stream>>>(qlin16, wg + (size_t)l * DIM * 6, rm);
        attn_flash<<<1024, 256, 0, stream>>>(qlin16, vT, rm, ctx16, maskf);
        attn_row0<<<128, 256, 0, stream>>>(vT, rm, ctx16);
        // wo proj: N=512 nx=8, split-K x2 (Khalf=256) -> 1024 blocks; fp32 partials
        gemm2<0, 0, 0, 1, 2><<<1024, 256, 0, stream>>>(
            ctx16, ctx16, woT + (size_t)l * 512 * 512, nullptr, nullptr,
            proj0, proj1, 256, 512, 512, 512, BIG, 8);
        add_ln2<<<NROWS, 256, 0, stream>>>(xr, proj0, proj1, bo + lD,
                                           ln1g + lD, ln1b + lD, xq16);
        if (pos) {
            int slot = (l - 3) / 2;
            // fw1 full-width: N=2048 nx=32 -> 2048 blocks; relu, bf16 out
            gemm2<1, 1, 0, 0, 2><<<2048, 256, 0, stream>>>(
                xq16, xq16, fw1T + (size_t)slot * DFF2 * 512,
                fb1 + (size_t)l * DFF2, nullptr,
                hid, nullptr, 512, 512, 512, DFF2, BIG, 32);
            // fw2: N=512 nx=8, K=2048 split-K x2 (Khalf=1024) -> 1024 blocks
            gemm2<0, 0, 0, 1, 2><<<1024, 256, 0, stream>>>(
                hid, hid, fw2T + (size_t)slot * 512 * DFF2, nullptr, nullptr,
                proj0, proj1, 1024, DFF2, DFF2, 512, BIG, 8);
            add_ln2<<<NROWS, 256, 0, stream>>>(xr, proj0, proj1, fb2 + lD,
                                               ln2g + lD, ln2b + lD, xq16);
        }
    };

    run_block(ybuf, y16, y16, 0, 1, 0);
    run_block(ybuf, y16, y16, 1, 1, 0);
    run_block(xbuf, x16, x16, 2, 1, 0);
    run_block(xbuf, x16, y16, 3, 0, 1);
    run_block(xbuf, x16, x16, 4, 1, 0);
    run_block(xbuf, x16, y16, 5, 0, 1);

    hipMemcpyAsync(d_out, xbuf, nBytes, hipMemcpyDeviceToDevice, stream);
}

// Round 7
// 894.435 us; speedup vs baseline: 1.2204x; 1.2204x over previous
//
#include <hip/hip_runtime.h>
#include <hip/hip_bf16.h>

#define BSZ 16
#define SEQ 512
#define DIM 512
#define NH 8
#define DK 64
#define NROWS (BSZ*SEQ)   // 8192
#define DFF2 2048

typedef unsigned short u16;
typedef u16   u16x8 __attribute__((ext_vector_type(8)));
typedef short s16x8 __attribute__((ext_vector_type(8)));
typedef float f32x4 __attribute__((ext_vector_type(4)));

__device__ __forceinline__ u16 f2b(float x) {
    union { float f; unsigned int u; } c; c.f = x;
    unsigned int r = c.u + 0x7fff + ((c.u >> 16) & 1);   // RNE
    return (u16)(r >> 16);
}
__device__ __forceinline__ float b2f(u16 u) {
    union { unsigned int i; float f; } c; c.i = ((unsigned int)u) << 16; return c.f;
}

// async global->LDS, 16B per lane. LDS dest = wave-uniform base + lane*16.
__device__ __forceinline__ void gld16(const u16* g, u16* l) {
    __builtin_amdgcn_global_load_lds(
        (const __attribute__((address_space(1))) unsigned int*)(unsigned long long)g,
        (__attribute__((address_space(3))) unsigned int*)(unsigned int)(unsigned long long)l,
        16, 0, 0);
}

// ---- cast fp32 -> bf16 ----
__global__ __launch_bounds__(256) void cast_f2b4(const float* __restrict__ in,
                                                 u16* __restrict__ out, int n4) {
    int i = blockIdx.x * 256 + threadIdx.x;
    if (i >= n4) return;
    float4 v = ((const float4*)in)[i];
    ushort4 o; o.x = f2b(v.x); o.y = f2b(v.y); o.z = f2b(v.z); o.w = f2b(v.w);
    ((ushort4*)out)[i] = o;
}

// ---- transpose + cast weights: dest[z][N][K](bf16) from W[layer0+z*lstride][K][N](fp32) ----
__global__ __launch_bounds__(256) void transpose_cast(
    const float* __restrict__ W, u16* __restrict__ WT,
    int K, int N, int layer0, int lstride, size_t dstride)
{
    __shared__ float t[32][33];
    int z = blockIdx.z;
    const float* Wz = W + (size_t)(layer0 + z * lstride) * K * N;
    u16* WTz = WT + (size_t)z * dstride;
    int k0 = blockIdx.x * 32, n0 = blockIdx.y * 32;
    int tx = threadIdx.x & 31, ty = threadIdx.x >> 5;
    for (int i = ty; i < 32; i += 8) t[i][tx] = Wz[(size_t)(k0 + i) * N + n0 + tx];
    __syncthreads();
    for (int i = ty; i < 32; i += 8) WTz[(size_t)(n0 + i) * K + k0 + tx] = f2b(t[tx][i]);
}

// ---- MFMA GEMM. C[M,N] = A[M,K] @ WT[N,K]^T (+bias). Tile 128 x (NI*32), BK=32,
// double-buffered LDS, XCD-chunked 1-D grid swizzle.
// SPLIT : col-tiles with n0 >= nsplit use Av/bias2/C2 (fused q|v).
// SPLITK: grid doubled; second half computes k-slice 1 (A/WT + K) into C2
//         (fp32 partials; bias added later in add_ln2). K param = per-slice K.
// NI    : 2 -> 64-col tiles (more blocks/CU), 4 -> 128-col tiles.
template<int WRITE_BF16, int RELU, int SPLIT, int SPLITK, int NI>
__global__ __launch_bounds__(256) void gemm2(
    const u16* __restrict__ Aq, const u16* __restrict__ Av,
    const u16* __restrict__ WT,
    const float* __restrict__ bias1, const float* __restrict__ bias2,
    void* __restrict__ C1, void* __restrict__ C2,
    int K, int lda, int ldw, int ldc, int nsplit, int nx)
{
    __shared__ __attribute__((aligned(16))) u16 As[2][128 * 32];
    __shared__ __attribute__((aligned(16))) u16 Bs[2][NI * 32 * 32];
    int tid = threadIdx.x;
    int wave = tid >> 6, lane = tid & 63;
    int quad = lane >> 4, l16 = lane & 15;

    // XCD-chunked swizzle over the whole 1-D grid
    int bid = blockIdx.x;
    int per = gridDim.x >> 3;
    int swz = (bid & 7) * per + (bid >> 3);
    int nxy = SPLITK ? ((int)gridDim.x >> 1) : (int)gridDim.x;
    int kslice = 0;
    if (SPLITK && swz >= nxy) { kslice = 1; swz -= nxy; }
    int bx = swz % nx, by = swz / nx;
    int n0 = bx * (NI * 32), m0 = by * 128;

    int wrow = (wave & 1) * 64;
    int wcol = (wave >> 1) * (NI * 16);
    bool isv = SPLIT && (n0 >= nsplit);
    const u16* A = isv ? Av : Aq;

    // A staging: wave w covers rows [w*32, w*32+32); 2 gld16 of 16 rows each
    int sr = wave * 32 + (lane >> 2);
    int sc = (lane & 3) * 8;
    int ko = kslice * K;                     // k-slice base (elements)
    const u16* gA0 = A  + (size_t)(m0 + sr) * lda + sc + ko;
    const u16* gA1 = gA0 + (size_t)16 * lda;
    int lo0 = (wave * 32) * 32;
    int lo1 = (wave * 32 + 16) * 32;

    // B staging
    const u16* gB0;
    const u16* gB1 = nullptr;
    int bo0, bo1 = 0;
    if (NI == 4) {                           // 128-row B tile: like A
        gB0 = WT + (size_t)(n0 + sr) * ldw + sc + ko;
        gB1 = gB0 + (size_t)16 * ldw;
        bo0 = lo0; bo1 = lo1;
    } else {                                 // 64-row B tile: 1 gld16/wave (16 rows)
        gB0 = WT + (size_t)(n0 + wave * 16 + (lane >> 2)) * ldw + sc + ko;
        bo0 = (wave * 16) * 32;
    }

    f32x4 acc[4][NI];
    #pragma unroll
    for (int i = 0; i < 4; i++)
        #pragma unroll
        for (int j = 0; j < NI; j++) acc[i][j] = (f32x4){0.f, 0.f, 0.f, 0.f};

    // prologue: stage k-tile 0 into buf 0
    gld16(gA0, &As[0][lo0]);
    gld16(gA1, &As[0][lo1]);
    gld16(gB0, &Bs[0][bo0]);
    if (NI == 4) gld16(gB1, &Bs[0][bo1]);
    __syncthreads();

    int NT = K >> 5;
    int cur = 0;
    for (int t = 0; t < NT; ++t) {
        if (t + 1 < NT) {                    // prefetch next tile into other buffer
            int k0 = (t + 1) << 5;
            gld16(gA0 + k0, &As[cur ^ 1][lo0]);
            gld16(gA1 + k0, &As[cur ^ 1][lo1]);
            gld16(gB0 + k0, &Bs[cur ^ 1][bo0]);
            if (NI == 4) gld16(gB1 + k0, &Bs[cur ^ 1][bo1]);
        }
        s16x8 af[4], bf[NI];
        #pragma unroll
        for (int i = 0; i < 4; i++)
            af[i] = *(s16x8*)&As[cur][(wrow + i * 16 + l16) * 32 + quad * 8];
        #pragma unroll
        for (int i = 0; i < NI; i++)
            bf[i] = *(s16x8*)&Bs[cur][(wcol + i * 16 + l16) * 32 + quad * 8];
        #pragma unroll
        for (int mi = 0; mi < 4; mi++)
            #pragma unroll
            for (int ni = 0; ni < NI; ni++)
                acc[mi][ni] = __builtin_amdgcn_mfma_f32_16x16x32_bf16(
                    af[mi], bf[ni], acc[mi][ni], 0, 0, 0);
        __syncthreads();                     // drains prefetch loads + frag reads
        cur ^= 1;
    }

    const float* bias = isv ? bias2 : bias1;
    void* C = (isv || (SPLITK && kslice)) ? C2 : C1;
    int nb = n0 - (isv ? nsplit : 0);
    #pragma unroll
    for (int ni = 0; ni < NI; ni++) {
        int cn = nb + wcol + ni * 16 + l16;
        float bb = bias ? bias[cn] : 0.f;
        #pragma unroll
        for (int mi = 0; mi < 4; mi++) {
            int cm = m0 + wrow + mi * 16 + quad * 4;
            #pragma unroll
            for (int r = 0; r < 4; r++) {
                size_t off = (size_t)(cm + r) * ldc + cn;
                float v = acc[mi][ni][r] + bb;
                if (RELU) v = fmaxf(v, 0.f);
                if (WRITE_BF16) ((u16*)C)[off] = f2b(v);
                else            ((float*)C)[off] = v;
            }
        }
    }
}

// ---- rmask init for all 6 layers: [l][b][h], shared heads = 1, routed = 0 ----
__global__ void init_rmask6(float* __restrict__ r) {
    int t = blockIdx.x * 256 + threadIdx.x;
    if (t < 6 * 128) r[t] = ((t & 7) < 2) ? 1.0f : 0.0f;
}

// ---- router: 32 lanes per row, 8 rows/block. wg staged in LDS, chunk-skewed. ----
__global__ __launch_bounds__(256) void router_kernel(
    const u16* __restrict__ qlin, const float* __restrict__ wg,
    float* __restrict__ rmask)
{
    __shared__ float s_wg[6 * 544];     // 13056 B
    __shared__ float sacc[8];
    int tid = threadIdx.x;
    #pragma unroll
    for (int k = 0; k < 12; k++) {
        int n = tid + k * 256;          // 0..3071
        int d = n / 6, r = n - d * 6;
        s_wg[r * 544 + (d >> 4) * 17 + (d & 15)] = wg[n];
    }
    if (tid < 8) sacc[tid] = 0.f;
    __syncthreads();

    int c = tid & 31;                   // chunk within row
    int row = blockIdx.x * 8 + (tid >> 5);
    int cb = c * 17;
    const u16* xr = qlin + (size_t)row * DIM + c * 16;
    u16x8 q0 = *(const u16x8*)xr;
    u16x8 q1 = *(const u16x8*)(xr + 8);

    float lg[6] = {0.f, 0.f, 0.f, 0.f, 0.f, 0.f};
    #pragma unroll
    for (int j = 0; j < 8; j++) {
        float x = b2f(q0[j]);
        #pragma unroll
        for (int r = 0; r < 6; r++) lg[r] += x * s_wg[r * 544 + cb + j];
    }
    #pragma unroll
    for (int j = 0; j < 8; j++) {
        float x = b2f(q1[j]);
        #pragma unroll
        for (int r = 0; r < 6; r++) lg[r] += x * s_wg[r * 544 + cb + 8 + j];
    }
    #pragma unroll
    for (int r = 0; r < 6; r++) {
        #pragma unroll
        for (int o = 1; o < 32; o <<= 1) lg[r] += __shfl_xor(lg[r], o);
    }
    float m = lg[0];
    #pragma unroll
    for (int r = 1; r < 6; r++) m = fmaxf(m, lg[r]);
    float s = 0.f;
    #pragma unroll
    for (int r = 0; r < 6; r++) { lg[r] = __expf(lg[r] - m); s += lg[r]; }
    float inv = 1.0f / s;
    #pragma unroll
    for (int r = 0; r < 6; r++) lg[r] *= inv;
    int i1 = 0; float g1 = lg[0];
    #pragma unroll
    for (int r = 1; r < 6; r++) if (lg[r] > g1) { g1 = lg[r]; i1 = r; }
    int i2 = -1; float g2 = -1.f;
    #pragma unroll
    for (int r = 0; r < 6; r++) if (r != i1 && lg[r] > g2) { g2 = lg[r]; i2 = r; }
    if (c == 0) {
        atomicAdd(&sacc[i1], g1);
        atomicAdd(&sacc[i2], g2);
    }
    __syncthreads();
    if (tid < 6) {
        int b = blockIdx.x >> 6;        // 64 blocks per batch
        atomicAdd(&rmask[b * 8 + 2 + tid], sacc[tid] * (1.0f / (float)SEQ));
    }
}

// ---- per-layer V transpose: vT[b][h][d][j] from v[(b,j)][h*64+d] ----
__global__ __launch_bounds__(256) void transpose_v(
    const u16* __restrict__ v, u16* __restrict__ vT)
{
    __shared__ u16 t[64][72];
    int jt = blockIdx.x, bh = blockIdx.y;
    int b = bh >> 3, h = bh & 7;
    int tid = threadIdx.x;
    int lr = tid >> 2, lc = (tid & 3) * 16;
    const u16* src = v + (size_t)(b * SEQ + jt * 64 + lr) * DIM + h * DK + lc;
    *(u16x8*)&t[lr][lc]     = *(const u16x8*)src;
    *(u16x8*)&t[lr][lc + 8] = *(const u16x8*)(src + 8);
    __syncthreads();
    u16x8 o0, o1;
    #pragma unroll
    for (int i = 0; i < 8; i++) o0[i] = t[lc + i][lr];
    #pragma unroll
    for (int i = 0; i < 8; i++) o1[i] = t[lc + 8 + i][lr];
    u16* dst = vT + ((size_t)bh * DK + lr) * SEQ + jt * 64 + lc;
    *(u16x8*)dst       = o0;
    *(u16x8*)(dst + 8) = o1;
}

// ---- MFMA flash attention v3: round-5 LDS-staged structure (coalesced loads,
// 16x reuse) + XCD-chunked 1-D grid (proven: FETCH 40->8MB) + T14 async-STAGE
// split: jt+1's K/V global loads are issued BEFORE jt's compute, so HBM/L2
// latency hides under QK^T+softmax+PV; the LDS write lands at the top of the
// next iteration. Q fragments hoisted to registers (jt-invariant).
__global__ __launch_bounds__(256) void attn_flash(
    const u16* __restrict__ qlin, const u16* __restrict__ vT,
    const float* __restrict__ rmask, u16* __restrict__ ctx, int mask_flag)
{
    __shared__ u16 s_k [64][72];
    __shared__ u16 s_vt[64][72];   // [d][j]
    __shared__ u16 s_p [64][72];
    int gi = (blockIdx.x & 7) * ((int)gridDim.x >> 3) + (blockIdx.x >> 3);
    int qt = gi & 7, h = (gi >> 3) & 7, b = gi >> 6;
    int tid = threadIdx.x;
    int wave = tid >> 6, lane = tid & 63;
    int quad = lane >> 4, l16 = lane & 15;
    int lr = tid >> 2, lc = (tid & 3) * 16;

    const u16* qbase = qlin + (size_t)(b * SEQ) * DIM + h * DK;   // [s][d]
    const u16* vbase = vT + (size_t)(b * NH + h) * DK * SEQ;      // [d][j]

    // Q fragments hoisted to registers (jt-invariant)
    s16x8 aq[2];
    #pragma unroll
    for (int ks = 0; ks < 2; ks++)
        aq[ks] = *(const s16x8*)(qbase + (size_t)(qt * 64 + wave * 16 + l16) * DIM
                                 + ks * 32 + quad * 8);

    // stage registers for jt=0 (coalesced 16B x2 per thread)
    const u16* ks0 = qbase + (size_t)lr * DIM + lc;
    const u16* vs0 = vbase + (size_t)lr * SEQ + lc;
    u16x8 k0 = *(const u16x8*)ks0, k1 = *(const u16x8*)(ks0 + 8);
    u16x8 v0 = *(const u16x8*)vs0, v1 = *(const u16x8*)(vs0 + 8);

    f32x4 acc_o[4];
    #pragma unroll
    for (int i = 0; i < 4; i++) acc_o[i] = (f32x4){0.f, 0.f, 0.f, 0.f};
    float m_i[4] = {-1e30f, -1e30f, -1e30f, -1e30f};
    float l_i[4] = {0.f, 0.f, 0.f, 0.f};

    for (int jt = 0; jt <= qt; jt++) {
        __syncthreads();               // prior iter's s_k/s_vt frag reads done
        *(u16x8*)&s_k[lr][lc]      = k0;
        *(u16x8*)&s_k[lr][lc + 8]  = k1;
        *(u16x8*)&s_vt[lr][lc]     = v0;
        *(u16x8*)&s_vt[lr][lc + 8] = v1;
        __syncthreads();               // staging visible
        if (jt < qt) {                 // T14: issue next tile's loads NOW;
            const u16* kn = qbase + (size_t)((jt + 1) * 64 + lr) * DIM + lc;
            const u16* vn = vbase + (size_t)lr * SEQ + (jt + 1) * 64 + lc;
            k0 = *(const u16x8*)kn;  k1 = *(const u16x8*)(kn + 8);   // latency hides
            v0 = *(const u16x8*)vn;  v1 = *(const u16x8*)(vn + 8);   // under compute
        }

        f32x4 acc_s[4];
        #pragma unroll
        for (int i = 0; i < 4; i++) acc_s[i] = (f32x4){0.f, 0.f, 0.f, 0.f};
        #pragma unroll
        for (int ks = 0; ks < 2; ks++) {
            #pragma unroll
            for (int nf = 0; nf < 4; nf++) {
                s16x8 bb = *(s16x8*)&s_k[nf * 16 + l16][ks * 32 + quad * 8];
                acc_s[nf] = __builtin_amdgcn_mfma_f32_16x16x32_bf16(aq[ks], bb, acc_s[nf], 0, 0, 0);
            }
        }

        int qg0 = qt * 64 + wave * 16 + quad * 4;
        float sc[4][4];
        #pragma unroll
        for (int nf = 0; nf < 4; nf++) {
            int jg = jt * 64 + nf * 16 + l16;
            #pragma unroll
            for (int r = 0; r < 4; r++) {
                float v = acc_s[nf][r] * 0.125f;
                if (jt == qt) {
                    int bound = mask_flag ? (qg0 + r) : (qg0 + r - 1);
                    if (jg > bound) v = -1e30f;
                }
                sc[nf][r] = v;
            }
        }
        float tmax[4];
        #pragma unroll
        for (int r = 0; r < 4; r++) {
            float t = fmaxf(fmaxf(sc[0][r], sc[1][r]), fmaxf(sc[2][r], sc[3][r]));
            #pragma unroll
            for (int o = 1; o < 16; o <<= 1) t = fmaxf(t, __shfl_xor(t, o));
            tmax[r] = t;
        }
        float p[4][4];
        #pragma unroll
        for (int r = 0; r < 4; r++) {
            float mnew = fmaxf(m_i[r], tmax[r]);
            float alpha = __expf(m_i[r] - mnew);
            float su = 0.f;
            #pragma unroll
            for (int nf = 0; nf < 4; nf++) { p[nf][r] = __expf(sc[nf][r] - mnew); su += p[nf][r]; }
            #pragma unroll
            for (int o = 1; o < 16; o <<= 1) su += __shfl_xor(su, o);
            l_i[r] = l_i[r] * alpha + su;
            m_i[r] = mnew;
            #pragma unroll
            for (int nf = 0; nf < 4; nf++) acc_o[nf][r] *= alpha;
        }
        // P transpose through per-wave LDS rows (no cross-wave sharing; in-order
        // per-wave DS pipe). wave_barrier pins compiler ordering.
        #pragma unroll
        for (int nf = 0; nf < 4; nf++)
            #pragma unroll
            for (int r = 0; r < 4; r++)
                s_p[wave * 16 + quad * 4 + r][nf * 16 + l16] = f2b(p[nf][r]);
        __builtin_amdgcn_wave_barrier();
        s16x8 pa[2];
        pa[0] = *(s16x8*)&s_p[wave * 16 + l16][quad * 8];
        pa[1] = *(s16x8*)&s_p[wave * 16 + l16][32 + quad * 8];
        __builtin_amdgcn_wave_barrier();

        #pragma unroll
        for (int ks = 0; ks < 2; ks++) {
            #pragma unroll
            for (int nf = 0; nf < 4; nf++) {
                s16x8 bb = *(s16x8*)&s_vt[nf * 16 + l16][ks * 32 + quad * 8];
                acc_o[nf] = __builtin_amdgcn_mfma_f32_16x16x32_bf16(pa[ks], bb, acc_o[nf], 0, 0, 0);
            }
        }
    }

    float rm = rmask[b * 8 + h];
    int qrow = qt * 64 + wave * 16 + quad * 4;
    #pragma unroll
    for (int r = 0; r < 4; r++) {
        float scale = rm / l_i[r];
        u16* dst = ctx + (size_t)(b * SEQ + qrow + r) * DIM + h * DK;
        #pragma unroll
        for (int nf = 0; nf < 4; nf++)
            dst[nf * 16 + l16] = f2b(acc_o[nf][r] * scale);
    }
}

// ---- row q==0: uniform 1/SEQ over ALL keys; coalesced reads from vT ----
__global__ __launch_bounds__(256) void attn_row0(
    const u16* __restrict__ vT, const float* __restrict__ rmask, u16* __restrict__ ctx)
{
    int bh = blockIdx.x;
    int b = bh >> 3, h = bh & 7;
    int d = threadIdx.x >> 2, seg = threadIdx.x & 3;
    const u16* src = vT + ((size_t)bh * DK + d) * SEQ + seg * 128;
    float s = 0.f;
    for (int i = 0; i < 16; i++) {
        u16x8 v = *(const u16x8*)(src + i * 8);
        #pragma unroll
        for (int j = 0; j < 8; j++) s += b2f(v[j]);
    }
    s += __shfl_down(s, 1);
    s += __shfl_down(s, 2);
    if (seg == 0)
        ctx[(size_t)(b * SEQ) * DIM + h * DK + d] =
            f2b(s * (1.0f / (float)SEQ) * rmask[b * 8 + h]);
}

// ---- x = LN(x + p0 + p1 + bias_col), also emit bf16 copy ----
__global__ __launch_bounds__(256) void add_ln2(
    float* __restrict__ x, const float* __restrict__ p0, const float* __restrict__ p1,
    const float* __restrict__ bcol,
    const float* __restrict__ g, const float* __restrict__ bta,
    u16* __restrict__ out16)
{
    __shared__ float redA[4], redB[4];
    int row = blockIdx.x, tid = threadIdx.x;
    size_t base = (size_t)row * DIM;
    float t0 = x[base + tid]       + p0[base + tid]       + p1[base + tid]       + bcol[tid];
    float t1 = x[base + tid + 256] + p0[base + tid + 256] + p1[base + tid + 256] + bcol[tid + 256];
    float s = t0 + t1, sq = t0 * t0 + t1 * t1;
    for (int o = 32; o > 0; o >>= 1) { s += __shfl_down(s, o, 64); sq += __shfl_down(sq, o, 64); }
    int lane = tid & 63, wid = tid >> 6;
    if (lane == 0) { redA[wid] = s; redB[wid] = sq; }
    __syncthreads();
    float S1 = redA[0] + redA[1] + redA[2] + redA[3];
    float S2 = redB[0] + redB[1] + redB[2] + redB[3];
    float mu = S1 * (1.0f / (float)DIM);
    float var = S2 * (1.0f / (float)DIM) - mu * mu;
    float rstd = rsqrtf(var + 1e-5f);
    float o0 = g[tid]       * (t0 - mu) * rstd + bta[tid];
    float o1 = g[tid + 256] * (t1 - mu) * rstd + bta[tid + 256];
    x[base + tid]       = o0;
    x[base + tid + 256] = o1;
    out16[base + tid]       = f2b(o0);
    out16[base + tid + 256] = f2b(o1);
}

// ---------------- host side ----------------
extern "C" void kernel_launch(void* const* d_in, const int* in_sizes, int n_in,
                              void* d_out, int out_size, void* d_ws, size_t ws_size,
                              hipStream_t stream) {
    const float* qe   = (const float*)d_in[0];
    const float* ie   = (const float*)d_in[1];
    const float* wq   = (const float*)d_in[2];
    const float* bq   = (const float*)d_in[3];
    const float* wv   = (const float*)d_in[4];
    const float* bv   = (const float*)d_in[5];
    const float* wo   = (const float*)d_in[6];
    const float* bo   = (const float*)d_in[7];
    const float* wg   = (const float*)d_in[8];
    const float* ln1g = (const float*)d_in[9];
    const float* ln1b = (const float*)d_in[10];
    const float* fw1  = (const float*)d_in[11];
    const float* fb1  = (const float*)d_in[12];
    const float* fw2  = (const float*)d_in[13];
    const float* fb2  = (const float*)d_in[14];
    const float* ln2g = (const float*)d_in[15];
    const float* ln2b = (const float*)d_in[16];

    const size_t RD = (size_t)NROWS * DIM;     // 4,194,304
    float* ws   = (float*)d_ws;
    float* xbuf = ws;                          // question residual (fp32)
    float* ybuf = ws + RD;                     // knowledge residual (fp32)

    u16* b16    = (u16*)(ws + 2 * RD);
    u16* x16    = b16;                 b16 += RD;
    u16* y16    = b16;                 b16 += RD;
    u16* ctx16  = b16;                 b16 += RD;
    u16* qlin16 = b16;                 b16 += RD;
    u16* vbuf16 = b16;                 b16 += RD;
    u16* vT     = b16;                 b16 += RD;
    float* proj0 = (float*)vbuf16;              // 16.8 MiB overlay: vbuf16+vT (dead after attn)
    u16* hid    = b16;                 b16 += 4 * RD;   // 8192x2048 bf16, dedicated
    float* proj1 = (float*)b16;        b16 += 2 * RD;   // 8192x512 fp32 split-K partial
    u16* wqvT   = b16;                 b16 += 6 * (size_t)1024 * 512;
    u16* woT    = b16;                 b16 += 6 * (size_t)512 * 512;
    u16* fw1T   = b16;                 b16 += 2 * (size_t)DFF2 * 512;
    u16* fw2T   = b16;                 b16 += 2 * (size_t)512 * DFF2;
    float* rmask6 = (float*)b16;                // 6*128 floats

    const size_t nBytes = RD * sizeof(float);
    hipMemcpyAsync(xbuf, qe, nBytes, hipMemcpyDeviceToDevice, stream);
    hipMemcpyAsync(ybuf, ie, nBytes, hipMemcpyDeviceToDevice, stream);
    cast_f2b4<<<(int)(RD / 4 / 256), 256, 0, stream>>>(qe, x16, (int)(RD / 4));
    cast_f2b4<<<(int)(RD / 4 / 256), 256, 0, stream>>>(ie, y16, (int)(RD / 4));

    transpose_cast<<<dim3(16, 16, 6), 256, 0, stream>>>(wq, wqvT,             512, 512, 0, 1, (size_t)1024 * 512);
    transpose_cast<<<dim3(16, 16, 6), 256, 0, stream>>>(wv, wqvT + 512 * 512, 512, 512, 0, 1, (size_t)1024 * 512);
    transpose_cast<<<dim3(16, 16, 6), 256, 0, stream>>>(wo, woT,              512, 512, 0, 1, (size_t)512 * 512);
    transpose_cast<<<dim3(16, 64, 2), 256, 0, stream>>>(fw1, fw1T, 512, DFF2, 3, 2, (size_t)DFF2 * 512);
    transpose_cast<<<dim3(64, 16, 2), 256, 0, stream>>>(fw2, fw2T, DFF2, 512, 3, 2, (size_t)512 * DFF2);
    init_rmask6<<<3, 256, 0, stream>>>(rmask6);

    const int BIG = 1 << 30;
    auto run_block = [&](float* xr, u16* xq16, const u16* xv16, int l, int maskf, int pos) {
        size_t lD = (size_t)l * DIM;
        float* rm = rmask6 + l * 128;
        // q|v fused: N=1024, 64-col tiles -> nx=16, 1024 blocks (4/CU)
        gemm2<1, 0, 1, 0, 2><<<1024, 256, 0, stream>>>(
            xq16, xv16, wqvT + (size_t)l * 1024 * 512, bq + lD, bv + lD,
            qlin16, vbuf16, 512, 512, 512, 512, 512, 16);
        transpose_v<<<dim3(8, 128), 256, 0, stream>>>(vbuf16, vT);
        router_kernel<<<NROWS / 8, 256, 0, stream>>>(qlin16, wg + (size_t)l * DIM * 6, rm);
        attn_flash<<<1024, 256, 0, stream>>>(qlin16, vT, rm, ctx16, maskf);
        attn_row0<<<128, 256, 0, stream>>>(vT, rm, ctx16);
        // wo proj: N=512 nx=8, split-K x2 (Khalf=256) -> 1024 blocks; fp32 partials
        gemm2<0, 0, 0, 1, 2><<<1024, 256, 0, stream>>>(
            ctx16, ctx16, woT + (size_t)l * 512 * 512, nullptr, nullptr,
            proj0, proj1, 256, 512, 512, 512, BIG, 8);
        add_ln2<<<NROWS, 256, 0, stream>>>(xr, proj0, proj1, bo + lD,
                                           ln1g + lD, ln1b + lD, xq16);
        if (pos) {
            int slot = (l - 3) / 2;
            // fw1 full-width: N=2048 nx=32 -> 2048 blocks; relu, bf16 out
            gemm2<1, 1, 0, 0, 2><<<2048, 256, 0, stream>>>(
                xq16, xq16, fw1T + (size_t)slot * DFF2 * 512,
                fb1 + (size_t)l * DFF2, nullptr,
                hid, nullptr, 512, 512, 512, DFF2, BIG, 32);
            // fw2: N=512 nx=8, K=2048 split-K x2 (Khalf=1024) -> 1024 blocks
            gemm2<0, 0, 0, 1, 2><<<1024, 256, 0, stream>>>(
                hid, hid, fw2T + (size_t)slot * 512 * DFF2, nullptr, nullptr,
                proj0, proj1, 1024, DFF2, DFF2, 512, BIG, 8);
            add_ln2<<<NROWS, 256, 0, stream>>>(xr, proj0, proj1, fb2 + lD,
                                               ln2g + lD, ln2b + lD, xq16);
        }
    };

    run_block(ybuf, y16, y16, 0, 1, 0);
    run_block(ybuf, y16, y16, 1, 1, 0);
    run_block(xbuf, x16, x16, 2, 1, 0);
    run_block(xbuf, x16, y16, 3, 0, 1);
    run_block(xbuf, x16, x16, 4, 1, 0);
    run_block(xbuf, x16, y16, 5, 0, 1);

    hipMemcpyAsync(d_out, xbuf, nBytes, hipMemcpyDeviceToDevice, stream);
}

// Round 8
// 872.336 us; speedup vs baseline: 1.2514x; 1.0253x over previous
//
#include <hip/hip_runtime.h>
#include <hip/hip_bf16.h>

#define BSZ 16
#define SEQ 512
#define DIM 512
#define NH 8
#define DK 64
#define NROWS (BSZ*SEQ)   // 8192
#define DFF2 2048

typedef unsigned short u16;
typedef u16   u16x8 __attribute__((ext_vector_type(8)));
typedef short s16x8 __attribute__((ext_vector_type(8)));
typedef float f32x4 __attribute__((ext_vector_type(4)));

__device__ __forceinline__ u16 f2b(float x) {
    union { float f; unsigned int u; } c; c.f = x;
    unsigned int r = c.u + 0x7fff + ((c.u >> 16) & 1);   // RNE
    return (u16)(r >> 16);
}
__device__ __forceinline__ float b2f(u16 u) {
    union { unsigned int i; float f; } c; c.i = ((unsigned int)u) << 16; return c.f;
}

// async global->LDS, 16B per lane. LDS dest = wave-uniform base + lane*16.
__device__ __forceinline__ void gld16(const u16* g, u16* l) {
    __builtin_amdgcn_global_load_lds(
        (const __attribute__((address_space(1))) unsigned int*)(unsigned long long)g,
        (__attribute__((address_space(3))) unsigned int*)(unsigned int)(unsigned long long)l,
        16, 0, 0);
}

// ---- fused residual-copy + cast: fcopy = in (fp32), out = bf16(in) ----
__global__ __launch_bounds__(256) void cast_dual(const float* __restrict__ in,
                                                 float* __restrict__ fcopy,
                                                 u16* __restrict__ out, int n4) {
    int i = blockIdx.x * 256 + threadIdx.x;
    if (i >= n4) return;
    float4 v = ((const float4*)in)[i];
    ((float4*)fcopy)[i] = v;
    ushort4 o; o.x = f2b(v.x); o.y = f2b(v.y); o.z = f2b(v.z); o.w = f2b(v.w);
    ((ushort4*)out)[i] = o;
}

// ---- transpose + cast weights: dest[z][N][K](bf16) from W[layer0+z*lstride][K][N](fp32) ----
__global__ __launch_bounds__(256) void transpose_cast(
    const float* __restrict__ W, u16* __restrict__ WT,
    int K, int N, int layer0, int lstride, size_t dstride)
{
    __shared__ float t[32][33];
    int z = blockIdx.z;
    const float* Wz = W + (size_t)(layer0 + z * lstride) * K * N;
    u16* WTz = WT + (size_t)z * dstride;
    int k0 = blockIdx.x * 32, n0 = blockIdx.y * 32;
    int tx = threadIdx.x & 31, ty = threadIdx.x >> 5;
    for (int i = ty; i < 32; i += 8) t[i][tx] = Wz[(size_t)(k0 + i) * N + n0 + tx];
    __syncthreads();
    for (int i = ty; i < 32; i += 8) WTz[(size_t)(n0 + i) * K + k0 + tx] = f2b(t[tx][i]);
}

// ---- MFMA GEMM. C[M,N] = A[M,K] @ WT[N,K]^T (+bias). Tile 128 x (NI*32), BK=32,
// double-buffered LDS, XCD-chunked 1-D grid swizzle.
// SPLIT : col-tiles with n0 >= nsplit use Av/bias2/C2 (fused q|v).
// SPLITK: grid doubled; second half computes k-slice 1 (A/WT + K) into C2
//         (bf16 partials; bias added later in add_ln2). K param = per-slice K.
// NI    : 2 -> 64-col tiles (more blocks/CU), 4 -> 128-col tiles.
template<int WRITE_BF16, int RELU, int SPLIT, int SPLITK, int NI>
__global__ __launch_bounds__(256) void gemm2(
    const u16* __restrict__ Aq, const u16* __restrict__ Av,
    const u16* __restrict__ WT,
    const float* __restrict__ bias1, const float* __restrict__ bias2,
    void* __restrict__ C1, void* __restrict__ C2,
    int K, int lda, int ldw, int ldc, int nsplit, int nx)
{
    __shared__ __attribute__((aligned(16))) u16 As[2][128 * 32];
    __shared__ __attribute__((aligned(16))) u16 Bs[2][NI * 32 * 32];
    int tid = threadIdx.x;
    int wave = tid >> 6, lane = tid & 63;
    int quad = lane >> 4, l16 = lane & 15;

    // XCD-chunked swizzle over the whole 1-D grid
    int bid = blockIdx.x;
    int per = gridDim.x >> 3;
    int swz = (bid & 7) * per + (bid >> 3);
    int nxy = SPLITK ? ((int)gridDim.x >> 1) : (int)gridDim.x;
    int kslice = 0;
    if (SPLITK && swz >= nxy) { kslice = 1; swz -= nxy; }
    int bx = swz % nx, by = swz / nx;
    int n0 = bx * (NI * 32), m0 = by * 128;

    int wrow = (wave & 1) * 64;
    int wcol = (wave >> 1) * (NI * 16);
    bool isv = SPLIT && (n0 >= nsplit);
    const u16* A = isv ? Av : Aq;

    // A staging: wave w covers rows [w*32, w*32+32); 2 gld16 of 16 rows each
    int sr = wave * 32 + (lane >> 2);
    int sc = (lane & 3) * 8;
    int ko = kslice * K;                     // k-slice base (elements)
    const u16* gA0 = A  + (size_t)(m0 + sr) * lda + sc + ko;
    const u16* gA1 = gA0 + (size_t)16 * lda;
    int lo0 = (wave * 32) * 32;
    int lo1 = (wave * 32 + 16) * 32;

    // B staging
    const u16* gB0;
    const u16* gB1 = nullptr;
    int bo0, bo1 = 0;
    if (NI == 4) {                           // 128-row B tile: like A
        gB0 = WT + (size_t)(n0 + sr) * ldw + sc + ko;
        gB1 = gB0 + (size_t)16 * ldw;
        bo0 = lo0; bo1 = lo1;
    } else {                                 // 64-row B tile: 1 gld16/wave (16 rows)
        gB0 = WT + (size_t)(n0 + wave * 16 + (lane >> 2)) * ldw + sc + ko;
        bo0 = (wave * 16) * 32;
    }

    f32x4 acc[4][NI];
    #pragma unroll
    for (int i = 0; i < 4; i++)
        #pragma unroll
        for (int j = 0; j < NI; j++) acc[i][j] = (f32x4){0.f, 0.f, 0.f, 0.f};

    // prologue: stage k-tile 0 into buf 0
    gld16(gA0, &As[0][lo0]);
    gld16(gA1, &As[0][lo1]);
    gld16(gB0, &Bs[0][bo0]);
    if (NI == 4) gld16(gB1, &Bs[0][bo1]);
    __syncthreads();

    int NT = K >> 5;
    int cur = 0;
    for (int t = 0; t < NT; ++t) {
        if (t + 1 < NT) {                    // prefetch next tile into other buffer
            int k0 = (t + 1) << 5;
            gld16(gA0 + k0, &As[cur ^ 1][lo0]);
            gld16(gA1 + k0, &As[cur ^ 1][lo1]);
            gld16(gB0 + k0, &Bs[cur ^ 1][bo0]);
            if (NI == 4) gld16(gB1 + k0, &Bs[cur ^ 1][bo1]);
        }
        s16x8 af[4], bf[NI];
        #pragma unroll
        for (int i = 0; i < 4; i++)
            af[i] = *(s16x8*)&As[cur][(wrow + i * 16 + l16) * 32 + quad * 8];
        #pragma unroll
        for (int i = 0; i < NI; i++)
            bf[i] = *(s16x8*)&Bs[cur][(wcol + i * 16 + l16) * 32 + quad * 8];
        #pragma unroll
        for (int mi = 0; mi < 4; mi++)
            #pragma unroll
            for (int ni = 0; ni < NI; ni++)
                acc[mi][ni] = __builtin_amdgcn_mfma_f32_16x16x32_bf16(
                    af[mi], bf[ni], acc[mi][ni], 0, 0, 0);
        __syncthreads();                     // drains prefetch loads + frag reads
        cur ^= 1;
    }

    const float* bias = isv ? bias2 : bias1;
    void* C = (isv || (SPLITK && kslice)) ? C2 : C1;
    int nb = n0 - (isv ? nsplit : 0);
    #pragma unroll
    for (int ni = 0; ni < NI; ni++) {
        int cn = nb + wcol + ni * 16 + l16;
        float bb = bias ? bias[cn] : 0.f;
        #pragma unroll
        for (int mi = 0; mi < 4; mi++) {
            int cm = m0 + wrow + mi * 16 + quad * 4;
            #pragma unroll
            for (int r = 0; r < 4; r++) {
                size_t off = (size_t)(cm + r) * ldc + cn;
                float v = acc[mi][ni][r] + bb;
                if (RELU) v = fmaxf(v, 0.f);
                if (WRITE_BF16) ((u16*)C)[off] = f2b(v);
                else            ((float*)C)[off] = v;
            }
        }
    }
}

// ---- rmask init for all 6 layers: [l][b][h], shared heads = 1, routed = 0 ----
__global__ void init_rmask6(float* __restrict__ r) {
    int t = blockIdx.x * 256 + threadIdx.x;
    if (t < 6 * 128) r[t] = ((t & 7) < 2) ? 1.0f : 0.0f;
}

// ---- router: 32 lanes per row, 8 rows/block. wg staged in LDS, chunk-skewed. ----
__global__ __launch_bounds__(256) void router_kernel(
    const u16* __restrict__ qlin, const float* __restrict__ wg,
    float* __restrict__ rmask)
{
    __shared__ float s_wg[6 * 544];     // 13056 B
    __shared__ float sacc[8];
    int tid = threadIdx.x;
    #pragma unroll
    for (int k = 0; k < 12; k++) {
        int n = tid + k * 256;          // 0..3071
        int d = n / 6, r = n - d * 6;
        s_wg[r * 544 + (d >> 4) * 17 + (d & 15)] = wg[n];
    }
    if (tid < 8) sacc[tid] = 0.f;
    __syncthreads();

    int c = tid & 31;                   // chunk within row
    int row = blockIdx.x * 8 + (tid >> 5);
    int cb = c * 17;
    const u16* xr = qlin + (size_t)row * DIM + c * 16;
    u16x8 q0 = *(const u16x8*)xr;
    u16x8 q1 = *(const u16x8*)(xr + 8);

    float lg[6] = {0.f, 0.f, 0.f, 0.f, 0.f, 0.f};
    #pragma unroll
    for (int j = 0; j < 8; j++) {
        float x = b2f(q0[j]);
        #pragma unroll
        for (int r = 0; r < 6; r++) lg[r] += x * s_wg[r * 544 + cb + j];
    }
    #pragma unroll
    for (int j = 0; j < 8; j++) {
        float x = b2f(q1[j]);
        #pragma unroll
        for (int r = 0; r < 6; r++) lg[r] += x * s_wg[r * 544 + cb + 8 + j];
    }
    #pragma unroll
    for (int r = 0; r < 6; r++) {
        #pragma unroll
        for (int o = 1; o < 32; o <<= 1) lg[r] += __shfl_xor(lg[r], o);
    }
    float m = lg[0];
    #pragma unroll
    for (int r = 1; r < 6; r++) m = fmaxf(m, lg[r]);
    float s = 0.f;
    #pragma unroll
    for (int r = 0; r < 6; r++) { lg[r] = __expf(lg[r] - m); s += lg[r]; }
    float inv = 1.0f / s;
    #pragma unroll
    for (int r = 0; r < 6; r++) lg[r] *= inv;
    int i1 = 0; float g1 = lg[0];
    #pragma unroll
    for (int r = 1; r < 6; r++) if (lg[r] > g1) { g1 = lg[r]; i1 = r; }
    int i2 = -1; float g2 = -1.f;
    #pragma unroll
    for (int r = 0; r < 6; r++) if (r != i1 && lg[r] > g2) { g2 = lg[r]; i2 = r; }
    if (c == 0) {
        atomicAdd(&sacc[i1], g1);
        atomicAdd(&sacc[i2], g2);
    }
    __syncthreads();
    if (tid < 6) {
        int b = blockIdx.x >> 6;        // 64 blocks per batch
        atomicAdd(&rmask[b * 8 + 2 + tid], sacc[tid] * (1.0f / (float)SEQ));
    }
}

// ---- per-layer V transpose: vT[b][h][d][j] from v[(b,j)][h*64+d] ----
__global__ __launch_bounds__(256) void transpose_v(
    const u16* __restrict__ v, u16* __restrict__ vT)
{
    __shared__ u16 t[64][72];
    int jt = blockIdx.x, bh = blockIdx.y;
    int b = bh >> 3, h = bh & 7;
    int tid = threadIdx.x;
    int lr = tid >> 2, lc = (tid & 3) * 16;
    const u16* src = v + (size_t)(b * SEQ + jt * 64 + lr) * DIM + h * DK + lc;
    *(u16x8*)&t[lr][lc]     = *(const u16x8*)src;
    *(u16x8*)&t[lr][lc + 8] = *(const u16x8*)(src + 8);
    __syncthreads();
    u16x8 o0, o1;
    #pragma unroll
    for (int i = 0; i < 8; i++) o0[i] = t[lc + i][lr];
    #pragma unroll
    for (int i = 0; i < 8; i++) o1[i] = t[lc + 8 + i][lr];
    u16* dst = vT + ((size_t)bh * DK + lr) * SEQ + jt * 64 + lc;
    *(u16x8*)dst       = o0;
    *(u16x8*)(dst + 8) = o1;
}

// ---- MFMA flash attention v3: LDS-staged (coalesced, 16x reuse) + XCD-chunked
// 1-D grid + T14 async-STAGE split (jt+1 loads issued before jt compute).
// Q fragments hoisted to registers (jt-invariant).
__global__ __launch_bounds__(256) void attn_flash(
    const u16* __restrict__ qlin, const u16* __restrict__ vT,
    const float* __restrict__ rmask, u16* __restrict__ ctx, int mask_flag)
{
    __shared__ u16 s_k [64][72];
    __shared__ u16 s_vt[64][72];   // [d][j]
    __shared__ u16 s_p [64][72];
    int gi = (blockIdx.x & 7) * ((int)gridDim.x >> 3) + (blockIdx.x >> 3);
    int qt = gi & 7, h = (gi >> 3) & 7, b = gi >> 6;
    int tid = threadIdx.x;
    int wave = tid >> 6, lane = tid & 63;
    int quad = lane >> 4, l16 = lane & 15;
    int lr = tid >> 2, lc = (tid & 3) * 16;

    const u16* qbase = qlin + (size_t)(b * SEQ) * DIM + h * DK;   // [s][d]
    const u16* vbase = vT + (size_t)(b * NH + h) * DK * SEQ;      // [d][j]

    // Q fragments hoisted to registers (jt-invariant)
    s16x8 aq[2];
    #pragma unroll
    for (int ks = 0; ks < 2; ks++)
        aq[ks] = *(const s16x8*)(qbase + (size_t)(qt * 64 + wave * 16 + l16) * DIM
                                 + ks * 32 + quad * 8);

    // stage registers for jt=0 (coalesced 16B x2 per thread)
    const u16* ks0 = qbase + (size_t)lr * DIM + lc;
    const u16* vs0 = vbase + (size_t)lr * SEQ + lc;
    u16x8 k0 = *(const u16x8*)ks0, k1 = *(const u16x8*)(ks0 + 8);
    u16x8 v0 = *(const u16x8*)vs0, v1 = *(const u16x8*)(vs0 + 8);

    f32x4 acc_o[4];
    #pragma unroll
    for (int i = 0; i < 4; i++) acc_o[i] = (f32x4){0.f, 0.f, 0.f, 0.f};
    float m_i[4] = {-1e30f, -1e30f, -1e30f, -1e30f};
    float l_i[4] = {0.f, 0.f, 0.f, 0.f};

    for (int jt = 0; jt <= qt; jt++) {
        __syncthreads();               // prior iter's s_k/s_vt frag reads done
        *(u16x8*)&s_k[lr][lc]      = k0;
        *(u16x8*)&s_k[lr][lc + 8]  = k1;
        *(u16x8*)&s_vt[lr][lc]     = v0;
        *(u16x8*)&s_vt[lr][lc + 8] = v1;
        __syncthreads();               // staging visible
        if (jt < qt) {                 // T14: issue next tile's loads NOW;
            const u16* kn = qbase + (size_t)((jt + 1) * 64 + lr) * DIM + lc;
            const u16* vn = vbase + (size_t)lr * SEQ + (jt + 1) * 64 + lc;
            k0 = *(const u16x8*)kn;  k1 = *(const u16x8*)(kn + 8);   // latency hides
            v0 = *(const u16x8*)vn;  v1 = *(const u16x8*)(vn + 8);   // under compute
        }

        f32x4 acc_s[4];
        #pragma unroll
        for (int i = 0; i < 4; i++) acc_s[i] = (f32x4){0.f, 0.f, 0.f, 0.f};
        #pragma unroll
        for (int ks = 0; ks < 2; ks++) {
            #pragma unroll
            for (int nf = 0; nf < 4; nf++) {
                s16x8 bb = *(s16x8*)&s_k[nf * 16 + l16][ks * 32 + quad * 8];
                acc_s[nf] = __builtin_amdgcn_mfma_f32_16x16x32_bf16(aq[ks], bb, acc_s[nf], 0, 0, 0);
            }
        }

        int qg0 = qt * 64 + wave * 16 + quad * 4;
        float sc[4][4];
        #pragma unroll
        for (int nf = 0; nf < 4; nf++) {
            int jg = jt * 64 + nf * 16 + l16;
            #pragma unroll
            for (int r = 0; r < 4; r++) {
                float v = acc_s[nf][r] * 0.125f;
                if (jt == qt) {
                    int bound = mask_flag ? (qg0 + r) : (qg0 + r - 1);
                    if (jg > bound) v = -1e30f;
                }
                sc[nf][r] = v;
            }
        }
        float tmax[4];
        #pragma unroll
        for (int r = 0; r < 4; r++) {
            float t = fmaxf(fmaxf(sc[0][r], sc[1][r]), fmaxf(sc[2][r], sc[3][r]));
            #pragma unroll
            for (int o = 1; o < 16; o <<= 1) t = fmaxf(t, __shfl_xor(t, o));
            tmax[r] = t;
        }
        float p[4][4];
        #pragma unroll
        for (int r = 0; r < 4; r++) {
            float mnew = fmaxf(m_i[r], tmax[r]);
            float alpha = __expf(m_i[r] - mnew);
            float su = 0.f;
            #pragma unroll
            for (int nf = 0; nf < 4; nf++) { p[nf][r] = __expf(sc[nf][r] - mnew); su += p[nf][r]; }
            #pragma unroll
            for (int o = 1; o < 16; o <<= 1) su += __shfl_xor(su, o);
            l_i[r] = l_i[r] * alpha + su;
            m_i[r] = mnew;
            #pragma unroll
            for (int nf = 0; nf < 4; nf++) acc_o[nf][r] *= alpha;
        }
        // P transpose through per-wave LDS rows (no cross-wave sharing; in-order
        // per-wave DS pipe). wave_barrier pins compiler ordering.
        #pragma unroll
        for (int nf = 0; nf < 4; nf++)
            #pragma unroll
            for (int r = 0; r < 4; r++)
                s_p[wave * 16 + quad * 4 + r][nf * 16 + l16] = f2b(p[nf][r]);
        __builtin_amdgcn_wave_barrier();
        s16x8 pa[2];
        pa[0] = *(s16x8*)&s_p[wave * 16 + l16][quad * 8];
        pa[1] = *(s16x8*)&s_p[wave * 16 + l16][32 + quad * 8];
        __builtin_amdgcn_wave_barrier();

        #pragma unroll
        for (int ks = 0; ks < 2; ks++) {
            #pragma unroll
            for (int nf = 0; nf < 4; nf++) {
                s16x8 bb = *(s16x8*)&s_vt[nf * 16 + l16][ks * 32 + quad * 8];
                acc_o[nf] = __builtin_amdgcn_mfma_f32_16x16x32_bf16(pa[ks], bb, acc_o[nf], 0, 0, 0);
            }
        }
    }

    float rm = rmask[b * 8 + h];
    int qrow = qt * 64 + wave * 16 + quad * 4;
    #pragma unroll
    for (int r = 0; r < 4; r++) {
        float scale = rm / l_i[r];
        u16* dst = ctx + (size_t)(b * SEQ + qrow + r) * DIM + h * DK;
        #pragma unroll
        for (int nf = 0; nf < 4; nf++)
            dst[nf * 16 + l16] = f2b(acc_o[nf][r] * scale);
    }
}

// ---- row q==0: uniform 1/SEQ over ALL keys; coalesced reads from vT ----
__global__ __launch_bounds__(256) void attn_row0(
    const u16* __restrict__ vT, const float* __restrict__ rmask, u16* __restrict__ ctx)
{
    int bh = blockIdx.x;
    int b = bh >> 3, h = bh & 7;
    int d = threadIdx.x >> 2, seg = threadIdx.x & 3;
    const u16* src = vT + ((size_t)bh * DK + d) * SEQ + seg * 128;
    float s = 0.f;
    for (int i = 0; i < 16; i++) {
        u16x8 v = *(const u16x8*)(src + i * 8);
        #pragma unroll
        for (int j = 0; j < 8; j++) s += b2f(v[j]);
    }
    s += __shfl_down(s, 1);
    s += __shfl_down(s, 2);
    if (seg == 0)
        ctx[(size_t)(b * SEQ) * DIM + h * DK + d] =
            f2b(s * (1.0f / (float)SEQ) * rmask[b * 8 + h]);
}

// ---- x = LN(x + p0 + p1 + bias_col), p0/p1 bf16 partials; emit bf16 copy ----
__global__ __launch_bounds__(256) void add_ln2(
    float* __restrict__ x, const u16* __restrict__ p0, const u16* __restrict__ p1,
    const float* __restrict__ bcol,
    const float* __restrict__ g, const float* __restrict__ bta,
    u16* __restrict__ out16)
{
    __shared__ float redA[4], redB[4];
    int row = blockIdx.x, tid = threadIdx.x;
    size_t base = (size_t)row * DIM;
    float t0 = x[base + tid]       + b2f(p0[base + tid])       + b2f(p1[base + tid])       + bcol[tid];
    float t1 = x[base + tid + 256] + b2f(p0[base + tid + 256]) + b2f(p1[base + tid + 256]) + bcol[tid + 256];
    float s = t0 + t1, sq = t0 * t0 + t1 * t1;
    for (int o = 32; o > 0; o >>= 1) { s += __shfl_down(s, o, 64); sq += __shfl_down(sq, o, 64); }
    int lane = tid & 63, wid = tid >> 6;
    if (lane == 0) { redA[wid] = s; redB[wid] = sq; }
    __syncthreads();
    float S1 = redA[0] + redA[1] + redA[2] + redA[3];
    float S2 = redB[0] + redB[1] + redB[2] + redB[3];
    float mu = S1 * (1.0f / (float)DIM);
    float var = S2 * (1.0f / (float)DIM) - mu * mu;
    float rstd = rsqrtf(var + 1e-5f);
    float o0 = g[tid]       * (t0 - mu) * rstd + bta[tid];
    float o1 = g[tid + 256] * (t1 - mu) * rstd + bta[tid + 256];
    x[base + tid]       = o0;
    x[base + tid + 256] = o1;
    out16[base + tid]       = f2b(o0);
    out16[base + tid + 256] = f2b(o1);
}

// ---------------- host side ----------------
extern "C" void kernel_launch(void* const* d_in, const int* in_sizes, int n_in,
                              void* d_out, int out_size, void* d_ws, size_t ws_size,
                              hipStream_t stream) {
    const float* qe   = (const float*)d_in[0];
    const float* ie   = (const float*)d_in[1];
    const float* wq   = (const float*)d_in[2];
    const float* bq   = (const float*)d_in[3];
    const float* wv   = (const float*)d_in[4];
    const float* bv   = (const float*)d_in[5];
    const float* wo   = (const float*)d_in[6];
    const float* bo   = (const float*)d_in[7];
    const float* wg   = (const float*)d_in[8];
    const float* ln1g = (const float*)d_in[9];
    const float* ln1b = (const float*)d_in[10];
    const float* fw1  = (const float*)d_in[11];
    const float* fb1  = (const float*)d_in[12];
    const float* fw2  = (const float*)d_in[13];
    const float* fb2  = (const float*)d_in[14];
    const float* ln2g = (const float*)d_in[15];
    const float* ln2b = (const float*)d_in[16];

    const size_t RD = (size_t)NROWS * DIM;     // 4,194,304
    float* ws   = (float*)d_ws;
    float* xbuf = ws;                          // question residual (fp32)
    float* ybuf = ws + RD;                     // knowledge residual (fp32)

    u16* b16    = (u16*)(ws + 2 * RD);
    u16* x16    = b16;                 b16 += RD;
    u16* y16    = b16;                 b16 += RD;
    u16* ctx16  = b16;                 b16 += RD;
    u16* qlin16 = b16;                 b16 += RD;
    u16* vbuf16 = b16;                 b16 += RD;
    u16* vT     = b16;                 b16 += RD;
    u16* proj0  = vbuf16;                       // overlay: vbuf16 dead after attn
    u16* hid    = b16;                 b16 += 4 * RD;   // 8192x2048 bf16, dedicated
    u16* proj1  = b16;                 b16 += RD;       // bf16 split-K partial
    u16* wqvT   = b16;                 b16 += 6 * (size_t)1024 * 512;
    u16* woT    = b16;                 b16 += 6 * (size_t)512 * 512;
    u16* fw1T   = b16;                 b16 += 2 * (size_t)DFF2 * 512;
    u16* fw2T   = b16;                 b16 += 2 * (size_t)512 * DFF2;
    float* rmask6 = (float*)b16;                // 6*128 floats

    cast_dual<<<(int)(RD / 4 / 256), 256, 0, stream>>>(qe, xbuf, x16, (int)(RD / 4));
    cast_dual<<<(int)(RD / 4 / 256), 256, 0, stream>>>(ie, ybuf, y16, (int)(RD / 4));

    transpose_cast<<<dim3(16, 16, 6), 256, 0, stream>>>(wq, wqvT,             512, 512, 0, 1, (size_t)1024 * 512);
    transpose_cast<<<dim3(16, 16, 6), 256, 0, stream>>>(wv, wqvT + 512 * 512, 512, 512, 0, 1, (size_t)1024 * 512);
    transpose_cast<<<dim3(16, 16, 6), 256, 0, stream>>>(wo, woT,              512, 512, 0, 1, (size_t)512 * 512);
    transpose_cast<<<dim3(16, 64, 2), 256, 0, stream>>>(fw1, fw1T, 512, DFF2, 3, 2, (size_t)DFF2 * 512);
    transpose_cast<<<dim3(64, 16, 2), 256, 0, stream>>>(fw2, fw2T, DFF2, 512, 3, 2, (size_t)512 * DFF2);
    init_rmask6<<<3, 256, 0, stream>>>(rmask6);

    const int BIG = 1 << 30;
    auto run_block = [&](float* xr, u16* xq16, const u16* xv16, int l, int maskf, int pos) {
        size_t lD = (size_t)l * DIM;
        float* rm = rmask6 + l * 128;
        // q|v fused: N=1024, 64-col tiles -> nx=16, 1024 blocks (4/CU)
        gemm2<1, 0, 1, 0, 2><<<1024, 256, 0, stream>>>(
            xq16, xv16, wqvT + (size_t)l * 1024 * 512, bq + lD, bv + lD,
            qlin16, vbuf16, 512, 512, 512, 512, 512, 16);
        transpose_v<<<dim3(8, 128), 256, 0, stream>>>(vbuf16, vT);
        router_kernel<<<NROWS / 8, 256, 0, stream>>>(qlin16, wg + (size_t)l * DIM * 6, rm);
        attn_flash<<<1024, 256, 0, stream>>>(qlin16, vT, rm, ctx16, maskf);
        attn_row0<<<128, 256, 0, stream>>>(vT, rm, ctx16);
        // wo proj: N=512 nx=8, split-K x2 (Khalf=256) -> 1024 blocks; bf16 partials
        gemm2<1, 0, 0, 1, 2><<<1024, 256, 0, stream>>>(
            ctx16, ctx16, woT + (size_t)l * 512 * 512, nullptr, nullptr,
            proj0, proj1, 256, 512, 512, 512, BIG, 8);
        add_ln2<<<NROWS, 256, 0, stream>>>(xr, proj0, proj1, bo + lD,
                                           ln1g + lD, ln1b + lD, xq16);
        if (pos) {
            int slot = (l - 3) / 2;
            // fw1 full-width: N=2048 nx=32 -> 2048 blocks; relu, bf16 out
            gemm2<1, 1, 0, 0, 2><<<2048, 256, 0, stream>>>(
                xq16, xq16, fw1T + (size_t)slot * DFF2 * 512,
                fb1 + (size_t)l * DFF2, nullptr,
                hid, nullptr, 512, 512, 512, DFF2, BIG, 32);
            // fw2: N=512 nx=8, K=2048 split-K x2 (Khalf=1024) -> 1024 blocks; bf16 partials
            gemm2<1, 0, 0, 1, 2><<<1024, 256, 0, stream>>>(
                hid, hid, fw2T + (size_t)slot * 512 * DFF2, nullptr, nullptr,
                proj0, proj1, 1024, DFF2, DFF2, 512, BIG, 8);
            add_ln2<<<NROWS, 256, 0, stream>>>(xr, proj0, proj1, fb2 + lD,
                                               ln2g + lD, ln2b + lD, xq16);
        }
    };

    run_block(ybuf, y16, y16, 0, 1, 0);
    run_block(ybuf, y16, y16, 1, 1, 0);
    run_block(xbuf, x16, x16, 2, 1, 0);
    run_block(xbuf, x16, y16, 3, 0, 1);
    run_block(xbuf, x16, x16, 4, 1, 0);
    run_block(xbuf, x16, y16, 5, 0, 1);

    const size_t nBytes = RD * sizeof(float);
    hipMemcpyAsync(d_out, xbuf, nBytes, hipMemcpyDeviceToDevice, stream);
}

// Round 9
// 841.202 us; speedup vs baseline: 1.2977x; 1.0370x over previous
//
#include <hip/hip_runtime.h>
#include <hip/hip_bf16.h>

#define BSZ 16
#define SEQ 512
#define DIM 512
#define NH 8
#define DK 64
#define NROWS (BSZ*SEQ)   // 8192
#define DFF2 2048

typedef unsigned short u16;
typedef u16   u16x8 __attribute__((ext_vector_type(8)));
typedef short s16x8 __attribute__((ext_vector_type(8)));
typedef float f32x4 __attribute__((ext_vector_type(4)));

__device__ __forceinline__ u16 f2b(float x) {
    union { float f; unsigned int u; } c; c.f = x;
    unsigned int r = c.u + 0x7fff + ((c.u >> 16) & 1);   // RNE
    return (u16)(r >> 16);
}
__device__ __forceinline__ float b2f(u16 u) {
    union { unsigned int i; float f; } c; c.i = ((unsigned int)u) << 16; return c.f;
}

// async global->LDS, 16B per lane. LDS dest = wave-uniform base + lane*16.
__device__ __forceinline__ void gld16(const u16* g, u16* l) {
    __builtin_amdgcn_global_load_lds(
        (const __attribute__((address_space(1))) unsigned int*)(unsigned long long)g,
        (__attribute__((address_space(3))) unsigned int*)(unsigned int)(unsigned long long)l,
        16, 0, 0);
}

// ---- fused residual-copy + cast: fcopy = in (fp32), out = bf16(in) ----
__global__ __launch_bounds__(256) void cast_dual(const float* __restrict__ in,
                                                 float* __restrict__ fcopy,
                                                 u16* __restrict__ out, int n4) {
    int i = blockIdx.x * 256 + threadIdx.x;
    if (i >= n4) return;
    float4 v = ((const float4*)in)[i];
    ((float4*)fcopy)[i] = v;
    ushort4 o; o.x = f2b(v.x); o.y = f2b(v.y); o.z = f2b(v.z); o.w = f2b(v.w);
    ((ushort4*)out)[i] = o;
}

// ---- transpose + cast weights: dest[z][N][K](bf16) from W[layer0+z*lstride][K][N](fp32) ----
__global__ __launch_bounds__(256) void transpose_cast(
    const float* __restrict__ W, u16* __restrict__ WT,
    int K, int N, int layer0, int lstride, size_t dstride)
{
    __shared__ float t[32][33];
    int z = blockIdx.z;
    const float* Wz = W + (size_t)(layer0 + z * lstride) * K * N;
    u16* WTz = WT + (size_t)z * dstride;
    int k0 = blockIdx.x * 32, n0 = blockIdx.y * 32;
    int tx = threadIdx.x & 31, ty = threadIdx.x >> 5;
    for (int i = ty; i < 32; i += 8) t[i][tx] = Wz[(size_t)(k0 + i) * N + n0 + tx];
    __syncthreads();
    for (int i = ty; i < 32; i += 8) WTz[(size_t)(n0 + i) * K + k0 + tx] = f2b(t[tx][i]);
}

// ---- MFMA GEMM. C[M,N] = A[M,K] @ WT[N,K]^T (+bias). Tile 128 x (NI*32), BK=32,
// double-buffered LDS, XCD-chunked 1-D grid swizzle.
// SPLIT : col-tiles with n0 >= nsplit use Av/bias2/C2 (fused q|v).
// SPLITK: grid doubled; second half computes k-slice 1 (A/WT + K) into C2
//         (bf16 partials; bias added later in add_ln2). K param = per-slice K.
// NI    : 2 -> 64-col tiles (more blocks/CU), 4 -> 128-col tiles.
template<int WRITE_BF16, int RELU, int SPLIT, int SPLITK, int NI>
__global__ __launch_bounds__(256) void gemm2(
    const u16* __restrict__ Aq, const u16* __restrict__ Av,
    const u16* __restrict__ WT,
    const float* __restrict__ bias1, const float* __restrict__ bias2,
    void* __restrict__ C1, void* __restrict__ C2,
    int K, int lda, int ldw, int ldc, int nsplit, int nx)
{
    __shared__ __attribute__((aligned(16))) u16 As[2][128 * 32];
    __shared__ __attribute__((aligned(16))) u16 Bs[2][NI * 32 * 32];
    int tid = threadIdx.x;
    int wave = tid >> 6, lane = tid & 63;
    int quad = lane >> 4, l16 = lane & 15;

    // XCD-chunked swizzle over the whole 1-D grid
    int bid = blockIdx.x;
    int per = gridDim.x >> 3;
    int swz = (bid & 7) * per + (bid >> 3);
    int nxy = SPLITK ? ((int)gridDim.x >> 1) : (int)gridDim.x;
    int kslice = 0;
    if (SPLITK && swz >= nxy) { kslice = 1; swz -= nxy; }
    int bx = swz % nx, by = swz / nx;
    int n0 = bx * (NI * 32), m0 = by * 128;

    int wrow = (wave & 1) * 64;
    int wcol = (wave >> 1) * (NI * 16);
    bool isv = SPLIT && (n0 >= nsplit);
    const u16* A = isv ? Av : Aq;

    // A staging: wave w covers rows [w*32, w*32+32); 2 gld16 of 16 rows each
    int sr = wave * 32 + (lane >> 2);
    int sc = (lane & 3) * 8;
    int ko = kslice * K;                     // k-slice base (elements)
    const u16* gA0 = A  + (size_t)(m0 + sr) * lda + sc + ko;
    const u16* gA1 = gA0 + (size_t)16 * lda;
    int lo0 = (wave * 32) * 32;
    int lo1 = (wave * 32 + 16) * 32;

    // B staging
    const u16* gB0;
    const u16* gB1 = nullptr;
    int bo0, bo1 = 0;
    if (NI == 4) {                           // 128-row B tile: like A
        gB0 = WT + (size_t)(n0 + sr) * ldw + sc + ko;
        gB1 = gB0 + (size_t)16 * ldw;
        bo0 = lo0; bo1 = lo1;
    } else {                                 // 64-row B tile: 1 gld16/wave (16 rows)
        gB0 = WT + (size_t)(n0 + wave * 16 + (lane >> 2)) * ldw + sc + ko;
        bo0 = (wave * 16) * 32;
    }

    f32x4 acc[4][NI];
    #pragma unroll
    for (int i = 0; i < 4; i++)
        #pragma unroll
        for (int j = 0; j < NI; j++) acc[i][j] = (f32x4){0.f, 0.f, 0.f, 0.f};

    // prologue: stage k-tile 0 into buf 0
    gld16(gA0, &As[0][lo0]);
    gld16(gA1, &As[0][lo1]);
    gld16(gB0, &Bs[0][bo0]);
    if (NI == 4) gld16(gB1, &Bs[0][bo1]);
    __syncthreads();

    int NT = K >> 5;
    int cur = 0;
    for (int t = 0; t < NT; ++t) {
        if (t + 1 < NT) {                    // prefetch next tile into other buffer
            int k0 = (t + 1) << 5;
            gld16(gA0 + k0, &As[cur ^ 1][lo0]);
            gld16(gA1 + k0, &As[cur ^ 1][lo1]);
            gld16(gB0 + k0, &Bs[cur ^ 1][bo0]);
            if (NI == 4) gld16(gB1 + k0, &Bs[cur ^ 1][bo1]);
        }
        s16x8 af[4], bf[NI];
        #pragma unroll
        for (int i = 0; i < 4; i++)
            af[i] = *(s16x8*)&As[cur][(wrow + i * 16 + l16) * 32 + quad * 8];
        #pragma unroll
        for (int i = 0; i < NI; i++)
            bf[i] = *(s16x8*)&Bs[cur][(wcol + i * 16 + l16) * 32 + quad * 8];
        #pragma unroll
        for (int mi = 0; mi < 4; mi++)
            #pragma unroll
            for (int ni = 0; ni < NI; ni++)
                acc[mi][ni] = __builtin_amdgcn_mfma_f32_16x16x32_bf16(
                    af[mi], bf[ni], acc[mi][ni], 0, 0, 0);
        __syncthreads();                     // drains prefetch loads + frag reads
        cur ^= 1;
    }

    const float* bias = isv ? bias2 : bias1;
    void* C = (isv || (SPLITK && kslice)) ? C2 : C1;
    int nb = n0 - (isv ? nsplit : 0);
    #pragma unroll
    for (int ni = 0; ni < NI; ni++) {
        int cn = nb + wcol + ni * 16 + l16;
        float bb = bias ? bias[cn] : 0.f;
        #pragma unroll
        for (int mi = 0; mi < 4; mi++) {
            int cm = m0 + wrow + mi * 16 + quad * 4;
            #pragma unroll
            for (int r = 0; r < 4; r++) {
                size_t off = (size_t)(cm + r) * ldc + cn;
                float v = acc[mi][ni][r] + bb;
                if (RELU) v = fmaxf(v, 0.f);
                if (WRITE_BF16) ((u16*)C)[off] = f2b(v);
                else            ((float*)C)[off] = v;
            }
        }
    }
}

// ---- rmask init for all 6 layers: [l][b][h], shared heads = 1, routed = 0 ----
__global__ void init_rmask6(float* __restrict__ r) {
    int t = blockIdx.x * 256 + threadIdx.x;
    if (t < 6 * 128) r[t] = ((t & 7) < 2) ? 1.0f : 0.0f;
}

// ---- router: 32 lanes per row, 8 rows/block. wg staged in LDS, chunk-skewed. ----
__global__ __launch_bounds__(256) void router_kernel(
    const u16* __restrict__ qlin, const float* __restrict__ wg,
    float* __restrict__ rmask)
{
    __shared__ float s_wg[6 * 544];     // 13056 B
    __shared__ float sacc[8];
    int tid = threadIdx.x;
    #pragma unroll
    for (int k = 0; k < 12; k++) {
        int n = tid + k * 256;          // 0..3071
        int d = n / 6, r = n - d * 6;
        s_wg[r * 544 + (d >> 4) * 17 + (d & 15)] = wg[n];
    }
    if (tid < 8) sacc[tid] = 0.f;
    __syncthreads();

    int c = tid & 31;                   // chunk within row
    int row = blockIdx.x * 8 + (tid >> 5);
    int cb = c * 17;
    const u16* xr = qlin + (size_t)row * DIM + c * 16;
    u16x8 q0 = *(const u16x8*)xr;
    u16x8 q1 = *(const u16x8*)(xr + 8);

    float lg[6] = {0.f, 0.f, 0.f, 0.f, 0.f, 0.f};
    #pragma unroll
    for (int j = 0; j < 8; j++) {
        float x = b2f(q0[j]);
        #pragma unroll
        for (int r = 0; r < 6; r++) lg[r] += x * s_wg[r * 544 + cb + j];
    }
    #pragma unroll
    for (int j = 0; j < 8; j++) {
        float x = b2f(q1[j]);
        #pragma unroll
        for (int r = 0; r < 6; r++) lg[r] += x * s_wg[r * 544 + cb + 8 + j];
    }
    #pragma unroll
    for (int r = 0; r < 6; r++) {
        #pragma unroll
        for (int o = 1; o < 32; o <<= 1) lg[r] += __shfl_xor(lg[r], o);
    }
    float m = lg[0];
    #pragma unroll
    for (int r = 1; r < 6; r++) m = fmaxf(m, lg[r]);
    float s = 0.f;
    #pragma unroll
    for (int r = 0; r < 6; r++) { lg[r] = __expf(lg[r] - m); s += lg[r]; }
    float inv = 1.0f / s;
    #pragma unroll
    for (int r = 0; r < 6; r++) lg[r] *= inv;
    int i1 = 0; float g1 = lg[0];
    #pragma unroll
    for (int r = 1; r < 6; r++) if (lg[r] > g1) { g1 = lg[r]; i1 = r; }
    int i2 = -1; float g2 = -1.f;
    #pragma unroll
    for (int r = 0; r < 6; r++) if (r != i1 && lg[r] > g2) { g2 = lg[r]; i2 = r; }
    if (c == 0) {
        atomicAdd(&sacc[i1], g1);
        atomicAdd(&sacc[i2], g2);
    }
    __syncthreads();
    if (tid < 6) {
        int b = blockIdx.x >> 6;        // 64 blocks per batch
        atomicAdd(&rmask[b * 8 + 2 + tid], sacc[tid] * (1.0f / (float)SEQ));
    }
}

// ---- per-layer V transpose: vT[b][h][d][j] from v[(b,j)][h*64+d] ----
__global__ __launch_bounds__(256) void transpose_v(
    const u16* __restrict__ v, u16* __restrict__ vT)
{
    __shared__ u16 t[64][72];
    int jt = blockIdx.x, bh = blockIdx.y;
    int b = bh >> 3, h = bh & 7;
    int tid = threadIdx.x;
    int lr = tid >> 2, lc = (tid & 3) * 16;
    const u16* src = v + (size_t)(b * SEQ + jt * 64 + lr) * DIM + h * DK + lc;
    *(u16x8*)&t[lr][lc]     = *(const u16x8*)src;
    *(u16x8*)&t[lr][lc + 8] = *(const u16x8*)(src + 8);
    __syncthreads();
    u16x8 o0, o1;
    #pragma unroll
    for (int i = 0; i < 8; i++) o0[i] = t[lc + i][lr];
    #pragma unroll
    for (int i = 0; i < 8; i++) o1[i] = t[lc + 8 + i][lr];
    u16* dst = vT + ((size_t)bh * DK + lr) * SEQ + jt * 64 + lc;
    *(u16x8*)dst       = o0;
    *(u16x8*)(dst + 8) = o1;
}

// ---- MFMA flash attention v4: QBLK=128, 8 waves (512 thr). Each wave owns 16
// q-rows (per-thread code identical to v3); 8 waves share each staged K/V tile
// -> staged bytes/FLOP halve, barrier-iterations drop 3.6x (1024x4.5 -> 512x2.5).
// Waves fully below a key tile skip the compute body (exact identity: alpha=1,
// su=0); barriers stay outside the branch. T14 prefetch + XCD chunk retained.
__global__ __launch_bounds__(512) void attn_flash(
    const u16* __restrict__ qlin, const u16* __restrict__ vT,
    const float* __restrict__ rmask, u16* __restrict__ ctx, int mask_flag)
{
    __shared__ u16 s_k [64][72];
    __shared__ u16 s_vt[64][72];    // [d][j]
    __shared__ u16 s_p [128][72];
    int gi = (blockIdx.x & 7) * ((int)gridDim.x >> 3) + (blockIdx.x >> 3);
    int qt = gi & 3, h = (gi >> 2) & 7, b = gi >> 5;
    int tid = threadIdx.x;
    int wave = tid >> 6, lane = tid & 63;
    int quad = lane >> 4, l16 = lane & 15;
    int lr = tid >> 3, lc = (tid & 7) * 8;   // staging: 512 thr x 16B = 8KB tile

    const u16* qbase = qlin + (size_t)(b * SEQ) * DIM + h * DK;   // [s][d]
    const u16* vbase = vT + (size_t)(b * NH + h) * DK * SEQ;      // [d][j]

    // Q fragments hoisted to registers (jt-invariant); wave's rows qt*128+wave*16+..
    int qg0 = qt * 128 + wave * 16 + quad * 4;
    s16x8 aq[2];
    #pragma unroll
    for (int ks = 0; ks < 2; ks++)
        aq[ks] = *(const s16x8*)(qbase + (size_t)(qt * 128 + wave * 16 + l16) * DIM
                                 + ks * 32 + quad * 8);

    // stage registers for jt=0
    u16x8 k0 = *(const u16x8*)(qbase + (size_t)lr * DIM + lc);
    u16x8 v0 = *(const u16x8*)(vbase + (size_t)lr * SEQ + lc);

    f32x4 acc_o[4];
    #pragma unroll
    for (int i = 0; i < 4; i++) acc_o[i] = (f32x4){0.f, 0.f, 0.f, 0.f};
    float m_i[4] = {-1e30f, -1e30f, -1e30f, -1e30f};
    float l_i[4] = {0.f, 0.f, 0.f, 0.f};

    int rmax = qt * 128 + wave * 16 + 15;            // wave's last q-row
    int jt_end = 2 * qt + 1;                         // last key tile needed
    for (int jt = 0; jt <= jt_end; jt++) {
        __syncthreads();               // prior iter's s_k/s_vt frag reads done
        *(u16x8*)&s_k [lr][lc] = k0;
        *(u16x8*)&s_vt[lr][lc] = v0;
        __syncthreads();               // staging visible
        if (jt < jt_end) {             // T14: issue next tile's loads NOW
            k0 = *(const u16x8*)(qbase + (size_t)((jt + 1) * 64 + lr) * DIM + lc);
            v0 = *(const u16x8*)(vbase + (size_t)lr * SEQ + (jt + 1) * 64 + lc);
        }

        // wave-uniform skip: tile fully masked for this wave's rows
        bool active = (jt * 64) <= (mask_flag ? rmax : rmax - 1);
        if (active) {
            f32x4 acc_s[4];
            #pragma unroll
            for (int i = 0; i < 4; i++) acc_s[i] = (f32x4){0.f, 0.f, 0.f, 0.f};
            #pragma unroll
            for (int ks = 0; ks < 2; ks++) {
                #pragma unroll
                for (int nf = 0; nf < 4; nf++) {
                    s16x8 bb = *(s16x8*)&s_k[nf * 16 + l16][ks * 32 + quad * 8];
                    acc_s[nf] = __builtin_amdgcn_mfma_f32_16x16x32_bf16(aq[ks], bb, acc_s[nf], 0, 0, 0);
                }
            }

            float sc[4][4];
            #pragma unroll
            for (int nf = 0; nf < 4; nf++) {
                int jg = jt * 64 + nf * 16 + l16;
                #pragma unroll
                for (int r = 0; r < 4; r++) {
                    float v = acc_s[nf][r] * 0.125f;
                    int bound = mask_flag ? (qg0 + r) : (qg0 + r - 1);
                    if (jg > bound) v = -1e30f;     // no-op for fully-allowed tiles
                    sc[nf][r] = v;
                }
            }
            float tmax[4];
            #pragma unroll
            for (int r = 0; r < 4; r++) {
                float t = fmaxf(fmaxf(sc[0][r], sc[1][r]), fmaxf(sc[2][r], sc[3][r]));
                #pragma unroll
                for (int o = 1; o < 16; o <<= 1) t = fmaxf(t, __shfl_xor(t, o));
                tmax[r] = t;
            }
            float p[4][4];
            #pragma unroll
            for (int r = 0; r < 4; r++) {
                float mnew = fmaxf(m_i[r], tmax[r]);
                float alpha = __expf(m_i[r] - mnew);
                float su = 0.f;
                #pragma unroll
                for (int nf = 0; nf < 4; nf++) { p[nf][r] = __expf(sc[nf][r] - mnew); su += p[nf][r]; }
                #pragma unroll
                for (int o = 1; o < 16; o <<= 1) su += __shfl_xor(su, o);
                l_i[r] = l_i[r] * alpha + su;
                m_i[r] = mnew;
                #pragma unroll
                for (int nf = 0; nf < 4; nf++) acc_o[nf][r] *= alpha;
            }
            // P transpose through per-wave LDS rows (rows wave*16..+15 only;
            // in-order per-wave DS pipe; wave_barrier pins compiler ordering)
            #pragma unroll
            for (int nf = 0; nf < 4; nf++)
                #pragma unroll
                for (int r = 0; r < 4; r++)
                    s_p[wave * 16 + quad * 4 + r][nf * 16 + l16] = f2b(p[nf][r]);
            __builtin_amdgcn_wave_barrier();
            s16x8 pa[2];
            pa[0] = *(s16x8*)&s_p[wave * 16 + l16][quad * 8];
            pa[1] = *(s16x8*)&s_p[wave * 16 + l16][32 + quad * 8];
            __builtin_amdgcn_wave_barrier();

            #pragma unroll
            for (int ks = 0; ks < 2; ks++) {
                #pragma unroll
                for (int nf = 0; nf < 4; nf++) {
                    s16x8 bb = *(s16x8*)&s_vt[nf * 16 + l16][ks * 32 + quad * 8];
                    acc_o[nf] = __builtin_amdgcn_mfma_f32_16x16x32_bf16(pa[ks], bb, acc_o[nf], 0, 0, 0);
                }
            }
        }
    }

    float rm = rmask[b * 8 + h];
    int qrow = qt * 128 + wave * 16 + quad * 4;
    #pragma unroll
    for (int r = 0; r < 4; r++) {
        float scale = rm / l_i[r];
        u16* dst = ctx + (size_t)(b * SEQ + qrow + r) * DIM + h * DK;
        #pragma unroll
        for (int nf = 0; nf < 4; nf++)
            dst[nf * 16 + l16] = f2b(acc_o[nf][r] * scale);
    }
}

// ---- row q==0: uniform 1/SEQ over ALL keys; coalesced reads from vT ----
__global__ __launch_bounds__(256) void attn_row0(
    const u16* __restrict__ vT, const float* __restrict__ rmask, u16* __restrict__ ctx)
{
    int bh = blockIdx.x;
    int b = bh >> 3, h = bh & 7;
    int d = threadIdx.x >> 2, seg = threadIdx.x & 3;
    const u16* src = vT + ((size_t)bh * DK + d) * SEQ + seg * 128;
    float s = 0.f;
    for (int i = 0; i < 16; i++) {
        u16x8 v = *(const u16x8*)(src + i * 8);
        #pragma unroll
        for (int j = 0; j < 8; j++) s += b2f(v[j]);
    }
    s += __shfl_down(s, 1);
    s += __shfl_down(s, 2);
    if (seg == 0)
        ctx[(size_t)(b * SEQ) * DIM + h * DK + d] =
            f2b(s * (1.0f / (float)SEQ) * rmask[b * 8 + h]);
}

// ---- x = LN(x + p0 + p1 + bias_col), p0/p1 bf16 partials; emit bf16 copy ----
__global__ __launch_bounds__(256) void add_ln2(
    float* __restrict__ x, const u16* __restrict__ p0, const u16* __restrict__ p1,
    const float* __restrict__ bcol,
    const float* __restrict__ g, const float* __restrict__ bta,
    u16* __restrict__ out16)
{
    __shared__ float redA[4], redB[4];
    int row = blockIdx.x, tid = threadIdx.x;
    size_t base = (size_t)row * DIM;
    float t0 = x[base + tid]       + b2f(p0[base + tid])       + b2f(p1[base + tid])       + bcol[tid];
    float t1 = x[base + tid + 256] + b2f(p0[base + tid + 256]) + b2f(p1[base + tid + 256]) + bcol[tid + 256];
    float s = t0 + t1, sq = t0 * t0 + t1 * t1;
    for (int o = 32; o > 0; o >>= 1) { s += __shfl_down(s, o, 64); sq += __shfl_down(sq, o, 64); }
    int lane = tid & 63, wid = tid >> 6;
    if (lane == 0) { redA[wid] = s; redB[wid] = sq; }
    __syncthreads();
    float S1 = redA[0] + redA[1] + redA[2] + redA[3];
    float S2 = redB[0] + redB[1] + redB[2] + redB[3];
    float mu = S1 * (1.0f / (float)DIM);
    float var = S2 * (1.0f / (float)DIM) - mu * mu;
    float rstd = rsqrtf(var + 1e-5f);
    float o0 = g[tid]       * (t0 - mu) * rstd + bta[tid];
    float o1 = g[tid + 256] * (t1 - mu) * rstd + bta[tid + 256];
    x[base + tid]       = o0;
    x[base + tid + 256] = o1;
    out16[base + tid]       = f2b(o0);
    out16[base + tid + 256] = f2b(o1);
}

// ---------------- host side ----------------
extern "C" void kernel_launch(void* const* d_in, const int* in_sizes, int n_in,
                              void* d_out, int out_size, void* d_ws, size_t ws_size,
                              hipStream_t stream) {
    const float* qe   = (const float*)d_in[0];
    const float* ie   = (const float*)d_in[1];
    const float* wq   = (const float*)d_in[2];
    const float* bq   = (const float*)d_in[3];
    const float* wv   = (const float*)d_in[4];
    const float* bv   = (const float*)d_in[5];
    const float* wo   = (const float*)d_in[6];
    const float* bo   = (const float*)d_in[7];
    const float* wg   = (const float*)d_in[8];
    const float* ln1g = (const float*)d_in[9];
    const float* ln1b = (const float*)d_in[10];
    const float* fw1  = (const float*)d_in[11];
    const float* fb1  = (const float*)d_in[12];
    const float* fw2  = (const float*)d_in[13];
    const float* fb2  = (const float*)d_in[14];
    const float* ln2g = (const float*)d_in[15];
    const float* ln2b = (const float*)d_in[16];

    const size_t RD = (size_t)NROWS * DIM;     // 4,194,304
    float* ws   = (float*)d_ws;
    float* xbuf = ws;                          // question residual (fp32)
    float* ybuf = ws + RD;                     // knowledge residual (fp32)

    u16* b16    = (u16*)(ws + 2 * RD);
    u16* x16    = b16;                 b16 += RD;
    u16* y16    = b16;                 b16 += RD;
    u16* ctx16  = b16;                 b16 += RD;
    u16* qlin16 = b16;                 b16 += RD;
    u16* vbuf16 = b16;                 b16 += RD;
    u16* vT     = b16;                 b16 += RD;
    u16* proj0  = vbuf16;                       // overlay: vbuf16 dead after attn
    u16* hid    = b16;                 b16 += 4 * RD;   // 8192x2048 bf16, dedicated
    u16* proj1  = b16;                 b16 += RD;       // bf16 split-K partial
    u16* wqvT   = b16;                 b16 += 6 * (size_t)1024 * 512;
    u16* woT    = b16;                 b16 += 6 * (size_t)512 * 512;
    u16* fw1T   = b16;                 b16 += 2 * (size_t)DFF2 * 512;
    u16* fw2T   = b16;                 b16 += 2 * (size_t)512 * DFF2;
    float* rmask6 = (float*)b16;                // 6*128 floats

    cast_dual<<<(int)(RD / 4 / 256), 256, 0, stream>>>(qe, xbuf, x16, (int)(RD / 4));
    cast_dual<<<(int)(RD / 4 / 256), 256, 0, stream>>>(ie, ybuf, y16, (int)(RD / 4));

    transpose_cast<<<dim3(16, 16, 6), 256, 0, stream>>>(wq, wqvT,             512, 512, 0, 1, (size_t)1024 * 512);
    transpose_cast<<<dim3(16, 16, 6), 256, 0, stream>>>(wv, wqvT + 512 * 512, 512, 512, 0, 1, (size_t)1024 * 512);
    transpose_cast<<<dim3(16, 16, 6), 256, 0, stream>>>(wo, woT,              512, 512, 0, 1, (size_t)512 * 512);
    transpose_cast<<<dim3(16, 64, 2), 256, 0, stream>>>(fw1, fw1T, 512, DFF2, 3, 2, (size_t)DFF2 * 512);
    transpose_cast<<<dim3(64, 16, 2), 256, 0, stream>>>(fw2, fw2T, DFF2, 512, 3, 2, (size_t)512 * DFF2);
    init_rmask6<<<3, 256, 0, stream>>>(rmask6);

    const int BIG = 1 << 30;
    auto run_block = [&](float* xr, u16* xq16, const u16* xv16, int l, int maskf, int pos) {
        size_t lD = (size_t)l * DIM;
        float* rm = rmask6 + l * 128;
        // q|v fused: N=1024, 64-col tiles -> nx=16, 1024 blocks (4/CU)
        gemm2<1, 0, 1, 0, 2><<<1024, 256, 0, stream>>>(
            xq16, xv16, wqvT + (size_t)l * 1024 * 512, bq + lD, bv + lD,
            qlin16, vbuf16, 512, 512, 512, 512, 512, 16);
        transpose_v<<<dim3(8, 128), 256, 0, stream>>>(vbuf16, vT);
        router_kernel<<<NROWS / 8, 256, 0, stream>>>(qlin16, wg + (size_t)l * DIM * 6, rm);
        attn_flash<<<512, 512, 0, stream>>>(qlin16, vT, rm, ctx16, maskf);
        attn_row0<<<128, 256, 0, stream>>>(vT, rm, ctx16);
        // wo proj: N=512 nx=8, split-K x2 (Khalf=256) -> 1024 blocks; bf16 partials
        gemm2<1, 0, 0, 1, 2><<<1024, 256, 0, stream>>>(
            ctx16, ctx16, woT + (size_t)l * 512 * 512, nullptr, nullptr,
            proj0, proj1, 256, 512, 512, 512, BIG, 8);
        add_ln2<<<NROWS, 256, 0, stream>>>(xr, proj0, proj1, bo + lD,
                                           ln1g + lD, ln1b + lD, xq16);
        if (pos) {
            int slot = (l - 3) / 2;
            // fw1: N=2048, 128-col tiles (NI=4) -> nx=16, 1024 blocks (4/CU)
            gemm2<1, 1, 0, 0, 4><<<1024, 256, 0, stream>>>(
                xq16, xq16, fw1T + (size_t)slot * DFF2 * 512,
                fb1 + (size_t)l * DFF2, nullptr,
                hid, nullptr, 512, 512, 512, DFF2, BIG, 16);
            // fw2: N=512 nx=8, K=2048 split-K x2 (Khalf=1024) -> 1024 blocks; bf16 partials
            gemm2<1, 0, 0, 1, 2><<<1024, 256, 0, stream>>>(
                hid, hid, fw2T + (size_t)slot * 512 * DFF2, nullptr, nullptr,
                proj0, proj1, 1024, DFF2, DFF2, 512, BIG, 8);
            add_ln2<<<NROWS, 256, 0, stream>>>(xr, proj0, proj1, fb2 + lD,
                                               ln2g + lD, ln2b + lD, xq16);
        }
    };

    run_block(ybuf, y16, y16, 0, 1, 0);
    run_block(ybuf, y16, y16, 1, 1, 0);
    run_block(xbuf, x16, x16, 2, 1, 0);
    run_block(xbuf, x16, y16, 3, 0, 1);
    run_block(xbuf, x16, x16, 4, 1, 0);
    run_block(xbuf, x16, y16, 5, 0, 1);

    const size_t nBytes = RD * sizeof(float);
    hipMemcpyAsync(d_out, xbuf, nBytes, hipMemcpyDeviceToDevice, stream);
}

// Round 10
// 837.461 us; speedup vs baseline: 1.3035x; 1.0045x over previous
//
#include <hip/hip_runtime.h>
#include <hip/hip_bf16.h>

#define BSZ 16
#define SEQ 512
#define DIM 512
#define NH 8
#define DK 64
#define NROWS (BSZ*SEQ)   // 8192
#define DFF2 2048

typedef unsigned short u16;
typedef u16   u16x8 __attribute__((ext_vector_type(8)));
typedef short s16x8 __attribute__((ext_vector_type(8)));
typedef float f32x4 __attribute__((ext_vector_type(4)));

__device__ __forceinline__ u16 f2b(float x) {
    union { float f; unsigned int u; } c; c.f = x;
    unsigned int r = c.u + 0x7fff + ((c.u >> 16) & 1);   // RNE
    return (u16)(r >> 16);
}
__device__ __forceinline__ float b2f(u16 u) {
    union { unsigned int i; float f; } c; c.i = ((unsigned int)u) << 16; return c.f;
}

// async global->LDS, 16B per lane. LDS dest = wave-uniform base + lane*16.
__device__ __forceinline__ void gld16(const u16* g, u16* l) {
    __builtin_amdgcn_global_load_lds(
        (const __attribute__((address_space(1))) unsigned int*)(unsigned long long)g,
        (__attribute__((address_space(3))) unsigned int*)(unsigned int)(unsigned long long)l,
        16, 0, 0);
}

// ---- fused residual-copy + cast: fcopy = in (fp32), out = bf16(in) ----
__global__ __launch_bounds__(256) void cast_dual(const float* __restrict__ in,
                                                 float* __restrict__ fcopy,
                                                 u16* __restrict__ out, int n4) {
    int i = blockIdx.x * 256 + threadIdx.x;
    if (i >= n4) return;
    float4 v = ((const float4*)in)[i];
    ((float4*)fcopy)[i] = v;
    ushort4 o; o.x = f2b(v.x); o.y = f2b(v.y); o.z = f2b(v.z); o.w = f2b(v.w);
    ((ushort4*)out)[i] = o;
}

// ---- transpose + cast weights: dest[z][N][K](bf16) from W[layer0+z*lstride][K][N](fp32) ----
__global__ __launch_bounds__(256) void transpose_cast(
    const float* __restrict__ W, u16* __restrict__ WT,
    int K, int N, int layer0, int lstride, size_t dstride)
{
    __shared__ float t[32][33];
    int z = blockIdx.z;
    const float* Wz = W + (size_t)(layer0 + z * lstride) * K * N;
    u16* WTz = WT + (size_t)z * dstride;
    int k0 = blockIdx.x * 32, n0 = blockIdx.y * 32;
    int tx = threadIdx.x & 31, ty = threadIdx.x >> 5;
    for (int i = ty; i < 32; i += 8) t[i][tx] = Wz[(size_t)(k0 + i) * N + n0 + tx];
    __syncthreads();
    for (int i = ty; i < 32; i += 8) WTz[(size_t)(n0 + i) * K + k0 + tx] = f2b(t[tx][i]);
}

// ---- MFMA GEMM. C[M,N] = A[M,K] @ WT[N,K]^T (+bias). Tile 128 x (NI*32), BK=32,
// double-buffered LDS, XCD-chunked 1-D grid swizzle.
// Epilogue: C tile staged through LDS (reusing the As/Bs buffer, dead after the
// K-loop) so global stores are 16B/lane coalesced — the scalar 2B stores caused
// 2x HBM write amplification (partial 64B sectors; r9: WRITE=69MB for 33.5MB out).
// SPLIT : col-tiles with n0 >= nsplit use Av/bias2/C2 (fused q|v).
// SPLITK: grid doubled; second half computes k-slice 1 into C2 (bf16 partials;
//         bias added later in add_ln2). K param = per-slice K.
template<int WRITE_BF16, int RELU, int SPLIT, int SPLITK, int NI>
__global__ __launch_bounds__(256) void gemm2(
    const u16* __restrict__ Aq, const u16* __restrict__ Av,
    const u16* __restrict__ WT,
    const float* __restrict__ bias1, const float* __restrict__ bias2,
    void* __restrict__ C1, void* __restrict__ C2,
    int K, int lda, int ldw, int ldc, int nsplit, int nx)
{
    __shared__ __attribute__((aligned(16))) u16 smem[2 * 128 * 32 + 2 * NI * 32 * 32];
    u16* As = smem;                       // [2][128*32]
    u16* Bs = smem + 2 * 128 * 32;        // [2][NI*32*32]
    int tid = threadIdx.x;
    int wave = tid >> 6, lane = tid & 63;
    int quad = lane >> 4, l16 = lane & 15;

    // XCD-chunked swizzle over the whole 1-D grid
    int bid = blockIdx.x;
    int per = gridDim.x >> 3;
    int swz = (bid & 7) * per + (bid >> 3);
    int nxy = SPLITK ? ((int)gridDim.x >> 1) : (int)gridDim.x;
    int kslice = 0;
    if (SPLITK && swz >= nxy) { kslice = 1; swz -= nxy; }
    int bx = swz % nx, by = swz / nx;
    int n0 = bx * (NI * 32), m0 = by * 128;

    int wrow = (wave & 1) * 64;
    int wcol = (wave >> 1) * (NI * 16);
    bool isv = SPLIT && (n0 >= nsplit);
    const u16* A = isv ? Av : Aq;

    // A staging: wave w covers rows [w*32, w*32+32); 2 gld16 of 16 rows each
    int sr = wave * 32 + (lane >> 2);
    int sc = (lane & 3) * 8;
    int ko = kslice * K;                     // k-slice base (elements)
    const u16* gA0 = A  + (size_t)(m0 + sr) * lda + sc + ko;
    const u16* gA1 = gA0 + (size_t)16 * lda;
    int lo0 = (wave * 32) * 32;
    int lo1 = (wave * 32 + 16) * 32;

    // B staging
    const u16* gB0;
    const u16* gB1 = nullptr;
    int bo0, bo1 = 0;
    if (NI == 4) {                           // 128-row B tile: like A
        gB0 = WT + (size_t)(n0 + sr) * ldw + sc + ko;
        gB1 = gB0 + (size_t)16 * ldw;
        bo0 = lo0; bo1 = lo1;
    } else {                                 // 64-row B tile: 1 gld16/wave (16 rows)
        gB0 = WT + (size_t)(n0 + wave * 16 + (lane >> 2)) * ldw + sc + ko;
        bo0 = (wave * 16) * 32;
    }

    f32x4 acc[4][NI];
    #pragma unroll
    for (int i = 0; i < 4; i++)
        #pragma unroll
        for (int j = 0; j < NI; j++) acc[i][j] = (f32x4){0.f, 0.f, 0.f, 0.f};

    // prologue: stage k-tile 0 into buf 0
    gld16(gA0, &As[lo0]);
    gld16(gA1, &As[lo1]);
    gld16(gB0, &Bs[bo0]);
    if (NI == 4) gld16(gB1, &Bs[bo1]);
    __syncthreads();

    int NT = K >> 5;
    int cur = 0;
    for (int t = 0; t < NT; ++t) {
        if (t + 1 < NT) {                    // prefetch next tile into other buffer
            int k0 = (t + 1) << 5;
            int nxt = cur ^ 1;
            gld16(gA0 + k0, &As[nxt * 128 * 32 + lo0]);
            gld16(gA1 + k0, &As[nxt * 128 * 32 + lo1]);
            gld16(gB0 + k0, &Bs[nxt * NI * 32 * 32 + bo0]);
            if (NI == 4) gld16(gB1 + k0, &Bs[nxt * NI * 32 * 32 + bo1]);
        }
        s16x8 af[4], bf[NI];
        #pragma unroll
        for (int i = 0; i < 4; i++)
            af[i] = *(s16x8*)&As[cur * 128 * 32 + (wrow + i * 16 + l16) * 32 + quad * 8];
        #pragma unroll
        for (int i = 0; i < NI; i++)
            bf[i] = *(s16x8*)&Bs[cur * NI * 32 * 32 + (wcol + i * 16 + l16) * 32 + quad * 8];
        #pragma unroll
        for (int mi = 0; mi < 4; mi++)
            #pragma unroll
            for (int ni = 0; ni < NI; ni++)
                acc[mi][ni] = __builtin_amdgcn_mfma_f32_16x16x32_bf16(
                    af[mi], bf[ni], acc[mi][ni], 0, 0, 0);
        __syncthreads();                     // drains prefetch loads + frag reads
        cur ^= 1;
    }

    const float* bias = isv ? bias2 : bias1;
    void* C = (isv || (SPLITK && kslice)) ? C2 : C1;
    int nb = n0 - (isv ? nsplit : 0);

    if (WRITE_BF16) {
        // ---- coalesced epilogue: acc -> LDS (bias/relu applied) -> 16B stores ----
        const int CSTR = NI * 32 + 8;        // u16 stride; NI=2: 128*72*2=18KB <= 24KB
        u16* Cs = smem;                      // As/Bs dead after final barrier
        #pragma unroll
        for (int ni = 0; ni < NI; ni++) {
            int lc_ = wcol + ni * 16 + l16;
            float bb = bias ? bias[nb + lc_] : 0.f;
            #pragma unroll
            for (int mi = 0; mi < 4; mi++) {
                int lrow = wrow + mi * 16 + quad * 4;
                #pragma unroll
                for (int r = 0; r < 4; r++) {
                    float v = acc[mi][ni][r] + bb;
                    if (RELU) v = fmaxf(v, 0.f);
                    Cs[(lrow + r) * CSTR + lc_] = f2b(v);
                }
            }
        }
        __syncthreads();
        const int CPR = NI * 4;              // 8-u16 chunks per row
        int row = tid / CPR;
        int col = (tid % CPR) * 8;
        #pragma unroll
        for (int i = 0; i < NI * 2; i++) {
            int rr = row + i * (256 / CPR);
            u16x8 vv = *(u16x8*)&Cs[rr * CSTR + col];
            *(u16x8*)((u16*)C + (size_t)(m0 + rr) * ldc + nb + col) = vv;
        }
    } else {
        #pragma unroll
        for (int ni = 0; ni < NI; ni++) {
            int cn = nb + wcol + ni * 16 + l16;
            float bb = bias ? bias[cn] : 0.f;
            #pragma unroll
            for (int mi = 0; mi < 4; mi++) {
                int cm = m0 + wrow + mi * 16 + quad * 4;
                #pragma unroll
                for (int r = 0; r < 4; r++) {
                    size_t off = (size_t)(cm + r) * ldc + cn;
                    float v = acc[mi][ni][r] + bb;
                    if (RELU) v = fmaxf(v, 0.f);
                    ((float*)C)[off] = v;
                }
            }
        }
    }
}

// ---- rmask init for all 6 layers: [l][b][h], shared heads = 1, routed = 0 ----
__global__ void init_rmask6(float* __restrict__ r) {
    int t = blockIdx.x * 256 + threadIdx.x;
    if (t < 6 * 128) r[t] = ((t & 7) < 2) ? 1.0f : 0.0f;
}

// ---- router: 32 lanes per row, 8 rows/block. wg staged in LDS, chunk-skewed. ----
__global__ __launch_bounds__(256) void router_kernel(
    const u16* __restrict__ qlin, const float* __restrict__ wg,
    float* __restrict__ rmask)
{
    __shared__ float s_wg[6 * 544];     // 13056 B
    __shared__ float sacc[8];
    int tid = threadIdx.x;
    #pragma unroll
    for (int k = 0; k < 12; k++) {
        int n = tid + k * 256;          // 0..3071
        int d = n / 6, r = n - d * 6;
        s_wg[r * 544 + (d >> 4) * 17 + (d & 15)] = wg[n];
    }
    if (tid < 8) sacc[tid] = 0.f;
    __syncthreads();

    int c = tid & 31;                   // chunk within row
    int row = blockIdx.x * 8 + (tid >> 5);
    int cb = c * 17;
    const u16* xr = qlin + (size_t)row * DIM + c * 16;
    u16x8 q0 = *(const u16x8*)xr;
    u16x8 q1 = *(const u16x8*)(xr + 8);

    float lg[6] = {0.f, 0.f, 0.f, 0.f, 0.f, 0.f};
    #pragma unroll
    for (int j = 0; j < 8; j++) {
        float x = b2f(q0[j]);
        #pragma unroll
        for (int r = 0; r < 6; r++) lg[r] += x * s_wg[r * 544 + cb + j];
    }
    #pragma unroll
    for (int j = 0; j < 8; j++) {
        float x = b2f(q1[j]);
        #pragma unroll
        for (int r = 0; r < 6; r++) lg[r] += x * s_wg[r * 544 + cb + 8 + j];
    }
    #pragma unroll
    for (int r = 0; r < 6; r++) {
        #pragma unroll
        for (int o = 1; o < 32; o <<= 1) lg[r] += __shfl_xor(lg[r], o);
    }
    float m = lg[0];
    #pragma unroll
    for (int r = 1; r < 6; r++) m = fmaxf(m, lg[r]);
    float s = 0.f;
    #pragma unroll
    for (int r = 0; r < 6; r++) { lg[r] = __expf(lg[r] - m); s += lg[r]; }
    float inv = 1.0f / s;
    #pragma unroll
    for (int r = 0; r < 6; r++) lg[r] *= inv;
    int i1 = 0; float g1 = lg[0];
    #pragma unroll
    for (int r = 1; r < 6; r++) if (lg[r] > g1) { g1 = lg[r]; i1 = r; }
    int i2 = -1; float g2 = -1.f;
    #pragma unroll
    for (int r = 0; r < 6; r++) if (r != i1 && lg[r] > g2) { g2 = lg[r]; i2 = r; }
    if (c == 0) {
        atomicAdd(&sacc[i1], g1);
        atomicAdd(&sacc[i2], g2);
    }
    __syncthreads();
    if (tid < 6) {
        int b = blockIdx.x >> 6;        // 64 blocks per batch
        atomicAdd(&rmask[b * 8 + 2 + tid], sacc[tid] * (1.0f / (float)SEQ));
    }
}

// ---- per-layer V transpose: vT[b][h][d][j] from v[(b,j)][h*64+d] ----
__global__ __launch_bounds__(256) void transpose_v(
    const u16* __restrict__ v, u16* __restrict__ vT)
{
    __shared__ u16 t[64][72];
    int jt = blockIdx.x, bh = blockIdx.y;
    int b = bh >> 3, h = bh & 7;
    int tid = threadIdx.x;
    int lr = tid >> 2, lc = (tid & 3) * 16;
    const u16* src = v + (size_t)(b * SEQ + jt * 64 + lr) * DIM + h * DK + lc;
    *(u16x8*)&t[lr][lc]     = *(const u16x8*)src;
    *(u16x8*)&t[lr][lc + 8] = *(const u16x8*)(src + 8);
    __syncthreads();
    u16x8 o0, o1;
    #pragma unroll
    for (int i = 0; i < 8; i++) o0[i] = t[lc + i][lr];
    #pragma unroll
    for (int i = 0; i < 8; i++) o1[i] = t[lc + 8 + i][lr];
    u16* dst = vT + ((size_t)bh * DK + lr) * SEQ + jt * 64 + lc;
    *(u16x8*)dst       = o0;
    *(u16x8*)(dst + 8) = o1;
}

// ---- MFMA flash attention v4: QBLK=128, 8 waves (512 thr). Each wave owns 16
// q-rows; 8 waves share each staged K/V tile. Wave-uniform skip for fully-masked
// tiles. T14 prefetch + XCD chunk.
__global__ __launch_bounds__(512) void attn_flash(
    const u16* __restrict__ qlin, const u16* __restrict__ vT,
    const float* __restrict__ rmask, u16* __restrict__ ctx, int mask_flag)
{
    __shared__ u16 s_k [64][72];
    __shared__ u16 s_vt[64][72];    // [d][j]
    __shared__ u16 s_p [128][72];
    int gi = (blockIdx.x & 7) * ((int)gridDim.x >> 3) + (blockIdx.x >> 3);
    int qt = gi & 3, h = (gi >> 2) & 7, b = gi >> 5;
    int tid = threadIdx.x;
    int wave = tid >> 6, lane = tid & 63;
    int quad = lane >> 4, l16 = lane & 15;
    int lr = tid >> 3, lc = (tid & 7) * 8;   // staging: 512 thr x 16B = 8KB tile

    const u16* qbase = qlin + (size_t)(b * SEQ) * DIM + h * DK;   // [s][d]
    const u16* vbase = vT + (size_t)(b * NH + h) * DK * SEQ;      // [d][j]

    // Q fragments hoisted to registers (jt-invariant); wave's rows qt*128+wave*16+..
    int qg0 = qt * 128 + wave * 16 + quad * 4;
    s16x8 aq[2];
    #pragma unroll
    for (int ks = 0; ks < 2; ks++)
        aq[ks] = *(const s16x8*)(qbase + (size_t)(qt * 128 + wave * 16 + l16) * DIM
                                 + ks * 32 + quad * 8);

    // stage registers for jt=0
    u16x8 k0 = *(const u16x8*)(qbase + (size_t)lr * DIM + lc);
    u16x8 v0 = *(const u16x8*)(vbase + (size_t)lr * SEQ + lc);

    f32x4 acc_o[4];
    #pragma unroll
    for (int i = 0; i < 4; i++) acc_o[i] = (f32x4){0.f, 0.f, 0.f, 0.f};
    float m_i[4] = {-1e30f, -1e30f, -1e30f, -1e30f};
    float l_i[4] = {0.f, 0.f, 0.f, 0.f};

    int rmax = qt * 128 + wave * 16 + 15;            // wave's last q-row
    int jt_end = 2 * qt + 1;                         // last key tile needed
    for (int jt = 0; jt <= jt_end; jt++) {
        __syncthreads();               // prior iter's s_k/s_vt frag reads done
        *(u16x8*)&s_k [lr][lc] = k0;
        *(u16x8*)&s_vt[lr][lc] = v0;
        __syncthreads();               // staging visible
        if (jt < jt_end) {             // T14: issue next tile's loads NOW
            k0 = *(const u16x8*)(qbase + (size_t)((jt + 1) * 64 + lr) * DIM + lc);
            v0 = *(const u16x8*)(vbase + (size_t)lr * SEQ + (jt + 1) * 64 + lc);
        }

        // wave-uniform skip: tile fully masked for this wave's rows
        bool active = (jt * 64) <= (mask_flag ? rmax : rmax - 1);
        if (active) {
            f32x4 acc_s[4];
            #pragma unroll
            for (int i = 0; i < 4; i++) acc_s[i] = (f32x4){0.f, 0.f, 0.f, 0.f};
            #pragma unroll
            for (int ks = 0; ks < 2; ks++) {
                #pragma unroll
                for (int nf = 0; nf < 4; nf++) {
                    s16x8 bb = *(s16x8*)&s_k[nf * 16 + l16][ks * 32 + quad * 8];
                    acc_s[nf] = __builtin_amdgcn_mfma_f32_16x16x32_bf16(aq[ks], bb, acc_s[nf], 0, 0, 0);
                }
            }

            float sc[4][4];
            #pragma unroll
            for (int nf = 0; nf < 4; nf++) {
                int jg = jt * 64 + nf * 16 + l16;
                #pragma unroll
                for (int r = 0; r < 4; r++) {
                    float v = acc_s[nf][r] * 0.125f;
                    int bound = mask_flag ? (qg0 + r) : (qg0 + r - 1);
                    if (jg > bound) v = -1e30f;     // no-op for fully-allowed tiles
                    sc[nf][r] = v;
                }
            }
            float tmax[4];
            #pragma unroll
            for (int r = 0; r < 4; r++) {
                float t = fmaxf(fmaxf(sc[0][r], sc[1][r]), fmaxf(sc[2][r], sc[3][r]));
                #pragma unroll
                for (int o = 1; o < 16; o <<= 1) t = fmaxf(t, __shfl_xor(t, o));
                tmax[r] = t;
            }
            float p[4][4];
            #pragma unroll
            for (int r = 0; r < 4; r++) {
                float mnew = fmaxf(m_i[r], tmax[r]);
                float alpha = __expf(m_i[r] - mnew);
                float su = 0.f;
                #pragma unroll
                for (int nf = 0; nf < 4; nf++) { p[nf][r] = __expf(sc[nf][r] - mnew); su += p[nf][r]; }
                #pragma unroll
                for (int o = 1; o < 16; o <<= 1) su += __shfl_xor(su, o);
                l_i[r] = l_i[r] * alpha + su;
                m_i[r] = mnew;
                #pragma unroll
                for (int nf = 0; nf < 4; nf++) acc_o[nf][r] *= alpha;
            }
            // P transpose through per-wave LDS rows (rows wave*16..+15 only;
            // in-order per-wave DS pipe; wave_barrier pins compiler ordering)
            #pragma unroll
            for (int nf = 0; nf < 4; nf++)
                #pragma unroll
                for (int r = 0; r < 4; r++)
                    s_p[wave * 16 + quad * 4 + r][nf * 16 + l16] = f2b(p[nf][r]);
            __builtin_amdgcn_wave_barrier();
            s16x8 pa[2];
            pa[0] = *(s16x8*)&s_p[wave * 16 + l16][quad * 8];
            pa[1] = *(s16x8*)&s_p[wave * 16 + l16][32 + quad * 8];
            __builtin_amdgcn_wave_barrier();

            #pragma unroll
            for (int ks = 0; ks < 2; ks++) {
                #pragma unroll
                for (int nf = 0; nf < 4; nf++) {
                    s16x8 bb = *(s16x8*)&s_vt[nf * 16 + l16][ks * 32 + quad * 8];
                    acc_o[nf] = __builtin_amdgcn_mfma_f32_16x16x32_bf16(pa[ks], bb, acc_o[nf], 0, 0, 0);
                }
            }
        }
    }

    float rm = rmask[b * 8 + h];
    int qrow = qt * 128 + wave * 16 + quad * 4;
    #pragma unroll
    for (int r = 0; r < 4; r++) {
        float scale = rm / l_i[r];
        u16* dst = ctx + (size_t)(b * SEQ + qrow + r) * DIM + h * DK;
        #pragma unroll
        for (int nf = 0; nf < 4; nf++)
            dst[nf * 16 + l16] = f2b(acc_o[nf][r] * scale);
    }
}

// ---- row q==0: uniform 1/SEQ over ALL keys; coalesced reads from vT ----
__global__ __launch_bounds__(256) void attn_row0(
    const u16* __restrict__ vT, const float* __restrict__ rmask, u16* __restrict__ ctx)
{
    int bh = blockIdx.x;
    int b = bh >> 3, h = bh & 7;
    int d = threadIdx.x >> 2, seg = threadIdx.x & 3;
    const u16* src = vT + ((size_t)bh * DK + d) * SEQ + seg * 128;
    float s = 0.f;
    for (int i = 0; i < 16; i++) {
        u16x8 v = *(const u16x8*)(src + i * 8);
        #pragma unroll
        for (int j = 0; j < 8; j++) s += b2f(v[j]);
    }
    s += __shfl_down(s, 1);
    s += __shfl_down(s, 2);
    if (seg == 0)
        ctx[(size_t)(b * SEQ) * DIM + h * DK + d] =
            f2b(s * (1.0f / (float)SEQ) * rmask[b * 8 + h]);
}

// ---- x = LN(x + p0 + p1 + bias_col), p0/p1 bf16 partials; emit bf16 copy ----
__global__ __launch_bounds__(256) void add_ln2(
    float* __restrict__ x, const u16* __restrict__ p0, const u16* __restrict__ p1,
    const float* __restrict__ bcol,
    const float* __restrict__ g, const float* __restrict__ bta,
    u16* __restrict__ out16)
{
    __shared__ float redA[4], redB[4];
    int row = blockIdx.x, tid = threadIdx.x;
    size_t base = (size_t)row * DIM;
    float t0 = x[base + tid]       + b2f(p0[base + tid])       + b2f(p1[base + tid])       + bcol[tid];
    float t1 = x[base + tid + 256] + b2f(p0[base + tid + 256]) + b2f(p1[base + tid + 256]) + bcol[tid + 256];
    float s = t0 + t1, sq = t0 * t0 + t1 * t1;
    for (int o = 32; o > 0; o >>= 1) { s += __shfl_down(s, o, 64); sq += __shfl_down(sq, o, 64); }
    int lane = tid & 63, wid = tid >> 6;
    if (lane == 0) { redA[wid] = s; redB[wid] = sq; }
    __syncthreads();
    float S1 = redA[0] + redA[1] + redA[2] + redA[3];
    float S2 = redB[0] + redB[1] + redB[2] + redB[3];
    float mu = S1 * (1.0f / (float)DIM);
    float var = S2 * (1.0f / (float)DIM) - mu * mu;
    float rstd = rsqrtf(var + 1e-5f);
    float o0 = g[tid]       * (t0 - mu) * rstd + bta[tid];
    float o1 = g[tid + 256] * (t1 - mu) * rstd + bta[tid + 256];
    x[base + tid]       = o0;
    x[base + tid + 256] = o1;
    out16[base + tid]       = f2b(o0);
    out16[base + tid + 256] = f2b(o1);
}

// ---------------- host side ----------------
extern "C" void kernel_launch(void* const* d_in, const int* in_sizes, int n_in,
                              void* d_out, int out_size, void* d_ws, size_t ws_size,
                              hipStream_t stream) {
    const float* qe   = (const float*)d_in[0];
    const float* ie   = (const float*)d_in[1];
    const float* wq   = (const float*)d_in[2];
    const float* bq   = (const float*)d_in[3];
    const float* wv   = (const float*)d_in[4];
    const float* bv   = (const float*)d_in[5];
    const float* wo   = (const float*)d_in[6];
    const float* bo   = (const float*)d_in[7];
    const float* wg   = (const float*)d_in[8];
    const float* ln1g = (const float*)d_in[9];
    const float* ln1b = (const float*)d_in[10];
    const float* fw1  = (const float*)d_in[11];
    const float* fb1  = (const float*)d_in[12];
    const float* fw2  = (const float*)d_in[13];
    const float* fb2  = (const float*)d_in[14];
    const float* ln2g = (const float*)d_in[15];
    const float* ln2b = (const float*)d_in[16];

    const size_t RD = (size_t)NROWS * DIM;     // 4,194,304
    float* ws   = (float*)d_ws;
    float* xbuf = ws;                          // question residual (fp32)
    float* ybuf = ws + RD;                     // knowledge residual (fp32)

    u16* b16    = (u16*)(ws + 2 * RD);
    u16* x16    = b16;                 b16 += RD;
    u16* y16    = b16;                 b16 += RD;
    u16* ctx16  = b16;                 b16 += RD;
    u16* qlin16 = b16;                 b16 += RD;
    u16* vbuf16 = b16;                 b16 += RD;
    u16* vT     = b16;                 b16 += RD;
    u16* proj0  = vbuf16;                       // overlay: vbuf16 dead after attn
    u16* hid    = b16;                 b16 += 4 * RD;   // 8192x2048 bf16, dedicated
    u16* proj1  = b16;                 b16 += RD;       // bf16 split-K partial
    u16* wqvT   = b16;                 b16 += 6 * (size_t)1024 * 512;
    u16* woT    = b16;                 b16 += 6 * (size_t)512 * 512;
    u16* fw1T   = b16;                 b16 += 2 * (size_t)DFF2 * 512;
    u16* fw2T   = b16;                 b16 += 2 * (size_t)512 * DFF2;
    float* rmask6 = (float*)b16;                // 6*128 floats

    cast_dual<<<(int)(RD / 4 / 256), 256, 0, stream>>>(qe, xbuf, x16, (int)(RD / 4));
    cast_dual<<<(int)(RD / 4 / 256), 256, 0, stream>>>(ie, ybuf, y16, (int)(RD / 4));

    transpose_cast<<<dim3(16, 16, 6), 256, 0, stream>>>(wq, wqvT,             512, 512, 0, 1, (size_t)1024 * 512);
    transpose_cast<<<dim3(16, 16, 6), 256, 0, stream>>>(wv, wqvT + 512 * 512, 512, 512, 0, 1, (size_t)1024 * 512);
    transpose_cast<<<dim3(16, 16, 6), 256, 0, stream>>>(wo, woT,              512, 512, 0, 1, (size_t)512 * 512);
    transpose_cast<<<dim3(16, 64, 2), 256, 0, stream>>>(fw1, fw1T, 512, DFF2, 3, 2, (size_t)DFF2 * 512);
    transpose_cast<<<dim3(64, 16, 2), 256, 0, stream>>>(fw2, fw2T, DFF2, 512, 3, 2, (size_t)512 * DFF2);
    init_rmask6<<<3, 256, 0, stream>>>(rmask6);

    const int BIG = 1 << 30;
    auto run_block = [&](float* xr, u16* xq16, const u16* xv16, int l, int maskf, int pos) {
        size_t lD = (size_t)l * DIM;
        float* rm = rmask6 + l * 128;
        // q|v fused: N=1024, 64-col tiles -> nx=16, 1024 blocks (4/CU)
        gemm2<1, 0, 1, 0, 2><<<1024, 256, 0, stream>>>(
            xq16, xv16, wqvT + (size_t)l * 1024 * 512, bq + lD, bv + lD,
            qlin16, vbuf16, 512, 512, 512, 512, 512, 16);
        transpose_v<<<dim3(8, 128), 256, 0, stream>>>(vbuf16, vT);
        router_kernel<<<NROWS / 8, 256, 0, stream>>>(qlin16, wg + (size_t)l * DIM * 6, rm);
        attn_flash<<<512, 512, 0, stream>>>(qlin16, vT, rm, ctx16, maskf);
        attn_row0<<<128, 256, 0, stream>>>(vT, rm, ctx16);
        // wo proj: N=512 nx=8, split-K x2 (Khalf=256) -> 1024 blocks; bf16 partials
        gemm2<1, 0, 0, 1, 2><<<1024, 256, 0, stream>>>(
            ctx16, ctx16, woT + (size_t)l * 512 * 512, nullptr, nullptr,
            proj0, proj1, 256, 512, 512, 512, BIG, 8);
        add_ln2<<<NROWS, 256, 0, stream>>>(xr, proj0, proj1, bo + lD,
                                           ln1g + lD, ln1b + lD, xq16);
        if (pos) {
            int slot = (l - 3) / 2;
            // fw1: N=2048, 64-col tiles (NI=2) -> nx=32, 2048 blocks (8/CU; r9
            // NI=4@1024 regressed 49.5us vs <41 -> reverted)
            gemm2<1, 1, 0, 0, 2><<<2048, 256, 0, stream>>>(
                xq16, xq16, fw1T + (size_t)slot * DFF2 * 512,
                fb1 + (size_t)l * DFF2, nullptr,
                hid, nullptr, 512, 512, 512, DFF2, BIG, 32);
            // fw2: N=512 nx=8, K=2048 split-K x2 (Khalf=1024) -> 1024 blocks; bf16 partials
            gemm2<1, 0, 0, 1, 2><<<1024, 256, 0, stream>>>(
                hid, hid, fw2T + (size_t)slot * 512 * DFF2, nullptr, nullptr,
                proj0, proj1, 1024, DFF2, DFF2, 512, BIG, 8);
            add_ln2<<<NROWS, 256, 0, stream>>>(xr, proj0, proj1, fb2 + lD,
                                               ln2g + lD, ln2b + lD, xq16);
        }
    };

    run_block(ybuf, y16, y16, 0, 1, 0);
    run_block(ybuf, y16, y16, 1, 1, 0);
    run_block(xbuf, x16, x16, 2, 1, 0);
    run_block(xbuf, x16, y16, 3, 0, 1);
    run_block(xbuf, x16, x16, 4, 1, 0);
    run_block(xbuf, x16, y16, 5, 0, 1);

    const size_t nBytes = RD * sizeof(float);
    hipMemcpyAsync(d_out, xbuf, nBytes, hipMemcpyDeviceToDevice, stream);
}

// Round 11
// 816.098 us; speedup vs baseline: 1.3376x; 1.0262x over previous
//
#include <hip/hip_runtime.h>
#include <hip/hip_bf16.h>

#define BSZ 16
#define SEQ 512
#define DIM 512
#define NH 8
#define DK 64
#define NROWS (BSZ*SEQ)   // 8192
#define DFF2 2048

typedef unsigned short u16;
typedef u16   u16x8 __attribute__((ext_vector_type(8)));
typedef u16   u16x4 __attribute__((ext_vector_type(4)));
typedef short s16x8 __attribute__((ext_vector_type(8)));
typedef float f32x4 __attribute__((ext_vector_type(4)));

__device__ __forceinline__ u16 f2b(float x) {
    union { float f; unsigned int u; } c; c.f = x;
    unsigned int r = c.u + 0x7fff + ((c.u >> 16) & 1);   // RNE
    return (u16)(r >> 16);
}
__device__ __forceinline__ float b2f(u16 u) {
    union { unsigned int i; float f; } c; c.i = ((unsigned int)u) << 16; return c.f;
}

// async global->LDS, 16B per lane. LDS dest = wave-uniform base + lane*16.
__device__ __forceinline__ void gld16(const u16* g, u16* l) {
    __builtin_amdgcn_global_load_lds(
        (const __attribute__((address_space(1))) unsigned int*)(unsigned long long)g,
        (__attribute__((address_space(3))) unsigned int*)(unsigned int)(unsigned long long)l,
        16, 0, 0);
}

// ---- fused residual-copy + cast: fcopy = in (fp32), out = bf16(in) ----
__global__ __launch_bounds__(256) void cast_dual(const float* __restrict__ in,
                                                 float* __restrict__ fcopy,
                                                 u16* __restrict__ out, int n4) {
    int i = blockIdx.x * 256 + threadIdx.x;
    if (i >= n4) return;
    float4 v = ((const float4*)in)[i];
    ((float4*)fcopy)[i] = v;
    ushort4 o; o.x = f2b(v.x); o.y = f2b(v.y); o.z = f2b(v.z); o.w = f2b(v.w);
    ((ushort4*)out)[i] = o;
}

// ---- transpose + cast weights: dest[z][N][K](bf16) from W[layer0+z*lstride][K][N](fp32) ----
__global__ __launch_bounds__(256) void transpose_cast(
    const float* __restrict__ W, u16* __restrict__ WT,
    int K, int N, int layer0, int lstride, size_t dstride)
{
    __shared__ float t[32][33];
    int z = blockIdx.z;
    const float* Wz = W + (size_t)(layer0 + z * lstride) * K * N;
    u16* WTz = WT + (size_t)z * dstride;
    int k0 = blockIdx.x * 32, n0 = blockIdx.y * 32;
    int tx = threadIdx.x & 31, ty = threadIdx.x >> 5;
    for (int i = ty; i < 32; i += 8) t[i][tx] = Wz[(size_t)(k0 + i) * N + n0 + tx];
    __syncthreads();
    for (int i = ty; i < 32; i += 8) WTz[(size_t)(n0 + i) * K + k0 + tx] = f2b(t[tx][i]);
}

// ---- MFMA GEMM. C[M,N] = A[M,K] @ WT[N,K]^T (+bias). Tile 128 x (NI*32), BK=32,
// double-buffered LDS, XCD-chunked 1-D grid swizzle.
// Epilogue: bf16 C staged through LDS for 16B coalesced stores.
// SPLIT : col-tiles with n0 >= nsplit use Av/bias2/C2 (fused q|v).
// VT    : (with SPLIT) V col-tiles store TRANSPOSED direct from acc into
//         C2 = vT[(b*8+h)*64+d][j] as u16x4 (8B) — replaces the transpose_v
//         kernel; values bit-identical (tile width 64 = one head, m-tile 128
//         = one batch slice). 8B partial sectors merge in L2 (1MB/XCD slice).
// SPLITK: grid doubled; second half computes k-slice 1 into C2 (bf16 partials;
//         bias added later in add_ln2). K param = per-slice K.
template<int WRITE_BF16, int RELU, int SPLIT, int SPLITK, int NI, int VT>
__global__ __launch_bounds__(256) void gemm2(
    const u16* __restrict__ Aq, const u16* __restrict__ Av,
    const u16* __restrict__ WT,
    const float* __restrict__ bias1, const float* __restrict__ bias2,
    void* __restrict__ C1, void* __restrict__ C2,
    int K, int lda, int ldw, int ldc, int nsplit, int nx)
{
    __shared__ __attribute__((aligned(16))) u16 smem[2 * 128 * 32 + 2 * NI * 32 * 32];
    u16* As = smem;                       // [2][128*32]
    u16* Bs = smem + 2 * 128 * 32;        // [2][NI*32*32]
    int tid = threadIdx.x;
    int wave = tid >> 6, lane = tid & 63;
    int quad = lane >> 4, l16 = lane & 15;

    // XCD-chunked swizzle over the whole 1-D grid
    int bid = blockIdx.x;
    int per = gridDim.x >> 3;
    int swz = (bid & 7) * per + (bid >> 3);
    int nxy = SPLITK ? ((int)gridDim.x >> 1) : (int)gridDim.x;
    int kslice = 0;
    if (SPLITK && swz >= nxy) { kslice = 1; swz -= nxy; }
    int bx = swz % nx, by = swz / nx;
    int n0 = bx * (NI * 32), m0 = by * 128;

    int wrow = (wave & 1) * 64;
    int wcol = (wave >> 1) * (NI * 16);
    bool isv = SPLIT && (n0 >= nsplit);
    const u16* A = isv ? Av : Aq;

    // A staging: wave w covers rows [w*32, w*32+32); 2 gld16 of 16 rows each
    int sr = wave * 32 + (lane >> 2);
    int sc = (lane & 3) * 8;
    int ko = kslice * K;                     // k-slice base (elements)
    const u16* gA0 = A  + (size_t)(m0 + sr) * lda + sc + ko;
    const u16* gA1 = gA0 + (size_t)16 * lda;
    int lo0 = (wave * 32) * 32;
    int lo1 = (wave * 32 + 16) * 32;

    // B staging
    const u16* gB0;
    const u16* gB1 = nullptr;
    int bo0, bo1 = 0;
    if (NI == 4) {                           // 128-row B tile: like A
        gB0 = WT + (size_t)(n0 + sr) * ldw + sc + ko;
        gB1 = gB0 + (size_t)16 * ldw;
        bo0 = lo0; bo1 = lo1;
    } else {                                 // 64-row B tile: 1 gld16/wave (16 rows)
        gB0 = WT + (size_t)(n0 + wave * 16 + (lane >> 2)) * ldw + sc + ko;
        bo0 = (wave * 16) * 32;
    }

    f32x4 acc[4][NI];
    #pragma unroll
    for (int i = 0; i < 4; i++)
        #pragma unroll
        for (int j = 0; j < NI; j++) acc[i][j] = (f32x4){0.f, 0.f, 0.f, 0.f};

    // prologue: stage k-tile 0 into buf 0
    gld16(gA0, &As[lo0]);
    gld16(gA1, &As[lo1]);
    gld16(gB0, &Bs[bo0]);
    if (NI == 4) gld16(gB1, &Bs[bo1]);
    __syncthreads();

    int NT = K >> 5;
    int cur = 0;
    for (int t = 0; t < NT; ++t) {
        if (t + 1 < NT) {                    // prefetch next tile into other buffer
            int k0 = (t + 1) << 5;
            int nxt = cur ^ 1;
            gld16(gA0 + k0, &As[nxt * 128 * 32 + lo0]);
            gld16(gA1 + k0, &As[nxt * 128 * 32 + lo1]);
            gld16(gB0 + k0, &Bs[nxt * NI * 32 * 32 + bo0]);
            if (NI == 4) gld16(gB1 + k0, &Bs[nxt * NI * 32 * 32 + bo1]);
        }
        s16x8 af[4], bf[NI];
        #pragma unroll
        for (int i = 0; i < 4; i++)
            af[i] = *(s16x8*)&As[cur * 128 * 32 + (wrow + i * 16 + l16) * 32 + quad * 8];
        #pragma unroll
        for (int i = 0; i < NI; i++)
            bf[i] = *(s16x8*)&Bs[cur * NI * 32 * 32 + (wcol + i * 16 + l16) * 32 + quad * 8];
        #pragma unroll
        for (int mi = 0; mi < 4; mi++)
            #pragma unroll
            for (int ni = 0; ni < NI; ni++)
                acc[mi][ni] = __builtin_amdgcn_mfma_f32_16x16x32_bf16(
                    af[mi], bf[ni], acc[mi][ni], 0, 0, 0);
        __syncthreads();                     // drains prefetch loads + frag reads
        cur ^= 1;
    }

    if (VT && isv) {
        // direct transposed V store: vT[(b*8+h)*64+d][j], d = (n0-nsplit)+lc_,
        // j = m0%512 + row-in-tile. u16x4 (8B aligned) per 4 consecutive j.
        int bI = m0 >> 9, j0 = m0 & 511;
        u16* dst = (u16*)C2 + ((size_t)(bI * NH * DK) + (n0 - nsplit)) * SEQ + j0;
        #pragma unroll
        for (int ni = 0; ni < NI; ni++) {
            int lc_ = wcol + ni * 16 + l16;          // 0..63 within head
            float bb = bias2[(n0 - nsplit) + lc_];
            #pragma unroll
            for (int mi = 0; mi < 4; mi++) {
                int jj = wrow + mi * 16 + quad * 4;
                u16x4 tv;
                #pragma unroll
                for (int r = 0; r < 4; r++) tv[r] = f2b(acc[mi][ni][r] + bb);
                *(u16x4*)(dst + (size_t)lc_ * SEQ + jj) = tv;
            }
        }
        return;
    }

    const float* bias = isv ? bias2 : bias1;
    void* C = (isv || (SPLITK && kslice)) ? C2 : C1;
    int nb = n0 - (isv ? nsplit : 0);

    if (WRITE_BF16) {
        // ---- coalesced epilogue: acc -> LDS (bias/relu applied) -> 16B stores ----
        const int CSTR = NI * 32 + 8;        // u16 stride; NI=2: 128*72*2=18KB <= 24KB
        u16* Cs = smem;                      // As/Bs dead after final barrier
        #pragma unroll
        for (int ni = 0; ni < NI; ni++) {
            int lc_ = wcol + ni * 16 + l16;
            float bb = bias ? bias[nb + lc_] : 0.f;
            #pragma unroll
            for (int mi = 0; mi < 4; mi++) {
                int lrow = wrow + mi * 16 + quad * 4;
                #pragma unroll
                for (int r = 0; r < 4; r++) {
                    float v = acc[mi][ni][r] + bb;
                    if (RELU) v = fmaxf(v, 0.f);
                    Cs[(lrow + r) * CSTR + lc_] = f2b(v);
                }
            }
        }
        __syncthreads();
        const int CPR = NI * 4;              // 8-u16 chunks per row
        int row = tid / CPR;
        int col = (tid % CPR) * 8;
        #pragma unroll
        for (int i = 0; i < NI * 2; i++) {
            int rr = row + i * (256 / CPR);
            u16x8 vv = *(u16x8*)&Cs[rr * CSTR + col];
            *(u16x8*)((u16*)C + (size_t)(m0 + rr) * ldc + nb + col) = vv;
        }
    } else {
        #pragma unroll
        for (int ni = 0; ni < NI; ni++) {
            int cn = nb + wcol + ni * 16 + l16;
            float bb = bias ? bias[cn] : 0.f;
            #pragma unroll
            for (int mi = 0; mi < 4; mi++) {
                int cm = m0 + wrow + mi * 16 + quad * 4;
                #pragma unroll
                for (int r = 0; r < 4; r++) {
                    size_t off = (size_t)(cm + r) * ldc + cn;
                    float v = acc[mi][ni][r] + bb;
                    if (RELU) v = fmaxf(v, 0.f);
                    ((float*)C)[off] = v;
                }
            }
        }
    }
}

// ---- rmask init for all 6 layers: [l][b][h], shared heads = 1, routed = 0 ----
__global__ void init_rmask6(float* __restrict__ r) {
    int t = blockIdx.x * 256 + threadIdx.x;
    if (t < 6 * 128) r[t] = ((t & 7) < 2) ? 1.0f : 0.0f;
}

// ---- router: 32 lanes per row, 8 rows/block. wg staged in LDS, chunk-skewed. ----
__global__ __launch_bounds__(256) void router_kernel(
    const u16* __restrict__ qlin, const float* __restrict__ wg,
    float* __restrict__ rmask)
{
    __shared__ float s_wg[6 * 544];     // 13056 B
    __shared__ float sacc[8];
    int tid = threadIdx.x;
    #pragma unroll
    for (int k = 0; k < 12; k++) {
        int n = tid + k * 256;          // 0..3071
        int d = n / 6, r = n - d * 6;
        s_wg[r * 544 + (d >> 4) * 17 + (d & 15)] = wg[n];
    }
    if (tid < 8) sacc[tid] = 0.f;
    __syncthreads();

    int c = tid & 31;                   // chunk within row
    int row = blockIdx.x * 8 + (tid >> 5);
    int cb = c * 17;
    const u16* xr = qlin + (size_t)row * DIM + c * 16;
    u16x8 q0 = *(const u16x8*)xr;
    u16x8 q1 = *(const u16x8*)(xr + 8);

    float lg[6] = {0.f, 0.f, 0.f, 0.f, 0.f, 0.f};
    #pragma unroll
    for (int j = 0; j < 8; j++) {
        float x = b2f(q0[j]);
        #pragma unroll
        for (int r = 0; r < 6; r++) lg[r] += x * s_wg[r * 544 + cb + j];
    }
    #pragma unroll
    for (int j = 0; j < 8; j++) {
        float x = b2f(q1[j]);
        #pragma unroll
        for (int r = 0; r < 6; r++) lg[r] += x * s_wg[r * 544 + cb + 8 + j];
    }
    #pragma unroll
    for (int r = 0; r < 6; r++) {
        #pragma unroll
        for (int o = 1; o < 32; o <<= 1) lg[r] += __shfl_xor(lg[r], o);
    }
    float m = lg[0];
    #pragma unroll
    for (int r = 1; r < 6; r++) m = fmaxf(m, lg[r]);
    float s = 0.f;
    #pragma unroll
    for (int r = 0; r < 6; r++) { lg[r] = __expf(lg[r] - m); s += lg[r]; }
    float inv = 1.0f / s;
    #pragma unroll
    for (int r = 0; r < 6; r++) lg[r] *= inv;
    int i1 = 0; float g1 = lg[0];
    #pragma unroll
    for (int r = 1; r < 6; r++) if (lg[r] > g1) { g1 = lg[r]; i1 = r; }
    int i2 = -1; float g2 = -1.f;
    #pragma unroll
    for (int r = 0; r < 6; r++) if (r != i1 && lg[r] > g2) { g2 = lg[r]; i2 = r; }
    if (c == 0) {
        atomicAdd(&sacc[i1], g1);
        atomicAdd(&sacc[i2], g2);
    }
    __syncthreads();
    if (tid < 6) {
        int b = blockIdx.x >> 6;        // 64 blocks per batch
        atomicAdd(&rmask[b * 8 + 2 + tid], sacc[tid] * (1.0f / (float)SEQ));
    }
}

// ---- MFMA flash attention v4: QBLK=128, 8 waves (512 thr). Each wave owns 16
// q-rows; 8 waves share each staged K/V tile. Wave-uniform skip for fully-masked
// tiles. T14 prefetch + XCD chunk.
__global__ __launch_bounds__(512) void attn_flash(
    const u16* __restrict__ qlin, const u16* __restrict__ vT,
    const float* __restrict__ rmask, u16* __restrict__ ctx, int mask_flag)
{
    __shared__ u16 s_k [64][72];
    __shared__ u16 s_vt[64][72];    // [d][j]
    __shared__ u16 s_p [128][72];
    int gi = (blockIdx.x & 7) * ((int)gridDim.x >> 3) + (blockIdx.x >> 3);
    int qt = gi & 3, h = (gi >> 2) & 7, b = gi >> 5;
    int tid = threadIdx.x;
    int wave = tid >> 6, lane = tid & 63;
    int quad = lane >> 4, l16 = lane & 15;
    int lr = tid >> 3, lc = (tid & 7) * 8;   // staging: 512 thr x 16B = 8KB tile

    const u16* qbase = qlin + (size_t)(b * SEQ) * DIM + h * DK;   // [s][d]
    const u16* vbase = vT + (size_t)(b * NH + h) * DK * SEQ;      // [d][j]

    // Q fragments hoisted to registers (jt-invariant); wave's rows qt*128+wave*16+..
    int qg0 = qt * 128 + wave * 16 + quad * 4;
    s16x8 aq[2];
    #pragma unroll
    for (int ks = 0; ks < 2; ks++)
        aq[ks] = *(const s16x8*)(qbase + (size_t)(qt * 128 + wave * 16 + l16) * DIM
                                 + ks * 32 + quad * 8);

    // stage registers for jt=0
    u16x8 k0 = *(const u16x8*)(qbase + (size_t)lr * DIM + lc);
    u16x8 v0 = *(const u16x8*)(vbase + (size_t)lr * SEQ + lc);

    f32x4 acc_o[4];
    #pragma unroll
    for (int i = 0; i < 4; i++) acc_o[i] = (f32x4){0.f, 0.f, 0.f, 0.f};
    float m_i[4] = {-1e30f, -1e30f, -1e30f, -1e30f};
    float l_i[4] = {0.f, 0.f, 0.f, 0.f};

    int rmax = qt * 128 + wave * 16 + 15;            // wave's last q-row
    int jt_end = 2 * qt + 1;                         // last key tile needed
    for (int jt = 0; jt <= jt_end; jt++) {
        __syncthreads();               // prior iter's s_k/s_vt frag reads done
        *(u16x8*)&s_k [lr][lc] = k0;
        *(u16x8*)&s_vt[lr][lc] = v0;
        __syncthreads();               // staging visible
        if (jt < jt_end) {             // T14: issue next tile's loads NOW
            k0 = *(const u16x8*)(qbase + (size_t)((jt + 1) * 64 + lr) * DIM + lc);
            v0 = *(const u16x8*)(vbase + (size_t)lr * SEQ + (jt + 1) * 64 + lc);
        }

        // wave-uniform skip: tile fully masked for this wave's rows
        bool active = (jt * 64) <= (mask_flag ? rmax : rmax - 1);
        if (active) {
            f32x4 acc_s[4];
            #pragma unroll
            for (int i = 0; i < 4; i++) acc_s[i] = (f32x4){0.f, 0.f, 0.f, 0.f};
            #pragma unroll
            for (int ks = 0; ks < 2; ks++) {
                #pragma unroll
                for (int nf = 0; nf < 4; nf++) {
                    s16x8 bb = *(s16x8*)&s_k[nf * 16 + l16][ks * 32 + quad * 8];
                    acc_s[nf] = __builtin_amdgcn_mfma_f32_16x16x32_bf16(aq[ks], bb, acc_s[nf], 0, 0, 0);
                }
            }

            float sc[4][4];
            #pragma unroll
            for (int nf = 0; nf < 4; nf++) {
                int jg = jt * 64 + nf * 16 + l16;
                #pragma unroll
                for (int r = 0; r < 4; r++) {
                    float v = acc_s[nf][r] * 0.125f;
                    int bound = mask_flag ? (qg0 + r) : (qg0 + r - 1);
                    if (jg > bound) v = -1e30f;     // no-op for fully-allowed tiles
                    sc[nf][r] = v;
                }
            }
            float tmax[4];
            #pragma unroll
            for (int r = 0; r < 4; r++) {
                float t = fmaxf(fmaxf(sc[0][r], sc[1][r]), fmaxf(sc[2][r], sc[3][r]));
                #pragma unroll
                for (int o = 1; o < 16; o <<= 1) t = fmaxf(t, __shfl_xor(t, o));
                tmax[r] = t;
            }
            float p[4][4];
            #pragma unroll
            for (int r = 0; r < 4; r++) {
                float mnew = fmaxf(m_i[r], tmax[r]);
                float alpha = __expf(m_i[r] - mnew);
                float su = 0.f;
                #pragma unroll
                for (int nf = 0; nf < 4; nf++) { p[nf][r] = __expf(sc[nf][r] - mnew); su += p[nf][r]; }
                #pragma unroll
                for (int o = 1; o < 16; o <<= 1) su += __shfl_xor(su, o);
                l_i[r] = l_i[r] * alpha + su;
                m_i[r] = mnew;
                #pragma unroll
                for (int nf = 0; nf < 4; nf++) acc_o[nf][r] *= alpha;
            }
            // P transpose through per-wave LDS rows (rows wave*16..+15 only;
            // in-order per-wave DS pipe; wave_barrier pins compiler ordering)
            #pragma unroll
            for (int nf = 0; nf < 4; nf++)
                #pragma unroll
                for (int r = 0; r < 4; r++)
                    s_p[wave * 16 + quad * 4 + r][nf * 16 + l16] = f2b(p[nf][r]);
            __builtin_amdgcn_wave_barrier();
            s16x8 pa[2];
            pa[0] = *(s16x8*)&s_p[wave * 16 + l16][quad * 8];
            pa[1] = *(s16x8*)&s_p[wave * 16 + l16][32 + quad * 8];
            __builtin_amdgcn_wave_barrier();

            #pragma unroll
            for (int ks = 0; ks < 2; ks++) {
                #pragma unroll
                for (int nf = 0; nf < 4; nf++) {
                    s16x8 bb = *(s16x8*)&s_vt[nf * 16 + l16][ks * 32 + quad * 8];
                    acc_o[nf] = __builtin_amdgcn_mfma_f32_16x16x32_bf16(pa[ks], bb, acc_o[nf], 0, 0, 0);
                }
            }
        }
    }

    float rm = rmask[b * 8 + h];
    int qrow = qt * 128 + wave * 16 + quad * 4;
    #pragma unroll
    for (int r = 0; r < 4; r++) {
        float scale = rm / l_i[r];
        u16* dst = ctx + (size_t)(b * SEQ + qrow + r) * DIM + h * DK;
        #pragma unroll
        for (int nf = 0; nf < 4; nf++)
            dst[nf * 16 + l16] = f2b(acc_o[nf][r] * scale);
    }
}

// ---- row q==0: uniform 1/SEQ over ALL keys; coalesced reads from vT ----
__global__ __launch_bounds__(256) void attn_row0(
    const u16* __restrict__ vT, const float* __restrict__ rmask, u16* __restrict__ ctx)
{
    int bh = blockIdx.x;
    int b = bh >> 3, h = bh & 7;
    int d = threadIdx.x >> 2, seg = threadIdx.x & 3;
    const u16* src = vT + ((size_t)bh * DK + d) * SEQ + seg * 128;
    float s = 0.f;
    for (int i = 0; i < 16; i++) {
        u16x8 v = *(const u16x8*)(src + i * 8);
        #pragma unroll
        for (int j = 0; j < 8; j++) s += b2f(v[j]);
    }
    s += __shfl_down(s, 1);
    s += __shfl_down(s, 2);
    if (seg == 0)
        ctx[(size_t)(b * SEQ) * DIM + h * DK + d] =
            f2b(s * (1.0f / (float)SEQ) * rmask[b * 8 + h]);
}

// ---- xout = LN(x + p0 + p1 + bias_col); p0/p1 bf16 partials; emit bf16 copy.
// xout normally == x; the final layer writes d_out directly (kills the memcpy).
__global__ __launch_bounds__(256) void add_ln2(
    const float* __restrict__ x, float* __restrict__ xout,
    const u16* __restrict__ p0, const u16* __restrict__ p1,
    const float* __restrict__ bcol,
    const float* __restrict__ g, const float* __restrict__ bta,
    u16* __restrict__ out16)
{
    __shared__ float redA[4], redB[4];
    int row = blockIdx.x, tid = threadIdx.x;
    size_t base = (size_t)row * DIM;
    float t0 = x[base + tid]       + b2f(p0[base + tid])       + b2f(p1[base + tid])       + bcol[tid];
    float t1 = x[base + tid + 256] + b2f(p0[base + tid + 256]) + b2f(p1[base + tid + 256]) + bcol[tid + 256];
    float s = t0 + t1, sq = t0 * t0 + t1 * t1;
    for (int o = 32; o > 0; o >>= 1) { s += __shfl_down(s, o, 64); sq += __shfl_down(sq, o, 64); }
    int lane = tid & 63, wid = tid >> 6;
    if (lane == 0) { redA[wid] = s; redB[wid] = sq; }
    __syncthreads();
    float S1 = redA[0] + redA[1] + redA[2] + redA[3];
    float S2 = redB[0] + redB[1] + redB[2] + redB[3];
    float mu = S1 * (1.0f / (float)DIM);
    float var = S2 * (1.0f / (float)DIM) - mu * mu;
    float rstd = rsqrtf(var + 1e-5f);
    float o0 = g[tid]       * (t0 - mu) * rstd + bta[tid];
    float o1 = g[tid + 256] * (t1 - mu) * rstd + bta[tid + 256];
    xout[base + tid]       = o0;
    xout[base + tid + 256] = o1;
    out16[base + tid]       = f2b(o0);
    out16[base + tid + 256] = f2b(o1);
}

// ---------------- host side ----------------
extern "C" void kernel_launch(void* const* d_in, const int* in_sizes, int n_in,
                              void* d_out, int out_size, void* d_ws, size_t ws_size,
                              hipStream_t stream) {
    const float* qe   = (const float*)d_in[0];
    const float* ie   = (const float*)d_in[1];
    const float* wq   = (const float*)d_in[2];
    const float* bq   = (const float*)d_in[3];
    const float* wv   = (const float*)d_in[4];
    const float* bv   = (const float*)d_in[5];
    const float* wo   = (const float*)d_in[6];
    const float* bo   = (const float*)d_in[7];
    const float* wg   = (const float*)d_in[8];
    const float* ln1g = (const float*)d_in[9];
    const float* ln1b = (const float*)d_in[10];
    const float* fw1  = (const float*)d_in[11];
    const float* fb1  = (const float*)d_in[12];
    const float* fw2  = (const float*)d_in[13];
    const float* fb2  = (const float*)d_in[14];
    const float* ln2g = (const float*)d_in[15];
    const float* ln2b = (const float*)d_in[16];

    const size_t RD = (size_t)NROWS * DIM;     // 4,194,304
    float* ws   = (float*)d_ws;
    float* xbuf = ws;                          // question residual (fp32)
    float* ybuf = ws + RD;                     // knowledge residual (fp32)

    u16* b16    = (u16*)(ws + 2 * RD);
    u16* x16    = b16;                 b16 += RD;
    u16* y16    = b16;                 b16 += RD;
    u16* ctx16  = b16;                 b16 += RD;
    u16* qlin16 = b16;                 b16 += RD;
    u16* proj0  = b16;                 b16 += RD;       // bf16 split-K partial 0
    u16* vT     = b16;                 b16 += RD;
    u16* hid    = b16;                 b16 += 4 * RD;   // 8192x2048 bf16, dedicated
    u16* proj1  = b16;                 b16 += RD;       // bf16 split-K partial 1
    u16* wqvT   = b16;                 b16 += 6 * (size_t)1024 * 512;
    u16* woT    = b16;                 b16 += 6 * (size_t)512 * 512;
    u16* fw1T   = b16;                 b16 += 2 * (size_t)DFF2 * 512;
    u16* fw2T   = b16;                 b16 += 2 * (size_t)512 * DFF2;
    float* rmask6 = (float*)b16;                // 6*128 floats

    cast_dual<<<(int)(RD / 4 / 256), 256, 0, stream>>>(qe, xbuf, x16, (int)(RD / 4));
    cast_dual<<<(int)(RD / 4 / 256), 256, 0, stream>>>(ie, ybuf, y16, (int)(RD / 4));

    transpose_cast<<<dim3(16, 16, 6), 256, 0, stream>>>(wq, wqvT,             512, 512, 0, 1, (size_t)1024 * 512);
    transpose_cast<<<dim3(16, 16, 6), 256, 0, stream>>>(wv, wqvT + 512 * 512, 512, 512, 0, 1, (size_t)1024 * 512);
    transpose_cast<<<dim3(16, 16, 6), 256, 0, stream>>>(wo, woT,              512, 512, 0, 1, (size_t)512 * 512);
    transpose_cast<<<dim3(16, 64, 2), 256, 0, stream>>>(fw1, fw1T, 512, DFF2, 3, 2, (size_t)DFF2 * 512);
    transpose_cast<<<dim3(64, 16, 2), 256, 0, stream>>>(fw2, fw2T, DFF2, 512, 3, 2, (size_t)512 * DFF2);
    init_rmask6<<<3, 256, 0, stream>>>(rmask6);

    const int BIG = 1 << 30;
    auto run_block = [&](float* xr, u16* xq16, const u16* xv16, int l, int maskf, int pos,
                         float* xo2) {
        size_t lD = (size_t)l * DIM;
        float* rm = rmask6 + l * 128;
        // q|v fused: N=1024, 64-col tiles -> nx=16, 1024 blocks (4/CU).
        // VT=1: V half stores transposed direct into vT (transpose_v fused away).
        gemm2<1, 0, 1, 0, 2, 1><<<1024, 256, 0, stream>>>(
            xq16, xv16, wqvT + (size_t)l * 1024 * 512, bq + lD, bv + lD,
            qlin16, vT, 512, 512, 512, 512, 512, 16);
        router_kernel<<<NROWS / 8, 256, 0, stream>>>(qlin16, wg + (size_t)l * DIM * 6, rm);
        attn_flash<<<512, 512, 0, stream>>>(qlin16, vT, rm, ctx16, maskf);
        attn_row0<<<128, 256, 0, stream>>>(vT, rm, ctx16);
        // wo proj: N=512 nx=8, split-K x2 (Khalf=256) -> 1024 blocks; bf16 partials
        gemm2<1, 0, 0, 1, 2, 0><<<1024, 256, 0, stream>>>(
            ctx16, ctx16, woT + (size_t)l * 512 * 512, nullptr, nullptr,
            proj0, proj1, 256, 512, 512, 512, BIG, 8);
        add_ln2<<<NROWS, 256, 0, stream>>>(xr, xr, proj0, proj1, bo + lD,
                                           ln1g + lD, ln1b + lD, xq16);
        if (pos) {
            int slot = (l - 3) / 2;
            // fw1: N=2048, 64-col tiles (NI=2) -> nx=32, 2048 blocks (8/CU)
            gemm2<1, 1, 0, 0, 2, 0><<<2048, 256, 0, stream>>>(
                xq16, xq16, fw1T + (size_t)slot * DFF2 * 512,
                fb1 + (size_t)l * DFF2, nullptr,
                hid, nullptr, 512, 512, 512, DFF2, BIG, 32);
            // fw2: N=512 nx=8, K=2048 split-K x2 (Khalf=1024) -> 1024 blocks; bf16 partials
            gemm2<1, 0, 0, 1, 2, 0><<<1024, 256, 0, stream>>>(
                hid, hid, fw2T + (size_t)slot * 512 * DFF2, nullptr, nullptr,
                proj0, proj1, 1024, DFF2, DFF2, 512, BIG, 8);
            add_ln2<<<NROWS, 256, 0, stream>>>(xr, xo2, proj0, proj1, fb2 + lD,
                                               ln2g + lD, ln2b + lD, xq16);
        }
    };

    run_block(ybuf, y16, y16, 0, 1, 0, ybuf);
    run_block(ybuf, y16, y16, 1, 1, 0, ybuf);
    run_block(xbuf, x16, x16, 2, 1, 0, xbuf);
    run_block(xbuf, x16, y16, 3, 0, 1, xbuf);
    run_block(xbuf, x16, x16, 4, 1, 0, xbuf);
    run_block(xbuf, x16, y16, 5, 0, 1, (float*)d_out);   // final LN -> d_out direct
}

// Round 12
// 782.697 us; speedup vs baseline: 1.3947x; 1.0427x over previous
//
#include <hip/hip_runtime.h>
#include <hip/hip_bf16.h>

#define BSZ 16
#define SEQ 512
#define DIM 512
#define NH 8
#define DK 64
#define NROWS (BSZ*SEQ)   // 8192
#define DFF2 2048

typedef unsigned short u16;
typedef u16   u16x8 __attribute__((ext_vector_type(8)));
typedef u16   u16x4 __attribute__((ext_vector_type(4)));
typedef short s16x8 __attribute__((ext_vector_type(8)));
typedef float f32x4 __attribute__((ext_vector_type(4)));

__device__ __forceinline__ u16 f2b(float x) {
    union { float f; unsigned int u; } c; c.f = x;
    unsigned int r = c.u + 0x7fff + ((c.u >> 16) & 1);   // RNE
    return (u16)(r >> 16);
}
__device__ __forceinline__ float b2f(u16 u) {
    union { unsigned int i; float f; } c; c.i = ((unsigned int)u) << 16; return c.f;
}

// async global->LDS, 16B per lane. LDS dest = wave-uniform base + lane*16.
__device__ __forceinline__ void gld16(const u16* g, u16* l) {
    __builtin_amdgcn_global_load_lds(
        (const __attribute__((address_space(1))) unsigned int*)(unsigned long long)g,
        (__attribute__((address_space(3))) unsigned int*)(unsigned int)(unsigned long long)l,
        16, 0, 0);
}

// ---- cast fp32 -> bf16 ----
__global__ __launch_bounds__(256) void cast_f2b4(const float* __restrict__ in,
                                                 u16* __restrict__ out, int n4) {
    int i = blockIdx.x * 256 + threadIdx.x;
    if (i >= n4) return;
    float4 v = ((const float4*)in)[i];
    ushort4 o; o.x = f2b(v.x); o.y = f2b(v.y); o.z = f2b(v.z); o.w = f2b(v.w);
    ((ushort4*)out)[i] = o;
}

// ---- transpose + cast weights: dest[z][N][K](bf16) from W[layer0+z*lstride][K][N](fp32) ----
__global__ __launch_bounds__(256) void transpose_cast(
    const float* __restrict__ W, u16* __restrict__ WT,
    int K, int N, int layer0, int lstride, size_t dstride)
{
    __shared__ float t[32][33];
    int z = blockIdx.z;
    const float* Wz = W + (size_t)(layer0 + z * lstride) * K * N;
    u16* WTz = WT + (size_t)z * dstride;
    int k0 = blockIdx.x * 32, n0 = blockIdx.y * 32;
    int tx = threadIdx.x & 31, ty = threadIdx.x >> 5;
    for (int i = ty; i < 32; i += 8) t[i][tx] = Wz[(size_t)(k0 + i) * N + n0 + tx];
    __syncthreads();
    for (int i = ty; i < 32; i += 8) WTz[(size_t)(n0 + i) * K + k0 + tx] = f2b(t[tx][i]);
}

// ---- combined 512x512 transpose for wq/wv/wo: z 0..5 wq, 6..11 wv, 12..17 wo ----
__global__ __launch_bounds__(256) void transpose_cast3(
    const float* __restrict__ wq, const float* __restrict__ wv,
    const float* __restrict__ wo, u16* __restrict__ wqvT, u16* __restrict__ woT)
{
    __shared__ float t[32][33];
    int z = blockIdx.z;
    const float* W; u16* D;
    if (z < 6)       { W = wq + (size_t)z * 512 * 512;        D = wqvT + (size_t)z * 1024 * 512; }
    else if (z < 12) { W = wv + (size_t)(z - 6) * 512 * 512;  D = wqvT + (size_t)(z - 6) * 1024 * 512 + 512 * 512; }
    else             { W = wo + (size_t)(z - 12) * 512 * 512; D = woT + (size_t)(z - 12) * 512 * 512; }
    int k0 = blockIdx.x * 32, n0 = blockIdx.y * 32;
    int tx = threadIdx.x & 31, ty = threadIdx.x >> 5;
    for (int i = ty; i < 32; i += 8) t[i][tx] = W[(size_t)(k0 + i) * 512 + n0 + tx];
    __syncthreads();
    for (int i = ty; i < 32; i += 8) D[(size_t)(n0 + i) * 512 + k0 + tx] = f2b(t[tx][i]);
}

// ---- MFMA GEMM. C[M,N] = A[M,K] @ WT[N,K]^T (+bias). Tile 128 x (NI*32), BK=32,
// double-buffered LDS, XCD-chunked 1-D grid swizzle.
// Epilogue: bf16 C staged through LDS for 16B coalesced stores.
// SPLIT : col-tiles with n0 >= nsplit use Av/bias2/C2 (fused q|v).
// VT    : (with SPLIT) V col-tiles store TRANSPOSED direct from acc into
//         C2 = vT[(b*8+h)*64+d][j] as u16x4 (8B) — replaces transpose_v.
// SPLITK: grid doubled; second half computes k-slice 1 into C2 (bf16 partials;
//         bias added later in add_ln2). K param = per-slice K.
template<int WRITE_BF16, int RELU, int SPLIT, int SPLITK, int NI, int VT>
__global__ __launch_bounds__(256) void gemm2(
    const u16* __restrict__ Aq, const u16* __restrict__ Av,
    const u16* __restrict__ WT,
    const float* __restrict__ bias1, const float* __restrict__ bias2,
    void* __restrict__ C1, void* __restrict__ C2,
    int K, int lda, int ldw, int ldc, int nsplit, int nx)
{
    __shared__ __attribute__((aligned(16))) u16 smem[2 * 128 * 32 + 2 * NI * 32 * 32];
    u16* As = smem;                       // [2][128*32]
    u16* Bs = smem + 2 * 128 * 32;        // [2][NI*32*32]
    int tid = threadIdx.x;
    int wave = tid >> 6, lane = tid & 63;
    int quad = lane >> 4, l16 = lane & 15;

    // XCD-chunked swizzle over the whole 1-D grid
    int bid = blockIdx.x;
    int per = gridDim.x >> 3;
    int swz = (bid & 7) * per + (bid >> 3);
    int nxy = SPLITK ? ((int)gridDim.x >> 1) : (int)gridDim.x;
    int kslice = 0;
    if (SPLITK && swz >= nxy) { kslice = 1; swz -= nxy; }
    int bx = swz % nx, by = swz / nx;
    int n0 = bx * (NI * 32), m0 = by * 128;

    int wrow = (wave & 1) * 64;
    int wcol = (wave >> 1) * (NI * 16);
    bool isv = SPLIT && (n0 >= nsplit);
    const u16* A = isv ? Av : Aq;

    // A staging: wave w covers rows [w*32, w*32+32); 2 gld16 of 16 rows each
    int sr = wave * 32 + (lane >> 2);
    int sc = (lane & 3) * 8;
    int ko = kslice * K;                     // k-slice base (elements)
    const u16* gA0 = A  + (size_t)(m0 + sr) * lda + sc + ko;
    const u16* gA1 = gA0 + (size_t)16 * lda;
    int lo0 = (wave * 32) * 32;
    int lo1 = (wave * 32 + 16) * 32;

    // B staging
    const u16* gB0;
    const u16* gB1 = nullptr;
    int bo0, bo1 = 0;
    if (NI == 4) {                           // 128-row B tile: like A
        gB0 = WT + (size_t)(n0 + sr) * ldw + sc + ko;
        gB1 = gB0 + (size_t)16 * ldw;
        bo0 = lo0; bo1 = lo1;
    } else {                                 // 64-row B tile: 1 gld16/wave (16 rows)
        gB0 = WT + (size_t)(n0 + wave * 16 + (lane >> 2)) * ldw + sc + ko;
        bo0 = (wave * 16) * 32;
    }

    f32x4 acc[4][NI];
    #pragma unroll
    for (int i = 0; i < 4; i++)
        #pragma unroll
        for (int j = 0; j < NI; j++) acc[i][j] = (f32x4){0.f, 0.f, 0.f, 0.f};

    // prologue: stage k-tile 0 into buf 0
    gld16(gA0, &As[lo0]);
    gld16(gA1, &As[lo1]);
    gld16(gB0, &Bs[bo0]);
    if (NI == 4) gld16(gB1, &Bs[bo1]);
    __syncthreads();

    int NT = K >> 5;
    int cur = 0;
    for (int t = 0; t < NT; ++t) {
        if (t + 1 < NT) {                    // prefetch next tile into other buffer
            int k0 = (t + 1) << 5;
            int nxt = cur ^ 1;
            gld16(gA0 + k0, &As[nxt * 128 * 32 + lo0]);
            gld16(gA1 + k0, &As[nxt * 128 * 32 + lo1]);
            gld16(gB0 + k0, &Bs[nxt * NI * 32 * 32 + bo0]);
            if (NI == 4) gld16(gB1 + k0, &Bs[nxt * NI * 32 * 32 + bo1]);
        }
        s16x8 af[4], bf[NI];
        #pragma unroll
        for (int i = 0; i < 4; i++)
            af[i] = *(s16x8*)&As[cur * 128 * 32 + (wrow + i * 16 + l16) * 32 + quad * 8];
        #pragma unroll
        for (int i = 0; i < NI; i++)
            bf[i] = *(s16x8*)&Bs[cur * NI * 32 * 32 + (wcol + i * 16 + l16) * 32 + quad * 8];
        #pragma unroll
        for (int mi = 0; mi < 4; mi++)
            #pragma unroll
            for (int ni = 0; ni < NI; ni++)
                acc[mi][ni] = __builtin_amdgcn_mfma_f32_16x16x32_bf16(
                    af[mi], bf[ni], acc[mi][ni], 0, 0, 0);
        __syncthreads();                     // drains prefetch loads + frag reads
        cur ^= 1;
    }

    if (VT && isv) {
        // direct transposed V store: vT[(b*8+h)*64+d][j], d = (n0-nsplit)+lc_,
        // j = m0%512 + row-in-tile. u16x4 (8B aligned) per 4 consecutive j.
        int bI = m0 >> 9, j0 = m0 & 511;
        u16* dst = (u16*)C2 + ((size_t)(bI * NH * DK) + (n0 - nsplit)) * SEQ + j0;
        #pragma unroll
        for (int ni = 0; ni < NI; ni++) {
            int lc_ = wcol + ni * 16 + l16;          // 0..63 within head
            float bb = bias2[(n0 - nsplit) + lc_];
            #pragma unroll
            for (int mi = 0; mi < 4; mi++) {
                int jj = wrow + mi * 16 + quad * 4;
                u16x4 tv;
                #pragma unroll
                for (int r = 0; r < 4; r++) tv[r] = f2b(acc[mi][ni][r] + bb);
                *(u16x4*)(dst + (size_t)lc_ * SEQ + jj) = tv;
            }
        }
        return;
    }

    const float* bias = isv ? bias2 : bias1;
    void* C = (isv || (SPLITK && kslice)) ? C2 : C1;
    int nb = n0 - (isv ? nsplit : 0);

    if (WRITE_BF16) {
        // ---- coalesced epilogue: acc -> LDS (bias/relu applied) -> 16B stores ----
        const int CSTR = NI * 32 + 8;        // u16 stride; NI=2: 128*72*2=18KB <= 24KB
        u16* Cs = smem;                      // As/Bs dead after final barrier
        #pragma unroll
        for (int ni = 0; ni < NI; ni++) {
            int lc_ = wcol + ni * 16 + l16;
            float bb = bias ? bias[nb + lc_] : 0.f;
            #pragma unroll
            for (int mi = 0; mi < 4; mi++) {
                int lrow = wrow + mi * 16 + quad * 4;
                #pragma unroll
                for (int r = 0; r < 4; r++) {
                    float v = acc[mi][ni][r] + bb;
                    if (RELU) v = fmaxf(v, 0.f);
                    Cs[(lrow + r) * CSTR + lc_] = f2b(v);
                }
            }
        }
        __syncthreads();
        const int CPR = NI * 4;              // 8-u16 chunks per row
        int row = tid / CPR;
        int col = (tid % CPR) * 8;
        #pragma unroll
        for (int i = 0; i < NI * 2; i++) {
            int rr = row + i * (256 / CPR);
            u16x8 vv = *(u16x8*)&Cs[rr * CSTR + col];
            *(u16x8*)((u16*)C + (size_t)(m0 + rr) * ldc + nb + col) = vv;
        }
    } else {
        #pragma unroll
        for (int ni = 0; ni < NI; ni++) {
            int cn = nb + wcol + ni * 16 + l16;
            float bb = bias ? bias[cn] : 0.f;
            #pragma unroll
            for (int mi = 0; mi < 4; mi++) {
                int cm = m0 + wrow + mi * 16 + quad * 4;
                #pragma unroll
                for (int r = 0; r < 4; r++) {
                    size_t off = (size_t)(cm + r) * ldc + cn;
                    float v = acc[mi][ni][r] + bb;
                    if (RELU) v = fmaxf(v, 0.f);
                    ((float*)C)[off] = v;
                }
            }
        }
    }
}

// ---- rmask init for all 6 layers: [l][b][h], shared heads = 1, routed = 0 ----
__global__ void init_rmask6(float* __restrict__ r) {
    int t = blockIdx.x * 256 + threadIdx.x;
    if (t < 6 * 128) r[t] = ((t & 7) < 2) ? 1.0f : 0.0f;
}

// ---- router: 32 lanes per row, 8 rows/block. wg staged in LDS, chunk-skewed. ----
__global__ __launch_bounds__(256) void router_kernel(
    const u16* __restrict__ qlin, const float* __restrict__ wg,
    float* __restrict__ rmask)
{
    __shared__ float s_wg[6 * 544];     // 13056 B
    __shared__ float sacc[8];
    int tid = threadIdx.x;
    #pragma unroll
    for (int k = 0; k < 12; k++) {
        int n = tid + k * 256;          // 0..3071
        int d = n / 6, r = n - d * 6;
        s_wg[r * 544 + (d >> 4) * 17 + (d & 15)] = wg[n];
    }
    if (tid < 8) sacc[tid] = 0.f;
    __syncthreads();

    int c = tid & 31;                   // chunk within row
    int row = blockIdx.x * 8 + (tid >> 5);
    int cb = c * 17;
    const u16* xr = qlin + (size_t)row * DIM + c * 16;
    u16x8 q0 = *(const u16x8*)xr;
    u16x8 q1 = *(const u16x8*)(xr + 8);

    float lg[6] = {0.f, 0.f, 0.f, 0.f, 0.f, 0.f};
    #pragma unroll
    for (int j = 0; j < 8; j++) {
        float x = b2f(q0[j]);
        #pragma unroll
        for (int r = 0; r < 6; r++) lg[r] += x * s_wg[r * 544 + cb + j];
    }
    #pragma unroll
    for (int j = 0; j < 8; j++) {
        float x = b2f(q1[j]);
        #pragma unroll
        for (int r = 0; r < 6; r++) lg[r] += x * s_wg[r * 544 + cb + 8 + j];
    }
    #pragma unroll
    for (int r = 0; r < 6; r++) {
        #pragma unroll
        for (int o = 1; o < 32; o <<= 1) lg[r] += __shfl_xor(lg[r], o);
    }
    float m = lg[0];
    #pragma unroll
    for (int r = 1; r < 6; r++) m = fmaxf(m, lg[r]);
    float s = 0.f;
    #pragma unroll
    for (int r = 0; r < 6; r++) { lg[r] = __expf(lg[r] - m); s += lg[r]; }
    float inv = 1.0f / s;
    #pragma unroll
    for (int r = 0; r < 6; r++) lg[r] *= inv;
    int i1 = 0; float g1 = lg[0];
    #pragma unroll
    for (int r = 1; r < 6; r++) if (lg[r] > g1) { g1 = lg[r]; i1 = r; }
    int i2 = -1; float g2 = -1.f;
    #pragma unroll
    for (int r = 0; r < 6; r++) if (r != i1 && lg[r] > g2) { g2 = lg[r]; i2 = r; }
    if (c == 0) {
        atomicAdd(&sacc[i1], g1);
        atomicAdd(&sacc[i2], g2);
    }
    __syncthreads();
    if (tid < 6) {
        int b = blockIdx.x >> 6;        // 64 blocks per batch
        atomicAdd(&rmask[b * 8 + 2 + tid], sacc[tid] * (1.0f / (float)SEQ));
    }
}

// ---- MFMA flash attention v5: QBLK=128, 8 waves. attn_row0 fused: the qt==3
// block of each (b,h) visits all 8 V tiles, so it accumulates sum_j V[d][j]
// from s_vt (outside the active-branch) and writes ctx row 0 = mean(V)*rm.
// qt==0 blocks skip their r==0 store -> row 0 has a single writer. ----
__global__ __launch_bounds__(512) void attn_flash(
    const u16* __restrict__ qlin, const u16* __restrict__ vT,
    const float* __restrict__ rmask, u16* __restrict__ ctx, int mask_flag)
{
    __shared__ u16 s_k [64][72];
    __shared__ u16 s_vt[64][72];    // [d][j]
    __shared__ u16 s_p [128][72];
    int gi = (blockIdx.x & 7) * ((int)gridDim.x >> 3) + (blockIdx.x >> 3);
    int qt = gi & 3, h = (gi >> 2) & 7, b = gi >> 5;
    int tid = threadIdx.x;
    int wave = tid >> 6, lane = tid & 63;
    int quad = lane >> 4, l16 = lane & 15;
    int lr = tid >> 3, lc = (tid & 7) * 8;   // staging: 512 thr x 16B = 8KB tile

    const u16* qbase = qlin + (size_t)(b * SEQ) * DIM + h * DK;   // [s][d]
    const u16* vbase = vT + (size_t)(b * NH + h) * DK * SEQ;      // [d][j]

    // Q fragments hoisted to registers (jt-invariant); wave's rows qt*128+wave*16+..
    int qg0 = qt * 128 + wave * 16 + quad * 4;
    s16x8 aq[2];
    #pragma unroll
    for (int ks = 0; ks < 2; ks++)
        aq[ks] = *(const s16x8*)(qbase + (size_t)(qt * 128 + wave * 16 + l16) * DIM
                                 + ks * 32 + quad * 8);

    // stage registers for jt=0
    u16x8 k0 = *(const u16x8*)(qbase + (size_t)lr * DIM + lc);
    u16x8 v0 = *(const u16x8*)(vbase + (size_t)lr * SEQ + lc);

    f32x4 acc_o[4];
    #pragma unroll
    for (int i = 0; i < 4; i++) acc_o[i] = (f32x4){0.f, 0.f, 0.f, 0.f};
    float m_i[4] = {-1e30f, -1e30f, -1e30f, -1e30f};
    float l_i[4] = {0.f, 0.f, 0.f, 0.f};
    float vsum = 0.f;                                // row-0 fusion (qt==3 only)

    int rmax = qt * 128 + wave * 16 + 15;            // wave's last q-row
    int jt_end = 2 * qt + 1;                         // last key tile needed
    for (int jt = 0; jt <= jt_end; jt++) {
        __syncthreads();               // prior iter's s_k/s_vt frag reads done
        *(u16x8*)&s_k [lr][lc] = k0;
        *(u16x8*)&s_vt[lr][lc] = v0;
        __syncthreads();               // staging visible
        if (jt < jt_end) {             // T14: issue next tile's loads NOW
            k0 = *(const u16x8*)(qbase + (size_t)((jt + 1) * 64 + lr) * DIM + lc);
            v0 = *(const u16x8*)(vbase + (size_t)lr * SEQ + (jt + 1) * 64 + lc);
        }

        if (qt == 3) {                 // row-0 fusion: accumulate V column sums
            u16x8 vv = *(u16x8*)&s_vt[tid >> 3][(tid & 7) * 8];
            #pragma unroll
            for (int j = 0; j < 8; j++) vsum += b2f(vv[j]);
        }

        // wave-uniform skip: tile fully masked for this wave's rows
        bool active = (jt * 64) <= (mask_flag ? rmax : rmax - 1);
        if (active) {
            f32x4 acc_s[4];
            #pragma unroll
            for (int i = 0; i < 4; i++) acc_s[i] = (f32x4){0.f, 0.f, 0.f, 0.f};
            #pragma unroll
            for (int ks = 0; ks < 2; ks++) {
                #pragma unroll
                for (int nf = 0; nf < 4; nf++) {
                    s16x8 bb = *(s16x8*)&s_k[nf * 16 + l16][ks * 32 + quad * 8];
                    acc_s[nf] = __builtin_amdgcn_mfma_f32_16x16x32_bf16(aq[ks], bb, acc_s[nf], 0, 0, 0);
                }
            }

            float sc[4][4];
            #pragma unroll
            for (int nf = 0; nf < 4; nf++) {
                int jg = jt * 64 + nf * 16 + l16;
                #pragma unroll
                for (int r = 0; r < 4; r++) {
                    float v = acc_s[nf][r] * 0.125f;
                    int bound = mask_flag ? (qg0 + r) : (qg0 + r - 1);
                    if (jg > bound) v = -1e30f;     // no-op for fully-allowed tiles
                    sc[nf][r] = v;
                }
            }
            float tmax[4];
            #pragma unroll
            for (int r = 0; r < 4; r++) {
                float t = fmaxf(fmaxf(sc[0][r], sc[1][r]), fmaxf(sc[2][r], sc[3][r]));
                #pragma unroll
                for (int o = 1; o < 16; o <<= 1) t = fmaxf(t, __shfl_xor(t, o));
                tmax[r] = t;
            }
            float p[4][4];
            #pragma unroll
            for (int r = 0; r < 4; r++) {
                float mnew = fmaxf(m_i[r], tmax[r]);
                float alpha = __expf(m_i[r] - mnew);
                float su = 0.f;
                #pragma unroll
                for (int nf = 0; nf < 4; nf++) { p[nf][r] = __expf(sc[nf][r] - mnew); su += p[nf][r]; }
                #pragma unroll
                for (int o = 1; o < 16; o <<= 1) su += __shfl_xor(su, o);
                l_i[r] = l_i[r] * alpha + su;
                m_i[r] = mnew;
                #pragma unroll
                for (int nf = 0; nf < 4; nf++) acc_o[nf][r] *= alpha;
            }
            // P transpose through per-wave LDS rows (rows wave*16..+15 only;
            // in-order per-wave DS pipe; wave_barrier pins compiler ordering)
            #pragma unroll
            for (int nf = 0; nf < 4; nf++)
                #pragma unroll
                for (int r = 0; r < 4; r++)
                    s_p[wave * 16 + quad * 4 + r][nf * 16 + l16] = f2b(p[nf][r]);
            __builtin_amdgcn_wave_barrier();
            s16x8 pa[2];
            pa[0] = *(s16x8*)&s_p[wave * 16 + l16][quad * 8];
            pa[1] = *(s16x8*)&s_p[wave * 16 + l16][32 + quad * 8];
            __builtin_amdgcn_wave_barrier();

            #pragma unroll
            for (int ks = 0; ks < 2; ks++) {
                #pragma unroll
                for (int nf = 0; nf < 4; nf++) {
                    s16x8 bb = *(s16x8*)&s_vt[nf * 16 + l16][ks * 32 + quad * 8];
                    acc_o[nf] = __builtin_amdgcn_mfma_f32_16x16x32_bf16(pa[ks], bb, acc_o[nf], 0, 0, 0);
                }
            }
        }
    }

    float rm = rmask[b * 8 + h];
    int qrow = qt * 128 + wave * 16 + quad * 4;
    #pragma unroll
    for (int r = 0; r < 4; r++) {
        if (qrow + r == 0) continue;             // row 0 written by qt==3 path
        float scale = rm / l_i[r];
        u16* dst = ctx + (size_t)(b * SEQ + qrow + r) * DIM + h * DK;
        #pragma unroll
        for (int nf = 0; nf < 4; nf++)
            dst[nf * 16 + l16] = f2b(acc_o[nf][r] * scale);
    }
    if (qt == 3) {
        float vs = vsum;
        vs += __shfl_down(vs, 4, 8);
        vs += __shfl_down(vs, 2, 8);
        vs += __shfl_down(vs, 1, 8);
        if ((tid & 7) == 0)
            ctx[(size_t)(b * SEQ) * DIM + h * DK + (tid >> 3)] =
                f2b(vs * (1.0f / (float)SEQ) * rm);
    }
}

// ---- xout = LN(x + p0 + p1 + bias_col); p0/p1 bf16 partials; emit bf16 copy.
// x may be the original network input (no residual copy needed); xout may be
// d_out for the final layer (kills the closing memcpy).
__global__ __launch_bounds__(256) void add_ln2(
    const float* __restrict__ x, float* __restrict__ xout,
    const u16* __restrict__ p0, const u16* __restrict__ p1,
    const float* __restrict__ bcol,
    const float* __restrict__ g, const float* __restrict__ bta,
    u16* __restrict__ out16)
{
    __shared__ float redA[4], redB[4];
    int row = blockIdx.x, tid = threadIdx.x;
    size_t base = (size_t)row * DIM;
    float t0 = x[base + tid]       + b2f(p0[base + tid])       + b2f(p1[base + tid])       + bcol[tid];
    float t1 = x[base + tid + 256] + b2f(p0[base + tid + 256]) + b2f(p1[base + tid + 256]) + bcol[tid + 256];
    float s = t0 + t1, sq = t0 * t0 + t1 * t1;
    for (int o = 32; o > 0; o >>= 1) { s += __shfl_down(s, o, 64); sq += __shfl_down(sq, o, 64); }
    int lane = tid & 63, wid = tid >> 6;
    if (lane == 0) { redA[wid] = s; redB[wid] = sq; }
    __syncthreads();
    float S1 = redA[0] + redA[1] + redA[2] + redA[3];
    float S2 = redB[0] + redB[1] + redB[2] + redB[3];
    float mu = S1 * (1.0f / (float)DIM);
    float var = S2 * (1.0f / (float)DIM) - mu * mu;
    float rstd = rsqrtf(var + 1e-5f);
    float o0 = g[tid]       * (t0 - mu) * rstd + bta[tid];
    float o1 = g[tid + 256] * (t1 - mu) * rstd + bta[tid + 256];
    xout[base + tid]       = o0;
    xout[base + tid + 256] = o1;
    out16[base + tid]       = f2b(o0);
    out16[base + tid + 256] = f2b(o1);
}

// ---------------- host side ----------------
extern "C" void kernel_launch(void* const* d_in, const int* in_sizes, int n_in,
                              void* d_out, int out_size, void* d_ws, size_t ws_size,
                              hipStream_t stream) {
    const float* qe   = (const float*)d_in[0];
    const float* ie   = (const float*)d_in[1];
    const float* wq   = (const float*)d_in[2];
    const float* bq   = (const float*)d_in[3];
    const float* wv   = (const float*)d_in[4];
    const float* bv   = (const float*)d_in[5];
    const float* wo   = (const float*)d_in[6];
    const float* bo   = (const float*)d_in[7];
    const float* wg   = (const float*)d_in[8];
    const float* ln1g = (const float*)d_in[9];
    const float* ln1b = (const float*)d_in[10];
    const float* fw1  = (const float*)d_in[11];
    const float* fb1  = (const float*)d_in[12];
    const float* fw2  = (const float*)d_in[13];
    const float* fb2  = (const float*)d_in[14];
    const float* ln2g = (const float*)d_in[15];
    const float* ln2b = (const float*)d_in[16];

    const size_t RD = (size_t)NROWS * DIM;     // 4,194,304
    float* ws   = (float*)d_ws;
    float* xbuf = ws;                          // question residual (fp32)
    float* ybuf = ws + RD;                     // knowledge residual (fp32)

    u16* b16    = (u16*)(ws + 2 * RD);
    u16* x16    = b16;                 b16 += RD;
    u16* y16    = b16;                 b16 += RD;
    u16* ctx16  = b16;                 b16 += RD;
    u16* qlin16 = b16;                 b16 += RD;
    u16* proj0  = b16;                 b16 += RD;       // bf16 split-K partial 0
    u16* vT     = b16;                 b16 += RD;
    u16* hid    = b16;                 b16 += 4 * RD;   // 8192x2048 bf16, dedicated
    u16* proj1  = b16;                 b16 += RD;       // bf16 split-K partial 1
    u16* wqvT   = b16;                 b16 += 6 * (size_t)1024 * 512;
    u16* woT    = b16;                 b16 += 6 * (size_t)512 * 512;
    u16* fw1T   = b16;                 b16 += 2 * (size_t)DFF2 * 512;
    u16* fw2T   = b16;                 b16 += 2 * (size_t)512 * DFF2;
    float* rmask6 = (float*)b16;                // 6*128 floats

    cast_f2b4<<<(int)(RD / 4 / 256), 256, 0, stream>>>(qe, x16, (int)(RD / 4));
    cast_f2b4<<<(int)(RD / 4 / 256), 256, 0, stream>>>(ie, y16, (int)(RD / 4));

    transpose_cast3<<<dim3(16, 16, 18), 256, 0, stream>>>(wq, wv, wo, wqvT, woT);
    transpose_cast<<<dim3(16, 64, 2), 256, 0, stream>>>(fw1, fw1T, 512, DFF2, 3, 2, (size_t)DFF2 * 512);
    transpose_cast<<<dim3(64, 16, 2), 256, 0, stream>>>(fw2, fw2T, DFF2, 512, 3, 2, (size_t)512 * DFF2);
    init_rmask6<<<3, 256, 0, stream>>>(rmask6);

    const int BIG = 1 << 30;
    // xi: residual input for attn-LN (may be the original network input);
    // xr: residual buffer thereafter; xo2: output of the pos-FFN LN.
    auto run_block = [&](const float* xi, float* xr, u16* xq16, const u16* xv16,
                         int l, int maskf, int pos, float* xo2) {
        size_t lD = (size_t)l * DIM;
        float* rm = rmask6 + l * 128;
        // q|v fused: N=1024, 64-col tiles -> nx=16, 1024 blocks (4/CU).
        // VT=1: V half stores transposed direct into vT.
        gemm2<1, 0, 1, 0, 2, 1><<<1024, 256, 0, stream>>>(
            xq16, xv16, wqvT + (size_t)l * 1024 * 512, bq + lD, bv + lD,
            qlin16, vT, 512, 512, 512, 512, 512, 16);
        router_kernel<<<NROWS / 8, 256, 0, stream>>>(qlin16, wg + (size_t)l * DIM * 6, rm);
        attn_flash<<<512, 512, 0, stream>>>(qlin16, vT, rm, ctx16, maskf);
        // wo proj: N=512 nx=8, split-K x2 (Khalf=256) -> 1024 blocks; bf16 partials
        gemm2<1, 0, 0, 1, 2, 0><<<1024, 256, 0, stream>>>(
            ctx16, ctx16, woT + (size_t)l * 512 * 512, nullptr, nullptr,
            proj0, proj1, 256, 512, 512, 512, BIG, 8);
        add_ln2<<<NROWS, 256, 0, stream>>>(xi, xr, proj0, proj1, bo + lD,
                                           ln1g + lD, ln1b + lD, xq16);
        if (pos) {
            int slot = (l - 3) / 2;
            // fw1: N=2048, 64-col tiles (NI=2) -> nx=32, 2048 blocks (8/CU)
            gemm2<1, 1, 0, 0, 2, 0><<<2048, 256, 0, stream>>>(
                xq16, xq16, fw1T + (size_t)slot * DFF2 * 512,
                fb1 + (size_t)l * DFF2, nullptr,
                hid, nullptr, 512, 512, 512, DFF2, BIG, 32);
            // fw2: N=512 nx=8, K=2048 split-K x2 (Khalf=1024) -> 1024 blocks; bf16 partials
            gemm2<1, 0, 0, 1, 2, 0><<<1024, 256, 0, stream>>>(
                hid, hid, fw2T + (size_t)slot * 512 * DFF2, nullptr, nullptr,
                proj0, proj1, 1024, DFF2, DFF2, 512, BIG, 8);
            add_ln2<<<NROWS, 256, 0, stream>>>(xr, xo2, proj0, proj1, fb2 + lD,
                                               ln2g + lD, ln2b + lD, xq16);
        }
    };

    run_block(ie,   ybuf, y16, y16, 0, 1, 0, ybuf);   // first LN reads input direct
    run_block(ybuf, ybuf, y16, y16, 1, 1, 0, ybuf);
    run_block(qe,   xbuf, x16, x16, 2, 1, 0, xbuf);   // first LN reads input direct
    run_block(xbuf, xbuf, x16, y16, 3, 0, 1, xbuf);
    run_block(xbuf, xbuf, x16, x16, 4, 1, 0, xbuf);
    run_block(xbuf, xbuf, x16, y16, 5, 0, 1, (float*)d_out);   // final LN -> d_out
}